// Round 7
// baseline (434.071 us; speedup 1.0000x reference)
//
#include <hip/hip_runtime.h>
#include <hip/hip_bf16.h>
#include <stdint.h>

#define N_NODES 20000
#define E_EDGES 320000
#define IN_F    128
#define HIDF    256
#define R_REL   4
#define NRKEYS  (N_NODES*R_REL)   // 80000
#define SCAN_BLOCKS 80            // 80*1024 = 81920 >= NRKEYS

typedef __attribute__((ext_vector_type(8))) short  short8;
typedef __attribute__((ext_vector_type(4))) float  floatx4;

__device__ __forceinline__ float bf2f(__hip_bfloat16 v){ return __bfloat162float(v); }
__device__ __forceinline__ __hip_bfloat16 f2bf(float v){ return __float2bfloat16(v); }
__device__ __forceinline__ float bfbits2f(unsigned short u){ return __uint_as_float(((unsigned)u)<<16); }
__device__ __forceinline__ unsigned short f2bfbits(float v){
    __hip_bfloat16 h = __float2bfloat16(v);
    return *(unsigned short*)&h;
}
__device__ __forceinline__ unsigned pack_bf2(float a, float b){
    return (unsigned)f2bfbits(a) | ((unsigned)f2bfbits(b) << 16);
}

// async global->LDS, 16B per lane. LDS dest is WAVE-UNIFORM base (+lane*16 by HW);
// global src is per-lane (pre-swizzled to implement the LDS XOR layout).
__device__ __forceinline__ void gload_lds16(const void* g, void* l)
{
    __builtin_amdgcn_global_load_lds((const __attribute__((address_space(1))) void*)g,
                                     (__attribute__((address_space(3))) void*)l, 16, 0, 0);
}

template<int N>
__device__ __forceinline__ void wait_vm()
{
    if constexpr (N == 0)      asm volatile("s_waitcnt vmcnt(0)" ::: "memory");
    else if constexpr (N == 3) asm volatile("s_waitcnt vmcnt(3)" ::: "memory");
    else if constexpr (N == 4) asm volatile("s_waitcnt vmcnt(4)" ::: "memory");
    else if constexpr (N == 5) asm volatile("s_waitcnt vmcnt(5)" ::: "memory");
    else if constexpr (N == 8) asm volatile("s_waitcnt vmcnt(8)" ::: "memory");
    else                       asm volatile("s_waitcnt vmcnt(0)" ::: "memory");
}

// bijective XCD-chunked swizzle (m204 formula): blocks remapped so each XCD owns a
// contiguous j-range; decomposing j with y FASTEST puts all column-tiles of the
// same A-panel on the SAME XCD back-to-back -> A-panel read from HBM once, then
// L2-hits instead of L3/HBM for the other y's. (Verified r2: FETCH 63.6->17.3 MB.)
// GEMM-structure history: r3 quad-buffer depth-3 lost to occupancy; r4 no-LDS
// register GEMM lost to per-wave L2 latency; r2 triple-buffer / 2-in-flight /
// vmcnt(L) structure is the measured optimum for the long-K GEMMs.
__device__ __forceinline__ int2 xcd_swizzle()
{
    int gx = gridDim.x, gy = gridDim.y;
    int nwg = gx * gy;
    int lin = blockIdx.x + gx * blockIdx.y;
    int q = nwg >> 3, r = nwg & 7;
    int k = lin & 7, i = lin >> 3;
    int j = (k < r ? k*(q+1) : r*(q+1) + (k-r)*q) + i;
    return make_int2(j / gy, j % gy);   // (x tile, y tile), y fastest
}

// ---------------- CSR build ----------------
__global__ void count_kernel(const int* __restrict__ ei, const int* __restrict__ et,
                             int* __restrict__ cnt)
{
    int e = blockIdx.x*256 + threadIdx.x;
    if (e >= E_EDGES) return;
    int dst = ei[E_EDGES + e];
    atomicAdd(&cnt[dst*R_REL + et[e]], 1);
}

// 3-phase parallel exclusive scan over cnt[NRKEYS] -> row_ptr, cursor
__global__ __launch_bounds__(1024) void scan_reduce_kernel(const int* __restrict__ cnt,
                                                           int* __restrict__ blocksum)
{
    int ix = blockIdx.x*1024 + threadIdx.x;
    int v = (ix < NRKEYS) ? cnt[ix] : 0;
    #pragma unroll
    for (int o=32;o>0;o>>=1) v += __shfl_xor(v, o, 64);
    __shared__ int wsum[16];
    int wave = threadIdx.x >> 6, lane = threadIdx.x & 63;
    if (lane == 0) wsum[wave] = v;
    __syncthreads();
    if (threadIdx.x == 0) {
        int s = 0;
        #pragma unroll
        for (int w=0;w<16;w++) s += wsum[w];
        blocksum[blockIdx.x] = s;
    }
}

__global__ __launch_bounds__(128) void scan_sums_kernel(const int* __restrict__ blocksum,
                                                        int* __restrict__ blockoff)
{
    __shared__ int s[128];
    int t = threadIdx.x;
    int v = (t < SCAN_BLOCKS) ? blocksum[t] : 0;
    s[t] = v; __syncthreads();
    for (int off=1; off<128; off<<=1) {
        int u = (t>=off) ? s[t-off] : 0;
        __syncthreads();
        s[t] += u;
        __syncthreads();
    }
    if (t < SCAN_BLOCKS) blockoff[t] = s[t] - v;   // exclusive
}

__global__ __launch_bounds__(1024) void scan_apply_kernel(const int* __restrict__ cnt,
                                                          const int* __restrict__ blockoff,
                                                          int* __restrict__ row_ptr,
                                                          int* __restrict__ cursor)
{
    __shared__ int s[1024];
    int t = threadIdx.x;
    int ix = blockIdx.x*1024 + t;
    int v = (ix < NRKEYS) ? cnt[ix] : 0;
    s[t] = v; __syncthreads();
    for (int off=1; off<1024; off<<=1) {
        int u = (t>=off) ? s[t-off] : 0;
        __syncthreads();
        s[t] += u;
        __syncthreads();
    }
    if (ix < NRKEYS) {
        int excl = blockoff[blockIdx.x] + s[t] - v;
        row_ptr[ix] = excl;
        cursor[ix]  = excl;
        if (ix == NRKEYS-1) row_ptr[NRKEYS] = excl + v;
    }
}

__global__ void fill_kernel(const int* __restrict__ ei, const int* __restrict__ et,
                            int* __restrict__ cursor, int* __restrict__ csr_src)
{
    int e = blockIdx.x*256 + threadIdx.x;
    if (e >= E_EDGES) return;
    int src = ei[e];
    int dst = ei[E_EDGES + e];
    int key = dst*R_REL + et[e];
    int pos = atomicAdd(&cursor[key], 1);
    csr_src[pos] = src;
}

// ---------------- weight prep: fp32 sources -> bf16 B^T = [Nout][K] ----------------
__global__ void make_b1t(const float* __restrict__ root1,
                         const float* __restrict__ W1,
                         __hip_bfloat16* __restrict__ B1t)
{
    int idx = blockIdx.x*256 + threadIdx.x;         // n*640 + k
    if (idx >= 256*640) return;
    int n = idx / 640, k = idx % 640;
    float v;
    if (k < 128) v = root1[k*256 + n];
    else         v = W1[(k-128)*256 + n];           // W1 contiguous [R*128][256]
    B1t[idx] = f2bf(v);
}

__global__ void make_b2t(const float* __restrict__ root2,
                         const float* __restrict__ W2,
                         __hip_bfloat16* __restrict__ B2t)
{
    int idx = blockIdx.x*256 + threadIdx.x;         // n*1280 + k
    if (idx >= 256*1280) return;
    int n = idx / 1280, k = idx % 1280;
    float v;
    if (k < 256) v = root2[k*256 + n];
    else         v = W2[(k-256)*256 + n];           // W2 contiguous [R*256][256]
    B2t[idx] = f2bf(v);
}

__global__ void make_b3t(const float* __restrict__ Wq, const float* __restrict__ Wk,
                         const float* __restrict__ Wv, const float* __restrict__ Wsk,
                         const float* __restrict__ bq, const float* __restrict__ bk,
                         const float* __restrict__ bv, const float* __restrict__ bsk,
                         __hip_bfloat16* __restrict__ B3t, float* __restrict__ bias3)
{
    int idx = blockIdx.x*256 + threadIdx.x;         // n*256 + k, n<1024
    if (idx >= 1024*256) return;
    int n = idx / 256, k = idx % 256;
    int g = n >> 8, nn = n & 255;
    const float* W = (g==0)?Wq:(g==1)?Wk:(g==2)?Wv:Wsk;
    B3t[idx] = f2bf(W[k*256 + nn]);
    if (k == 0) {
        const float* B = (g==0)?bq:(g==1)?bk:(g==2)?bv:bsk;
        bias3[n] = B[nn];
    }
}

// generic fp32 -> bf16 elementwise convert (layout-preserving)
__global__ void cvt_f32_bf16(const float* __restrict__ in, __hip_bfloat16* __restrict__ out, int n)
{
    int i = blockIdx.x*256 + threadIdx.x;
    if (i < n) out[i] = f2bf(in[i]);
}

// ---------------- RGCN aggregation ----------------
// r7: 2 edges per wave (half-waves of 32 lanes), bf16 x (halves agg1 gather
// traffic 164->82 MB and shrinks the gather working set 10->5 MB = L2-fit).
// agg1: xbf bf16 [N,128]; half-wave lane covers dims 4*l32..4*l32+3 (8 B).
__global__ __launch_bounds__(256) void agg1_kernel(const __hip_bfloat16* __restrict__ xbf,
                                                   const int* __restrict__ row_ptr,
                                                   const int* __restrict__ csr_src,
                                                   __hip_bfloat16* __restrict__ A1)
{
    int b = blockIdx.x*4 + (threadIdx.x >> 6);   // key = i*4 + r
    int lane = threadIdx.x & 63;
    int i = b >> 2, r = b & 3;
    int half = lane >> 5, l32 = lane & 31;
    int e0 = row_ptr[b], e1 = row_ptr[b+1];
    float s0=0.f, s1=0.f, s2=0.f, s3=0.f;
    for (int j = e0; j < e1; j += 2) {
        int je = j + half;
        if (je < e1) {
            int src = csr_src[je];
            ushort4 u = *(const ushort4*)(xbf + (size_t)src*IN_F + l32*4);
            s0 += bfbits2f(u.x); s1 += bfbits2f(u.y);
            s2 += bfbits2f(u.z); s3 += bfbits2f(u.w);
        }
    }
    s0 += __shfl_xor(s0, 32, 64);
    s1 += __shfl_xor(s1, 32, 64);
    s2 += __shfl_xor(s2, 32, 64);
    s3 += __shfl_xor(s3, 32, 64);
    float inv = (e1>e0) ? 1.f/(float)(e1-e0) : 0.f;
    if (half == 0) {
        uint2 w;
        w.x = pack_bf2(s0*inv, s1*inv);
        w.y = pack_bf2(s2*inv, s3*inv);
        *(uint2*)(A1 + (size_t)i*640 + 128 + r*128 + l32*4) = w;
        if (r == 0)   // root copy: already bf16, straight 8B copy
            *(uint2*)(A1 + (size_t)i*640 + l32*4) = *(const uint2*)(xbf + (size_t)i*IN_F + l32*4);
    }
}

// agg2: h1 bf16 in A2 cols 0..255 (ld 1280); half-wave lane covers 8 dims (16 B).
__global__ __launch_bounds__(256) void agg2_kernel(const int* __restrict__ row_ptr,
                                                   const int* __restrict__ csr_src,
                                                   __hip_bfloat16* __restrict__ A2)
{
    int b = blockIdx.x*4 + (threadIdx.x >> 6);
    int lane = threadIdx.x & 63;
    int i = b >> 2, r = b & 3;
    int half = lane >> 5, l32 = lane & 31;
    int e0 = row_ptr[b], e1 = row_ptr[b+1];
    float a[8];
    #pragma unroll
    for (int k=0;k<8;k++) a[k] = 0.f;
    for (int j = e0; j < e1; j += 2) {
        int je = j + half;
        if (je < e1) {
            int src = csr_src[je];
            short8 u = *(const short8*)(A2 + (size_t)src*1280 + l32*8);
            #pragma unroll
            for (int k=0;k<8;k++) a[k] += bfbits2f((unsigned short)u[k]);
        }
    }
    #pragma unroll
    for (int k=0;k<8;k++) a[k] += __shfl_xor(a[k], 32, 64);
    float inv = (e1>e0) ? 1.f/(float)(e1-e0) : 0.f;
    if (half == 0) {
        uint4 w;
        w.x = pack_bf2(a[0]*inv, a[1]*inv);
        w.y = pack_bf2(a[2]*inv, a[3]*inv);
        w.z = pack_bf2(a[4]*inv, a[5]*inv);
        w.w = pack_bf2(a[6]*inv, a[7]*inv);
        *(uint4*)(A2 + (size_t)i*1280 + 256 + r*256 + l32*8) = w;
    }
}

// ---------------- LDS-pipelined GEMM (r2 config: best measured) ----------------
// Triple-buffered global_load_lds, 2 batches in flight, counted vmcnt(L).
// Chunk-XOR LDS swizzle via pre-swizzled global source (0 bank conflicts, r1).
template<int MI>
__device__ __forceinline__ void gemm_bt_body(const __hip_bfloat16* __restrict__ A, int lda,
                                             const __hip_bfloat16* __restrict__ Bt,
                                             const float* __restrict__ bias,
                                             __hip_bfloat16* __restrict__ C, int ldc,
                                             int M, int K, int relu,
                                             int tile_m, int tile_n,
                                             __hip_bfloat16* lds_a, __hip_bfloat16* lds_b)
{
    constexpr int A_ELEMS = MI*1024;
    constexpr int B_ELEMS = 4096;
    constexpr int L = MI/2 + 2;
    const int tid  = threadIdx.x;
    const int wave = tid >> 6;
    const int lane = tid & 63;
    const int wm = wave >> 1, wn = wave & 1;
    const int fm = lane & 15;
    const int q  = lane >> 4;
    const int sw = (q ^ ((fm >> 1) & 3)) * 8;

    floatx4 acc[MI][4];
    #pragma unroll
    for (int i=0;i<MI;i++)
        #pragma unroll
        for (int j=0;j<4;j++) acc[i][j] = (floatx4){0.f,0.f,0.f,0.f};

    const int srow   = lane >> 2;
    const int schunk = lane & 3;
    size_t a_goff[MI/2];
    #pragma unroll
    for (int s = 0; s < MI/2; ++s) {
        int r = (s*4 + wave)*16 + srow;
        int c = schunk ^ ((r >> 1) & 3);
        a_goff[s] = (size_t)min(tile_m + r, M-1)*lda + c*8;
    }
    size_t b_goff[2];
    #pragma unroll
    for (int s = 0; s < 2; ++s) {
        int r = (s*4 + wave)*16 + srow;
        int c = schunk ^ ((r >> 1) & 3);
        b_goff[s] = (size_t)(tile_n + r)*K + c*8;
    }

    const int nt = K >> 5;

    auto issue = [&](int t, int bufi) {
        const int kn = t << 5;
        #pragma unroll
        for (int s = 0; s < MI/2; ++s)
            gload_lds16(A + a_goff[s] + kn, lds_a + bufi*A_ELEMS + (s*4 + wave)*512);
        #pragma unroll
        for (int s = 0; s < 2; ++s)
            gload_lds16(Bt + b_goff[s] + kn, lds_b + bufi*B_ELEMS + (s*4 + wave)*512);
    };

    issue(0, 0);
    if (nt > 1) { issue(1, 1); wait_vm<L>(); }
    else        { wait_vm<0>(); }
    __builtin_amdgcn_s_barrier();

    int cur = 0, nx2 = 2;
    for (int t = 0; t < nt; ++t) {
        if (t + 2 < nt) issue(t + 2, nx2);

        const __hip_bfloat16* la = lds_a + cur*A_ELEMS;
        const __hip_bfloat16* lb = lds_b + cur*B_ELEMS;
        short8 afr[MI], bfr[4];
        #pragma unroll
        for (int i=0;i<MI;i++)
            afr[i] = *(const short8*)(la + (wm*(MI*16) + i*16 + fm)*32 + sw);
        #pragma unroll
        for (int j=0;j<4;j++)
            bfr[j] = *(const short8*)(lb + (wn*64 + j*16 + fm)*32 + sw);

        __builtin_amdgcn_s_setprio(1);
        #pragma unroll
        for (int i=0;i<MI;i++)
            #pragma unroll
            for (int j=0;j<4;j++)
                acc[i][j] = __builtin_amdgcn_mfma_f32_16x16x32_bf16(afr[i], bfr[j], acc[i][j], 0,0,0);
        __builtin_amdgcn_s_setprio(0);

        if (t + 1 < nt) {
            if (t + 2 < nt) wait_vm<L>();
            else            wait_vm<0>();
            __builtin_amdgcn_s_barrier();
            cur = (cur == 2) ? 0 : cur + 1;
            nx2 = (nx2 == 2) ? 0 : nx2 + 1;
        }
    }

    const int crow_base = tile_m + wm*(MI*16);
    const int ccol_base = tile_n + wn*64;
    #pragma unroll
    for (int i=0;i<MI;i++) {
        #pragma unroll
        for (int j=0;j<4;j++) {
            int c  = ccol_base + j*16 + fm;
            float bb = bias[c];
            #pragma unroll
            for (int rg=0; rg<4; rg++) {
                int r = crow_base + i*16 + q*4 + rg;
                if (r < M) {
                    float v = acc[i][j][rg] + bb;
                    if (relu) v = fmaxf(v, 0.f);
                    C[(size_t)r*ldc + c] = f2bf(v);
                }
            }
        }
    }
}

template<int MI>
__global__ __launch_bounds__(256) void gemm_bt_t(const __hip_bfloat16* __restrict__ A, int lda,
                                                 const __hip_bfloat16* __restrict__ Bt,
                                                 const float* __restrict__ bias,
                                                 __hip_bfloat16* __restrict__ C, int ldc,
                                                 int M, int K, int relu)
{
    __shared__ __align__(16) __hip_bfloat16 lds_a[3*MI*1024];
    __shared__ __align__(16) __hip_bfloat16 lds_b[3*4096];
    int2 xy = xcd_swizzle();
    gemm_bt_body<MI>(A, lda, Bt, bias, C, ldc, M, K, relu,
                     xy.x*(MI*32), xy.y*128, lds_a, lds_b);
}

// ---------------- fused GRU gate-GEMM + elementwise (r7: 512 threads, 128x64) ----------------
// r6 post-mortem: kernel is latency-bound at 8 waves/CU (64 KB LDS, 4-wave
// blocks). r7: 512-thread blocks (8 waves, 4x2 wave grid), tile 128 rows x 64
// ch. LDS/buffer = A 2x128x32 (16 KB) + B 384x32 (24 KB) = 40 KB; dbuf 80 KB ->
// still 2 blocks/CU but 16 waves/CU (2x latency hiding at same per-wave work:
// 24 MFMA vs 16 ds_read per step). 5 gloads/thread/batch (L=5). Writes only
// the 20 MB fp32 out (fusion verified r5: WRITE 60->20 MB).
__global__ __launch_bounds__(512) void gemm_gru_fused(
    const __hip_bfloat16* __restrict__ A0,   // hatt bf16 [N,256]
    const __hip_bfloat16* __restrict__ A1,   // hprev bf16 [N,256]
    const __hip_bfloat16* __restrict__ Bt0,  // W_ih [768][256]
    const __hip_bfloat16* __restrict__ Bt1,  // W_hh [768][256]
    const float* __restrict__ b_ih, const float* __restrict__ b_hh,
    const float* __restrict__ hprev, float* __restrict__ out)
{
    constexpr int BUF_ELEMS = 20480;  // A 256x32 (8192) + B 384x32 (12288)
    __shared__ __align__(16) __hip_bfloat16 lds[2*BUF_ELEMS];   // 80 KB
    int2 xy = xcd_swizzle();          // grid (157, 4), y = 64-channel chunk
    const int tile_m = xy.x * 128;
    const int c0     = xy.y * 64;
    const int tid = threadIdx.x, wave = tid >> 6, lane = tid & 63;
    const int wm = wave >> 1, wn = wave & 1;     // 4x2 wave grid: 32 rows x 32 ch
    const int fm = lane & 15, q = lane >> 4;
    const int sw = (q ^ ((fm >> 1) & 3)) * 8;

    // 40 staging segments (16 frag-rows x 64 B each): 0..15 A, 16..39 B; 5/wave.
    // frag-row space: A = mat*128 + row_local (0..255);
    //                 B = (mat*3+gate)*64 + ch_local (0..383)
    const int sub = lane >> 2, ch = lane & 3;
    const __hip_bfloat16* gsrc[5];
    int dstoff[5];
    #pragma unroll
    for (int s = 0; s < 5; ++s) {
        int seg = wave*5 + s;                        // 0..39
        if (seg < 16) {
            int fr = seg*16 + sub;                   // 0..255
            int mat = fr >> 7, rl = fr & 127;
            int c = ch ^ ((fr >> 1) & 3);
            int grow = min(tile_m + rl, N_NODES-1);
            gsrc[s] = (mat ? A1 : A0) + (size_t)grow*256 + c*8;
            dstoff[s] = seg*512;
        } else {
            int fs = seg - 16;
            int fr = fs*16 + sub;                    // 0..383
            int grp = fr >> 6, ri = fr & 63;         // grp = mat*3 + gate
            int mat = grp >= 3, gate = mat ? grp-3 : grp;
            int c = ch ^ ((fr >> 1) & 3);
            int grow = gate*256 + c0 + ri;
            gsrc[s] = (mat ? Bt1 : Bt0) + (size_t)grow*256 + c*8;
            dstoff[s] = 8192 + fs*512;
        }
    }

    floatx4 acc[2][3][2][2];   // [mat][gate][row frag][col frag]
    #pragma unroll
    for (int m=0;m<2;m++)
        #pragma unroll
        for (int g=0;g<3;g++)
            #pragma unroll
            for (int i=0;i<2;i++)
                #pragma unroll
                for (int f=0;f<2;f++) acc[m][g][i][f] = (floatx4){0.f,0.f,0.f,0.f};

    auto issue = [&](int t, int bufi) {
        const int kn = t << 5;
        #pragma unroll
        for (int s = 0; s < 5; ++s)
            gload_lds16(gsrc[s] + kn, lds + bufi*BUF_ELEMS + dstoff[s]);
    };

    issue(0, 0);
    issue(1, 1);
    wait_vm<5>();                      // batch 0 landed; batch 1 in flight
    __builtin_amdgcn_s_barrier();

    #pragma unroll 1
    for (int t = 0; t < 8; ++t) {
        const __hip_bfloat16* lb = lds + (t & 1)*BUF_ELEMS;
        short8 af[2][2], bfr[2][3][2];
        #pragma unroll
        for (int m=0;m<2;m++)
            #pragma unroll
            for (int i=0;i<2;i++)
                af[m][i] = *(const short8*)(lb + (m*128 + wm*32 + i*16 + fm)*32 + sw);
        #pragma unroll
        for (int m=0;m<2;m++)
            #pragma unroll
            for (int g=0;g<3;g++)
                #pragma unroll
                for (int f=0;f<2;f++)
                    bfr[m][g][f] = *(const short8*)(lb + 8192 + (((m*3+g)*64 + wn*32 + f*16 + fm)*32) + sw);

        __builtin_amdgcn_s_setprio(1);
        #pragma unroll
        for (int m=0;m<2;m++)
            #pragma unroll
            for (int g=0;g<3;g++)
                #pragma unroll
                for (int i=0;i<2;i++)
                    #pragma unroll
                    for (int f=0;f<2;f++)
                        acc[m][g][i][f] = __builtin_amdgcn_mfma_f32_16x16x32_bf16(af[m][i], bfr[m][g][f], acc[m][g][i][f], 0,0,0);
        __builtin_amdgcn_s_setprio(0);

        if (t + 1 < 8) {
            __builtin_amdgcn_s_barrier();            // all waves done reading buf[t&1]
            if (t + 2 < 8) { issue(t + 2, t & 1); wait_vm<5>(); }  // t+1 landed, t+2 in flight
            else           wait_vm<0>();                           // tail drain
            __builtin_amdgcn_s_barrier();            // everyone's batch t+1 visible
        }
    }

    // epilogue: GRU math (exp-based sigmoid/tanh), write fp32 out only
    #pragma unroll
    for (int f=0; f<2; ++f) {
        int c = c0 + wn*32 + f*16 + fm;
        float bir = b_ih[c], biz = b_ih[256+c], bin = b_ih[512+c];
        float bhr = b_hh[c], bhz = b_hh[256+c], bhn = b_hh[512+c];
        #pragma unroll
        for (int i=0; i<2; ++i) {
            #pragma unroll
            for (int rg=0; rg<4; ++rg) {
                int r = tile_m + wm*32 + i*16 + q*4 + rg;
                if (r < N_NODES) {
                    float gir = acc[0][0][i][f][rg] + bir;
                    float giz = acc[0][1][i][f][rg] + biz;
                    float gin = acc[0][2][i][f][rg] + bin;
                    float ghr = acc[1][0][i][f][rg] + bhr;
                    float ghz = acc[1][1][i][f][rg] + bhz;
                    float ghn = acc[1][2][i][f][rg] + bhn;
                    float rr = 1.f/(1.f + __expf(-(gir + ghr)));
                    float zz = 1.f/(1.f + __expf(-(giz + ghz)));
                    float xn = gin + rr*ghn;
                    float e2 = __expf(xn + xn);
                    float nn = 1.f - 2.f/(e2 + 1.f);   // tanh(xn)
                    float h  = hprev[(size_t)r*256 + c];
                    out[(size_t)r*256 + c] = (1.f - zz)*nn + zz*h;
                }
            }
        }
    }
}

// ---------------- attention scores: ONE WAVE PER NODE ----------------
__global__ __launch_bounds__(256) void score_kernel(const __hip_bfloat16* __restrict__ qkvs,
                                                    const int* __restrict__ row_ptr,
                                                    const int* __restrict__ csr_src,
                                                    float* __restrict__ score)
{
    int i = blockIdx.x*4 + (threadIdx.x >> 6);
    int lane = threadIdx.x & 63;
    int h = lane >> 4, d4 = lane & 15;
    int e0 = row_ptr[i*R_REL], e1 = row_ptr[i*R_REL + R_REL];
    ushort4 qv = *(const ushort4*)(qkvs + (size_t)i*1024 + lane*4);
    float qx=bfbits2f(qv.x), qy=bfbits2f(qv.y), qz=bfbits2f(qv.z), qw=bfbits2f(qv.w);
    float* sp = score + (size_t)h*E_EDGES;
    int j = e0;
    for (; j+2 <= e1; j += 2) {
        int s0 = csr_src[j], s1 = csr_src[j+1];
        ushort4 k0 = *(const ushort4*)(qkvs + (size_t)s0*1024 + 256 + lane*4);
        ushort4 k1 = *(const ushort4*)(qkvs + (size_t)s1*1024 + 256 + lane*4);
        float d0 = qx*bfbits2f(k0.x)+qy*bfbits2f(k0.y)+qz*bfbits2f(k0.z)+qw*bfbits2f(k0.w);
        float d1 = qx*bfbits2f(k1.x)+qy*bfbits2f(k1.y)+qz*bfbits2f(k1.z)+qw*bfbits2f(k1.w);
        #pragma unroll
        for (int o=1;o<16;o<<=1){ d0 += __shfl_xor(d0,o,64); d1 += __shfl_xor(d1,o,64); }
        if (d4 == 0) { sp[j] = d0*0.125f; sp[j+1] = d1*0.125f; }
    }
    for (; j < e1; j++) {
        int s0 = csr_src[j];
        ushort4 k0 = *(const ushort4*)(qkvs + (size_t)s0*1024 + 256 + lane*4);
        float d0 = qx*bfbits2f(k0.x)+qy*bfbits2f(k0.y)+qz*bfbits2f(k0.z)+qw*bfbits2f(k0.w);
        #pragma unroll
        for (int o=1;o<16;o<<=1) d0 += __shfl_xor(d0,o,64);
        if (d4 == 0) sp[j] = d0*0.125f;
    }
}

// ---------------- attention aggregate: ONE WAVE PER NODE, all 4 heads ----------------
__global__ __launch_bounds__(256) void attn_agg_kernel(const __hip_bfloat16* __restrict__ qkvs,
                                                       const float* __restrict__ score,
                                                       const int* __restrict__ row_ptr,
                                                       const int* __restrict__ csr_src,
                                                       __hip_bfloat16* __restrict__ hatt)
{
    int i = blockIdx.x*4 + (threadIdx.x >> 6);   // node (4 nodes per block)
    int lane = threadIdx.x & 63;
    int h  = lane >> 4;
    int d4 = lane & 15;
    int e0 = row_ptr[i*R_REL], e1 = row_ptr[i*R_REL + R_REL];
    int deg = e1 - e0;
    const float* sp = score + (size_t)h*E_EDGES + e0;

    float m = -1e30f;
    for (int j = d4; j < deg; j += 16) m = fmaxf(m, sp[j]);
    #pragma unroll
    for (int o=1;o<16;o<<=1) m = fmaxf(m, __shfl_xor(m, o, 64));

    float ssum = 0.f;
    for (int j = d4; j < deg; j += 16) ssum += __expf(sp[j] - m);
    #pragma unroll
    for (int o=1;o<16;o<<=1) ssum += __shfl_xor(ssum, o, 64);
    float inv = 1.f / fmaxf(ssum, 1e-16f);

    float ax=0.f, ay=0.f, az=0.f, aw=0.f;
    int j = 0;
    for (; j+4 <= deg; j += 4) {
        int s0=csr_src[e0+j], s1=csr_src[e0+j+1], s2=csr_src[e0+j+2], s3=csr_src[e0+j+3];
        float w0 = __expf(sp[j]   - m) * inv;
        float w1 = __expf(sp[j+1] - m) * inv;
        float w2 = __expf(sp[j+2] - m) * inv;
        float w3 = __expf(sp[j+3] - m) * inv;
        ushort4 u0 = *(const ushort4*)(qkvs + (size_t)s0*1024 + 512 + lane*4);
        ushort4 u1 = *(const ushort4*)(qkvs + (size_t)s1*1024 + 512 + lane*4);
        ushort4 u2 = *(const ushort4*)(qkvs + (size_t)s2*1024 + 512 + lane*4);
        ushort4 u3 = *(const ushort4*)(qkvs + (size_t)s3*1024 + 512 + lane*4);
        ax += w0*bfbits2f(u0.x) + w1*bfbits2f(u1.x) + w2*bfbits2f(u2.x) + w3*bfbits2f(u3.x);
        ay += w0*bfbits2f(u0.y) + w1*bfbits2f(u1.y) + w2*bfbits2f(u2.y) + w3*bfbits2f(u3.y);
        az += w0*bfbits2f(u0.z) + w1*bfbits2f(u1.z) + w2*bfbits2f(u2.z) + w3*bfbits2f(u3.z);
        aw += w0*bfbits2f(u0.w) + w1*bfbits2f(u1.w) + w2*bfbits2f(u2.w) + w3*bfbits2f(u3.w);
    }
    for (; j < deg; j++) {
        int s = csr_src[e0+j];
        float w = __expf(sp[j] - m) * inv;
        ushort4 u = *(const ushort4*)(qkvs + (size_t)s*1024 + 512 + lane*4);
        ax += w*bfbits2f(u.x); ay += w*bfbits2f(u.y);
        az += w*bfbits2f(u.z); aw += w*bfbits2f(u.w);
    }
    ushort4 sk = *(const ushort4*)(qkvs + (size_t)i*1024 + 768 + lane*4);
    uint2 w;
    w.x = pack_bf2(ax + bfbits2f(sk.x), ay + bfbits2f(sk.y));
    w.y = pack_bf2(az + bfbits2f(sk.z), aw + bfbits2f(sk.w));
    *(uint2*)(hatt + (size_t)i*256 + lane*4) = w;
}

// ---------------- launch ----------------
extern "C" void kernel_launch(void* const* d_in, const int* in_sizes, int n_in,
                              void* d_out, int out_size, void* d_ws, size_t ws_size,
                              hipStream_t stream)
{
    const float* x       = (const float*)d_in[0];
    const int* edge_index= (const int*)d_in[1];
    const int* edge_type = (const int*)d_in[2];
    const float* hprev   = (const float*)d_in[3];
    const float* W1      = (const float*)d_in[4];
    const float* root1   = (const float*)d_in[5];
    const float* b1      = (const float*)d_in[6];
    const float* W2      = (const float*)d_in[7];
    const float* root2   = (const float*)d_in[8];
    const float* b2      = (const float*)d_in[9];
    const float* Wq      = (const float*)d_in[10];
    const float* bq      = (const float*)d_in[11];
    const float* Wk      = (const float*)d_in[12];
    const float* bk      = (const float*)d_in[13];
    const float* Wv      = (const float*)d_in[14];
    const float* bv      = (const float*)d_in[15];
    const float* Wskip   = (const float*)d_in[16];
    const float* bskip   = (const float*)d_in[17];
    const float* W_ih    = (const float*)d_in[18];
    const float* b_ih    = (const float*)d_in[19];
    const float* W_hh    = (const float*)d_in[20];
    const float* b_hh    = (const float*)d_in[21];

    char* ws = (char*)d_ws;
    size_t off = 0;
    auto take = [&](size_t bytes)->char* {
        char* p = ws + off;
        off = (off + bytes + 255) & ~(size_t)255;
        return p;
    };
    int* cnt        = (int*)take((size_t)NRKEYS*4);
    int* row_ptr    = (int*)take((size_t)(NRKEYS+1)*4);
    int* cursor     = (int*)take((size_t)NRKEYS*4);
    int* csr_src    = (int*)take((size_t)E_EDGES*4);
    int* blocksum   = (int*)take((size_t)SCAN_BLOCKS*4);
    int* blockoff   = (int*)take((size_t)(SCAN_BLOCKS+1)*4);
    float* score    = (float*)take((size_t)R_REL*E_EDGES*4);
    __hip_bfloat16* B1t   = (__hip_bfloat16*)take((size_t)256*640*2);
    __hip_bfloat16* B2t   = (__hip_bfloat16*)take((size_t)256*1280*2);
    __hip_bfloat16* B3t   = (__hip_bfloat16*)take((size_t)1024*256*2);
    __hip_bfloat16* Biht  = (__hip_bfloat16*)take((size_t)768*256*2);
    __hip_bfloat16* Bhht  = (__hip_bfloat16*)take((size_t)768*256*2);
    float*          bias3 = (float*)take((size_t)1024*4);
    __hip_bfloat16* hprev_bf = (__hip_bfloat16*)take((size_t)N_NODES*256*2);
    __hip_bfloat16* xbf      = (__hip_bfloat16*)take((size_t)N_NODES*IN_F*2);
    char* P1 = take((size_t)N_NODES*640*2);
    char* P2 = take((size_t)N_NODES*1536*2);

    __hip_bfloat16* A1   = (__hip_bfloat16*)P1;   // [N,640]  dead after gemm1
    __hip_bfloat16* h2   = (__hip_bfloat16*)P1;   // [N,256]  dead after gemm3
    __hip_bfloat16* hatt = (__hip_bfloat16*)P1;   // [N,256]  read by fused GRU
    __hip_bfloat16* A2   = (__hip_bfloat16*)P2;   // [N,1280] dead after gemm2
    __hip_bfloat16* qkvs = (__hip_bfloat16*)P2;   // [N,1024] dead after attn_agg

    hipMemsetAsync(cnt, 0, (size_t)NRKEYS*4, stream);
    count_kernel<<<(E_EDGES+255)/256, 256, 0, stream>>>(edge_index, edge_type, cnt);
    scan_reduce_kernel<<<SCAN_BLOCKS, 1024, 0, stream>>>(cnt, blocksum);
    scan_sums_kernel<<<1, 128, 0, stream>>>(blocksum, blockoff);
    scan_apply_kernel<<<SCAN_BLOCKS, 1024, 0, stream>>>(cnt, blockoff, row_ptr, cursor);
    fill_kernel<<<(E_EDGES+255)/256, 256, 0, stream>>>(edge_index, edge_type, cursor, csr_src);

    make_b1t<<<(256*640+255)/256, 256, 0, stream>>>(root1, W1, B1t);
    make_b2t<<<(256*1280+255)/256, 256, 0, stream>>>(root2, W2, B2t);
    make_b3t<<<(1024*256+255)/256, 256, 0, stream>>>(Wq, Wk, Wv, Wskip, bq, bk, bv, bskip, B3t, bias3);
    cvt_f32_bf16<<<(768*256+255)/256, 256, 0, stream>>>(W_ih, Biht, 768*256);
    cvt_f32_bf16<<<(768*256+255)/256, 256, 0, stream>>>(W_hh, Bhht, 768*256);
    cvt_f32_bf16<<<(N_NODES*256+255)/256, 256, 0, stream>>>(hprev, hprev_bf, N_NODES*256);
    cvt_f32_bf16<<<(N_NODES*IN_F+255)/256, 256, 0, stream>>>(x, xbf, N_NODES*IN_F);

    agg1_kernel<<<NRKEYS/4, 256, 0, stream>>>(xbf, row_ptr, csr_src, A1);

    // h1 = relu(A1 * B1) written into A2 cols 0..255 (ldc=1280)
    dim3 g12(313, 2);
    gemm_bt_t<2><<<g12, 256, 0, stream>>>(A1, 640, B1t, b1, A2, 1280, N_NODES, 640, 1);

    agg2_kernel<<<NRKEYS/4, 256, 0, stream>>>(row_ptr, csr_src, A2);

    // h2 overwrites A1 (dead) in P1
    gemm_bt_t<2><<<g12, 256, 0, stream>>>(A2, 1280, B2t, b2, h2, 256, N_NODES, 1280, 1);

    // qkvs overwrites A2 (dead) in P2
    dim3 g3(157, 8);
    gemm_bt_t<4><<<g3, 256, 0, stream>>>(h2, 256, B3t, bias3, qkvs, 1024, N_NODES, 256, 0);

    score_kernel<<<N_NODES/4, 256, 0, stream>>>(qkvs, row_ptr, csr_src, score);
    attn_agg_kernel<<<N_NODES/4, 256, 0, stream>>>(qkvs, score, row_ptr, csr_src, hatt);

    // fused GRU gate-GEMMs + elementwise (512 threads, 128x64 tiles, 16 waves/CU)
    gemm_gru_fused<<<dim3(157, 4), 512, 0, stream>>>(hatt, hprev_bf, Biht, Bhht,
                                                     b_ih, b_hh, hprev, (float*)d_out);
}

// Round 8
// 430.961 us; speedup vs baseline: 1.0072x; 1.0072x over previous
//
#include <hip/hip_runtime.h>
#include <hip/hip_bf16.h>
#include <stdint.h>

#define N_NODES 20000
#define E_EDGES 320000
#define IN_F    128
#define HIDF    256
#define R_REL   4
#define NRKEYS  (N_NODES*R_REL)   // 80000
#define SCAN_BLOCKS 80            // 80*1024 = 81920 >= NRKEYS

typedef __attribute__((ext_vector_type(8))) short  short8;
typedef __attribute__((ext_vector_type(4))) float  floatx4;

__device__ __forceinline__ float bf2f(__hip_bfloat16 v){ return __bfloat162float(v); }
__device__ __forceinline__ __hip_bfloat16 f2bf(float v){ return __float2bfloat16(v); }
__device__ __forceinline__ float bfbits2f(unsigned short u){ return __uint_as_float(((unsigned)u)<<16); }
__device__ __forceinline__ unsigned short f2bfbits(float v){
    __hip_bfloat16 h = __float2bfloat16(v);
    return *(unsigned short*)&h;
}
__device__ __forceinline__ unsigned pack_bf2(float a, float b){
    return (unsigned)f2bfbits(a) | ((unsigned)f2bfbits(b) << 16);
}

// async global->LDS, 16B per lane. LDS dest is WAVE-UNIFORM base (+lane*16 by HW);
// global src is per-lane (pre-swizzled to implement the LDS XOR layout).
__device__ __forceinline__ void gload_lds16(const void* g, void* l)
{
    __builtin_amdgcn_global_load_lds((const __attribute__((address_space(1))) void*)g,
                                     (__attribute__((address_space(3))) void*)l, 16, 0, 0);
}

template<int N>
__device__ __forceinline__ void wait_vm()
{
    if constexpr (N == 0)      asm volatile("s_waitcnt vmcnt(0)" ::: "memory");
    else if constexpr (N == 3) asm volatile("s_waitcnt vmcnt(3)" ::: "memory");
    else if constexpr (N == 4) asm volatile("s_waitcnt vmcnt(4)" ::: "memory");
    else                       asm volatile("s_waitcnt vmcnt(0)" ::: "memory");
}

// bijective XCD-chunked swizzle (m204 formula): blocks remapped so each XCD owns a
// contiguous j-range; decomposing j with y FASTEST puts all column-tiles of the
// same A-panel on the SAME XCD back-to-back -> A-panel read from HBM once, then
// L2-hits instead of L3/HBM for the other y's. (Verified r2: FETCH 63.6->17.3 MB.)
// GEMM-structure history: r3 quad-buffer depth-3 lost to occupancy; r4 no-LDS
// register GEMM (both operands global) lost to per-wave L2 latency; r2
// triple-buffer / 2-in-flight / vmcnt(L) is the measured optimum for long-K.
// Fused-GRU history: r5/6/7 barrier-convoy schedules converged at ~49 us.
__device__ __forceinline__ int2 xcd_swizzle()
{
    int gx = gridDim.x, gy = gridDim.y;
    int nwg = gx * gy;
    int lin = blockIdx.x + gx * blockIdx.y;
    int q = nwg >> 3, r = nwg & 7;
    int k = lin & 7, i = lin >> 3;
    int j = (k < r ? k*(q+1) : r*(q+1) + (k-r)*q) + i;
    return make_int2(j / gy, j % gy);   // (x tile, y tile), y fastest
}

// ---------------- CSR build ----------------
__global__ void count_kernel(const int* __restrict__ ei, const int* __restrict__ et,
                             int* __restrict__ cnt)
{
    int e = blockIdx.x*256 + threadIdx.x;
    if (e >= E_EDGES) return;
    int dst = ei[E_EDGES + e];
    atomicAdd(&cnt[dst*R_REL + et[e]], 1);
}

// 3-phase parallel exclusive scan over cnt[NRKEYS] -> row_ptr, cursor
__global__ __launch_bounds__(1024) void scan_reduce_kernel(const int* __restrict__ cnt,
                                                           int* __restrict__ blocksum)
{
    int ix = blockIdx.x*1024 + threadIdx.x;
    int v = (ix < NRKEYS) ? cnt[ix] : 0;
    #pragma unroll
    for (int o=32;o>0;o>>=1) v += __shfl_xor(v, o, 64);
    __shared__ int wsum[16];
    int wave = threadIdx.x >> 6, lane = threadIdx.x & 63;
    if (lane == 0) wsum[wave] = v;
    __syncthreads();
    if (threadIdx.x == 0) {
        int s = 0;
        #pragma unroll
        for (int w=0;w<16;w++) s += wsum[w];
        blocksum[blockIdx.x] = s;
    }
}

__global__ __launch_bounds__(128) void scan_sums_kernel(const int* __restrict__ blocksum,
                                                        int* __restrict__ blockoff)
{
    __shared__ int s[128];
    int t = threadIdx.x;
    int v = (t < SCAN_BLOCKS) ? blocksum[t] : 0;
    s[t] = v; __syncthreads();
    for (int off=1; off<128; off<<=1) {
        int u = (t>=off) ? s[t-off] : 0;
        __syncthreads();
        s[t] += u;
        __syncthreads();
    }
    if (t < SCAN_BLOCKS) blockoff[t] = s[t] - v;   // exclusive
}

__global__ __launch_bounds__(1024) void scan_apply_kernel(const int* __restrict__ cnt,
                                                          const int* __restrict__ blockoff,
                                                          int* __restrict__ row_ptr,
                                                          int* __restrict__ cursor)
{
    __shared__ int s[1024];
    int t = threadIdx.x;
    int ix = blockIdx.x*1024 + t;
    int v = (ix < NRKEYS) ? cnt[ix] : 0;
    s[t] = v; __syncthreads();
    for (int off=1; off<1024; off<<=1) {
        int u = (t>=off) ? s[t-off] : 0;
        __syncthreads();
        s[t] += u;
        __syncthreads();
    }
    if (ix < NRKEYS) {
        int excl = blockoff[blockIdx.x] + s[t] - v;
        row_ptr[ix] = excl;
        cursor[ix]  = excl;
        if (ix == NRKEYS-1) row_ptr[NRKEYS] = excl + v;
    }
}

__global__ void fill_kernel(const int* __restrict__ ei, const int* __restrict__ et,
                            int* __restrict__ cursor, int* __restrict__ csr_src)
{
    int e = blockIdx.x*256 + threadIdx.x;
    if (e >= E_EDGES) return;
    int src = ei[e];
    int dst = ei[E_EDGES + e];
    int key = dst*R_REL + et[e];
    int pos = atomicAdd(&cursor[key], 1);
    csr_src[pos] = src;
}

// ---------------- weight prep: fp32 sources -> bf16 B^T = [Nout][K] ----------------
__global__ void make_b1t(const float* __restrict__ root1,
                         const float* __restrict__ W1,
                         __hip_bfloat16* __restrict__ B1t)
{
    int idx = blockIdx.x*256 + threadIdx.x;         // n*640 + k
    if (idx >= 256*640) return;
    int n = idx / 640, k = idx % 640;
    float v;
    if (k < 128) v = root1[k*256 + n];
    else         v = W1[(k-128)*256 + n];           // W1 contiguous [R*128][256]
    B1t[idx] = f2bf(v);
}

__global__ void make_b2t(const float* __restrict__ root2,
                         const float* __restrict__ W2,
                         __hip_bfloat16* __restrict__ B2t)
{
    int idx = blockIdx.x*256 + threadIdx.x;         // n*1280 + k
    if (idx >= 256*1280) return;
    int n = idx / 1280, k = idx % 1280;
    float v;
    if (k < 256) v = root2[k*256 + n];
    else         v = W2[(k-256)*256 + n];           // W2 contiguous [R*256][256]
    B2t[idx] = f2bf(v);
}

__global__ void make_b3t(const float* __restrict__ Wq, const float* __restrict__ Wk,
                         const float* __restrict__ Wv, const float* __restrict__ Wsk,
                         const float* __restrict__ bq, const float* __restrict__ bk,
                         const float* __restrict__ bv, const float* __restrict__ bsk,
                         __hip_bfloat16* __restrict__ B3t, float* __restrict__ bias3)
{
    int idx = blockIdx.x*256 + threadIdx.x;         // n*256 + k, n<1024
    if (idx >= 1024*256) return;
    int n = idx / 256, k = idx % 256;
    int g = n >> 8, nn = n & 255;
    const float* W = (g==0)?Wq:(g==1)?Wk:(g==2)?Wv:Wsk;
    B3t[idx] = f2bf(W[k*256 + nn]);
    if (k == 0) {
        const float* B = (g==0)?bq:(g==1)?bk:(g==2)?bv:bsk;
        bias3[n] = B[nn];
    }
}

// generic fp32 -> bf16 elementwise convert (layout-preserving)
__global__ void cvt_f32_bf16(const float* __restrict__ in, __hip_bfloat16* __restrict__ out, int n)
{
    int i = blockIdx.x*256 + threadIdx.x;
    if (i < n) out[i] = f2bf(in[i]);
}

// ---------------- RGCN aggregation: one WAVE per (node,rel) key, unroll-4 ILP ----------------
// r8: reverted to the r6 ILP-4 structure (r7's half-wave variant traded MLP for
// instruction count and lost ~6 us). agg1 keeps bf16 x (r7-proven, absmax
// unchanged): lane covers dims 2*lane..2*lane+1 via uint (2 bf16, 4 B) ->
// half of r6's gather bytes at identical ILP.
__global__ __launch_bounds__(256) void agg1_kernel(const __hip_bfloat16* __restrict__ xbf,
                                                   const int* __restrict__ row_ptr,
                                                   const int* __restrict__ csr_src,
                                                   __hip_bfloat16* __restrict__ A1)
{
    int b = blockIdx.x*4 + (threadIdx.x >> 6);   // key = i*4 + r
    int lane = threadIdx.x & 63;
    int i = b >> 2, r = b & 3;
    int e0 = row_ptr[b], e1 = row_ptr[b+1];
    float sx0=0.f,sy0=0.f, sx1=0.f,sy1=0.f, sx2=0.f,sy2=0.f, sx3=0.f,sy3=0.f;
    int e = e0;
    for (; e+4 <= e1; e += 4) {
        int i0=csr_src[e], i1=csr_src[e+1], i2=csr_src[e+2], i3=csr_src[e+3];
        unsigned u0 = *(const unsigned*)(xbf + (size_t)i0*IN_F + lane*2);
        unsigned u1 = *(const unsigned*)(xbf + (size_t)i1*IN_F + lane*2);
        unsigned u2 = *(const unsigned*)(xbf + (size_t)i2*IN_F + lane*2);
        unsigned u3 = *(const unsigned*)(xbf + (size_t)i3*IN_F + lane*2);
        sx0+=bfbits2f((unsigned short)u0); sy0+=bfbits2f((unsigned short)(u0>>16));
        sx1+=bfbits2f((unsigned short)u1); sy1+=bfbits2f((unsigned short)(u1>>16));
        sx2+=bfbits2f((unsigned short)u2); sy2+=bfbits2f((unsigned short)(u2>>16));
        sx3+=bfbits2f((unsigned short)u3); sy3+=bfbits2f((unsigned short)(u3>>16));
    }
    for (; e < e1; e++) {
        int i0 = csr_src[e];
        unsigned u = *(const unsigned*)(xbf + (size_t)i0*IN_F + lane*2);
        sx0+=bfbits2f((unsigned short)u); sy0+=bfbits2f((unsigned short)(u>>16));
    }
    float sx = (sx0+sx1)+(sx2+sx3);
    float sy = (sy0+sy1)+(sy2+sy3);
    float inv = (e1>e0) ? 1.f/(float)(e1-e0) : 0.f;
    *(unsigned*)(A1 + (size_t)i*640 + 128 + r*128 + lane*2) = pack_bf2(sx*inv, sy*inv);
    if (r == 0)   // root copy: already bf16, straight 4B copy
        *(unsigned*)(A1 + (size_t)i*640 + lane*2) = *(const unsigned*)(xbf + (size_t)i*IN_F + lane*2);
}

// agg2: h1 bf16 in A2 cols 0..255 (ld 1280); lane covers dims 4*lane..4*lane+3 (8 B).
__global__ __launch_bounds__(256) void agg2_kernel(const int* __restrict__ row_ptr,
                                                   const int* __restrict__ csr_src,
                                                   __hip_bfloat16* __restrict__ A2)
{
    int b = blockIdx.x*4 + (threadIdx.x >> 6);
    int lane = threadIdx.x & 63;
    int i = b >> 2, r = b & 3;
    int e0 = row_ptr[b], e1 = row_ptr[b+1];
    float a0=0.f,a1=0.f,a2=0.f,a3=0.f;
    float b0=0.f,b1=0.f,b2=0.f,b3=0.f;
    float c0=0.f,c1=0.f,c2=0.f,c3=0.f;
    float d0=0.f,d1=0.f,d2=0.f,d3=0.f;
    int e = e0;
    for (; e+4 <= e1; e += 4) {
        int i0=csr_src[e], i1=csr_src[e+1], i2=csr_src[e+2], i3=csr_src[e+3];
        ushort4 u0 = *(const ushort4*)(A2 + (size_t)i0*1280 + lane*4);
        ushort4 u1 = *(const ushort4*)(A2 + (size_t)i1*1280 + lane*4);
        ushort4 u2 = *(const ushort4*)(A2 + (size_t)i2*1280 + lane*4);
        ushort4 u3 = *(const ushort4*)(A2 + (size_t)i3*1280 + lane*4);
        a0+=bfbits2f(u0.x); a1+=bfbits2f(u0.y); a2+=bfbits2f(u0.z); a3+=bfbits2f(u0.w);
        b0+=bfbits2f(u1.x); b1+=bfbits2f(u1.y); b2+=bfbits2f(u1.z); b3+=bfbits2f(u1.w);
        c0+=bfbits2f(u2.x); c1+=bfbits2f(u2.y); c2+=bfbits2f(u2.z); c3+=bfbits2f(u2.w);
        d0+=bfbits2f(u3.x); d1+=bfbits2f(u3.y); d2+=bfbits2f(u3.z); d3+=bfbits2f(u3.w);
    }
    for (; e < e1; e++) {
        int i0 = csr_src[e];
        ushort4 u = *(const ushort4*)(A2 + (size_t)i0*1280 + lane*4);
        a0+=bfbits2f(u.x); a1+=bfbits2f(u.y); a2+=bfbits2f(u.z); a3+=bfbits2f(u.w);
    }
    float s0=(a0+b0)+(c0+d0), s1=(a1+b1)+(c1+d1), s2=(a2+b2)+(c2+d2), s3=(a3+b3)+(c3+d3);
    float inv = (e1>e0) ? 1.f/(float)(e1-e0) : 0.f;
    uint2 w;
    w.x = pack_bf2(s0*inv, s1*inv);
    w.y = pack_bf2(s2*inv, s3*inv);
    *(uint2*)(A2 + (size_t)i*1280 + 256 + r*256 + lane*4) = w;
}

// ---------------- LDS-pipelined GEMM (r2 config: best measured) ----------------
// Triple-buffered global_load_lds, 2 batches in flight, counted vmcnt(L).
// Chunk-XOR LDS swizzle via pre-swizzled global source (0 bank conflicts, r1).
template<int MI>
__device__ __forceinline__ void gemm_bt_body(const __hip_bfloat16* __restrict__ A, int lda,
                                             const __hip_bfloat16* __restrict__ Bt,
                                             const float* __restrict__ bias,
                                             __hip_bfloat16* __restrict__ C, int ldc,
                                             int M, int K, int relu,
                                             int tile_m, int tile_n,
                                             __hip_bfloat16* lds_a, __hip_bfloat16* lds_b)
{
    constexpr int A_ELEMS = MI*1024;
    constexpr int B_ELEMS = 4096;
    constexpr int L = MI/2 + 2;
    const int tid  = threadIdx.x;
    const int wave = tid >> 6;
    const int lane = tid & 63;
    const int wm = wave >> 1, wn = wave & 1;
    const int fm = lane & 15;
    const int q  = lane >> 4;
    const int sw = (q ^ ((fm >> 1) & 3)) * 8;

    floatx4 acc[MI][4];
    #pragma unroll
    for (int i=0;i<MI;i++)
        #pragma unroll
        for (int j=0;j<4;j++) acc[i][j] = (floatx4){0.f,0.f,0.f,0.f};

    const int srow   = lane >> 2;
    const int schunk = lane & 3;
    size_t a_goff[MI/2];
    #pragma unroll
    for (int s = 0; s < MI/2; ++s) {
        int r = (s*4 + wave)*16 + srow;
        int c = schunk ^ ((r >> 1) & 3);
        a_goff[s] = (size_t)min(tile_m + r, M-1)*lda + c*8;
    }
    size_t b_goff[2];
    #pragma unroll
    for (int s = 0; s < 2; ++s) {
        int r = (s*4 + wave)*16 + srow;
        int c = schunk ^ ((r >> 1) & 3);
        b_goff[s] = (size_t)(tile_n + r)*K + c*8;
    }

    const int nt = K >> 5;

    auto issue = [&](int t, int bufi) {
        const int kn = t << 5;
        #pragma unroll
        for (int s = 0; s < MI/2; ++s)
            gload_lds16(A + a_goff[s] + kn, lds_a + bufi*A_ELEMS + (s*4 + wave)*512);
        #pragma unroll
        for (int s = 0; s < 2; ++s)
            gload_lds16(Bt + b_goff[s] + kn, lds_b + bufi*B_ELEMS + (s*4 + wave)*512);
    };

    issue(0, 0);
    if (nt > 1) { issue(1, 1); wait_vm<L>(); }
    else        { wait_vm<0>(); }
    __builtin_amdgcn_s_barrier();

    int cur = 0, nx2 = 2;
    for (int t = 0; t < nt; ++t) {
        if (t + 2 < nt) issue(t + 2, nx2);

        const __hip_bfloat16* la = lds_a + cur*A_ELEMS;
        const __hip_bfloat16* lb = lds_b + cur*B_ELEMS;
        short8 afr[MI], bfr[4];
        #pragma unroll
        for (int i=0;i<MI;i++)
            afr[i] = *(const short8*)(la + (wm*(MI*16) + i*16 + fm)*32 + sw);
        #pragma unroll
        for (int j=0;j<4;j++)
            bfr[j] = *(const short8*)(lb + (wn*64 + j*16 + fm)*32 + sw);

        __builtin_amdgcn_s_setprio(1);
        #pragma unroll
        for (int i=0;i<MI;i++)
            #pragma unroll
            for (int j=0;j<4;j++)
                acc[i][j] = __builtin_amdgcn_mfma_f32_16x16x32_bf16(afr[i], bfr[j], acc[i][j], 0,0,0);
        __builtin_amdgcn_s_setprio(0);

        if (t + 1 < nt) {
            if (t + 2 < nt) wait_vm<L>();
            else            wait_vm<0>();
            __builtin_amdgcn_s_barrier();
            cur = (cur == 2) ? 0 : cur + 1;
            nx2 = (nx2 == 2) ? 0 : nx2 + 1;
        }
    }

    const int crow_base = tile_m + wm*(MI*16);
    const int ccol_base = tile_n + wn*64;
    #pragma unroll
    for (int i=0;i<MI;i++) {
        #pragma unroll
        for (int j=0;j<4;j++) {
            int c  = ccol_base + j*16 + fm;
            float bb = bias[c];
            #pragma unroll
            for (int rg=0; rg<4; rg++) {
                int r = crow_base + i*16 + q*4 + rg;
                if (r < M) {
                    float v = acc[i][j][rg] + bb;
                    if (relu) v = fmaxf(v, 0.f);
                    C[(size_t)r*ldc + c] = f2bf(v);
                }
            }
        }
    }
}

template<int MI>
__global__ __launch_bounds__(256) void gemm_bt_t(const __hip_bfloat16* __restrict__ A, int lda,
                                                 const __hip_bfloat16* __restrict__ Bt,
                                                 const float* __restrict__ bias,
                                                 __hip_bfloat16* __restrict__ C, int ldc,
                                                 int M, int K, int relu)
{
    __shared__ __align__(16) __hip_bfloat16 lds_a[3*MI*1024];
    __shared__ __align__(16) __hip_bfloat16 lds_b[3*4096];
    int2 xy = xcd_swizzle();
    gemm_bt_body<MI>(A, lda, Bt, bias, C, ldc, M, K, relu,
                     xy.x*(MI*32), xy.y*128, lds_a, lds_b);
}

// ---------------- fused GRU gate-GEMM + elementwise (r8: B-resident, barrier-free) ----------------
// r5/6/7 post-mortem: the per-step barrier convoy is structural (~49 us floor for
// that schedule family). r8 removes it: block = 256 rows x 16 channels, 512 thr
// (8 waves). The block's ENTIRE B slice (2 mats x 3 gates x 16 ch x K=256 =
// 48 KB, chunk-XOR layout; wave t stages K-step t) is loaded to LDS ONCE ->
// one barrier total. Then each wave independently computes its 32x16 tile with
// a fully-unrolled K-loop: 4 A-frag loads straight from GLOBAL (L2-resident
// panels; y-fastest XCD swizzle keeps the A slice in one XCD's L2 across its
// 16 column-visits), 6 conflict-free ds_read_b128, 12 MFMA. Zero barriers in
// the loop; compiler pipelines the independent global loads. LDS 48 KB -> 2
// blocks/CU = 16 waves/CU; launch_bounds(512,4) caps VGPR at 128.
__global__ __launch_bounds__(512, 4) void gemm_gru_fused(
    const __hip_bfloat16* __restrict__ A0,   // hatt bf16 [N,256]
    const __hip_bfloat16* __restrict__ A1,   // hprev bf16 [N,256]
    const __hip_bfloat16* __restrict__ Bt0,  // W_ih [768][256]
    const __hip_bfloat16* __restrict__ Bt1,  // W_hh [768][256]
    const float* __restrict__ b_ih, const float* __restrict__ b_hh,
    const float* __restrict__ hprev, float* __restrict__ out)
{
    // B LDS: [t 0..7][row 0..95][32 K-elems as 4 chunks of 8, chunk-XOR'd]
    __shared__ __align__(16) __hip_bfloat16 ldsb[8*96*32];   // 49152 B
    int2 xy = xcd_swizzle();          // grid (79, 16), y = 16-channel chunk
    const int tile_m = xy.x * 256;
    const int c0     = xy.y * 16;
    const int tid = threadIdx.x, wave = tid >> 6, lane = tid & 63;
    const int fm = lane & 15, q = lane >> 4;
    const int sw = (q ^ ((fm >> 1) & 3)) * 8;

    // --- B staging: wave w stages its K-step t=w, all 6 row-groups of 16 ---
    // seg (t, rg): 16 rows x 32 K = 1 KB. Lane: sub = row in group, ch = phys
    // 16B chunk; global K pre-XOR'd so linear LDS write == swizzled layout.
    {
        const int sub = lane >> 2, ch = lane & 3;
        const int t = wave;
        #pragma unroll
        for (int rg = 0; rg < 6; ++rg) {
            int mat = rg >= 3, gate = mat ? rg - 3 : rg;
            int kk = t*32 + (ch ^ ((sub >> 1) & 3))*8;
            const __hip_bfloat16* src = (mat ? Bt1 : Bt0)
                                      + (size_t)(gate*256 + c0 + sub)*256 + kk;
            gload_lds16(src, ldsb + t*3072 + rg*512);
        }
    }

    // A fragment base pointers (per-wave 32 rows; loads straight from global)
    const int rowA = tile_m + wave*32;
    const __hip_bfloat16* ap[2][2];
    #pragma unroll
    for (int m = 0; m < 2; ++m)
        #pragma unroll
        for (int rf = 0; rf < 2; ++rf)
            ap[m][rf] = (m ? A1 : A0)
                      + (size_t)min(rowA + rf*16 + fm, N_NODES-1)*256 + q*8;

    floatx4 acc[2][3][2];   // [mat][gate][row frag]
    #pragma unroll
    for (int m=0;m<2;m++)
        #pragma unroll
        for (int g=0;g<3;g++)
            #pragma unroll
            for (int rf=0;rf<2;rf++) acc[m][g][rf] = (floatx4){0.f,0.f,0.f,0.f};

    wait_vm<0>();                      // this wave's B segs written
    __builtin_amdgcn_s_barrier();      // all waves' B segs visible

    // --- barrier-free K-loop: fully unrolled, compiler pipelines loads ---
    #pragma unroll
    for (int t = 0; t < 8; ++t) {
        short8 av[2][2];
        #pragma unroll
        for (int m=0;m<2;m++)
            #pragma unroll
            for (int rf=0;rf<2;rf++)
                av[m][rf] = *(const short8*)(ap[m][rf] + t*32);

        short8 bfr[2][3];
        #pragma unroll
        for (int m=0;m<2;m++)
            #pragma unroll
            for (int g=0;g<3;g++)
                bfr[m][g] = *(const short8*)(ldsb + t*3072 + (m*3+g)*512 + fm*32 + sw);

        __builtin_amdgcn_s_setprio(1);
        #pragma unroll
        for (int m=0;m<2;m++)
            #pragma unroll
            for (int g=0;g<3;g++)
                #pragma unroll
                for (int rf=0;rf<2;rf++)
                    acc[m][g][rf] = __builtin_amdgcn_mfma_f32_16x16x32_bf16(av[m][rf], bfr[m][g], acc[m][g][rf], 0,0,0);
        __builtin_amdgcn_s_setprio(0);
    }

    // --- epilogue: GRU math (exp-based sigmoid/tanh), write fp32 out only ---
    const int c = c0 + fm;
    const float bir = b_ih[c], biz = b_ih[256+c], bin = b_ih[512+c];
    const float bhr = b_hh[c], bhz = b_hh[256+c], bhn = b_hh[512+c];
    #pragma unroll
    for (int rf=0; rf<2; ++rf) {
        #pragma unroll
        for (int rg=0; rg<4; ++rg) {
            int r = rowA + rf*16 + q*4 + rg;
            if (r < N_NODES) {
                float gir = acc[0][0][rf][rg] + bir;
                float giz = acc[0][1][rf][rg] + biz;
                float gin = acc[0][2][rf][rg] + bin;
                float ghr = acc[1][0][rf][rg] + bhr;
                float ghz = acc[1][1][rf][rg] + bhz;
                float ghn = acc[1][2][rf][rg] + bhn;
                float rr = 1.f/(1.f + __expf(-(gir + ghr)));
                float zz = 1.f/(1.f + __expf(-(giz + ghz)));
                float xn = gin + rr*ghn;
                float e2 = __expf(xn + xn);
                float nn = 1.f - 2.f/(e2 + 1.f);   // tanh(xn)
                float h  = hprev[(size_t)r*256 + c];
                out[(size_t)r*256 + c] = (1.f - zz)*nn + zz*h;
            }
        }
    }
}

// ---------------- attention scores: ONE WAVE PER NODE ----------------
__global__ __launch_bounds__(256) void score_kernel(const __hip_bfloat16* __restrict__ qkvs,
                                                    const int* __restrict__ row_ptr,
                                                    const int* __restrict__ csr_src,
                                                    float* __restrict__ score)
{
    int i = blockIdx.x*4 + (threadIdx.x >> 6);
    int lane = threadIdx.x & 63;
    int h = lane >> 4, d4 = lane & 15;
    int e0 = row_ptr[i*R_REL], e1 = row_ptr[i*R_REL + R_REL];
    ushort4 qv = *(const ushort4*)(qkvs + (size_t)i*1024 + lane*4);
    float qx=bfbits2f(qv.x), qy=bfbits2f(qv.y), qz=bfbits2f(qv.z), qw=bfbits2f(qv.w);
    float* sp = score + (size_t)h*E_EDGES;
    int j = e0;
    for (; j+2 <= e1; j += 2) {
        int s0 = csr_src[j], s1 = csr_src[j+1];
        ushort4 k0 = *(const ushort4*)(qkvs + (size_t)s0*1024 + 256 + lane*4);
        ushort4 k1 = *(const ushort4*)(qkvs + (size_t)s1*1024 + 256 + lane*4);
        float d0 = qx*bfbits2f(k0.x)+qy*bfbits2f(k0.y)+qz*bfbits2f(k0.z)+qw*bfbits2f(k0.w);
        float d1 = qx*bfbits2f(k1.x)+qy*bfbits2f(k1.y)+qz*bfbits2f(k1.z)+qw*bfbits2f(k1.w);
        #pragma unroll
        for (int o=1;o<16;o<<=1){ d0 += __shfl_xor(d0,o,64); d1 += __shfl_xor(d1,o,64); }
        if (d4 == 0) { sp[j] = d0*0.125f; sp[j+1] = d1*0.125f; }
    }
    for (; j < e1; j++) {
        int s0 = csr_src[j];
        ushort4 k0 = *(const ushort4*)(qkvs + (size_t)s0*1024 + 256 + lane*4);
        float d0 = qx*bfbits2f(k0.x)+qy*bfbits2f(k0.y)+qz*bfbits2f(k0.z)+qw*bfbits2f(k0.w);
        #pragma unroll
        for (int o=1;o<16;o<<=1) d0 += __shfl_xor(d0,o,64);
        if (d4 == 0) sp[j] = d0*0.125f;
    }
}

// ---------------- attention aggregate: ONE WAVE PER NODE, all 4 heads ----------------
__global__ __launch_bounds__(256) void attn_agg_kernel(const __hip_bfloat16* __restrict__ qkvs,
                                                       const float* __restrict__ score,
                                                       const int* __restrict__ row_ptr,
                                                       const int* __restrict__ csr_src,
                                                       __hip_bfloat16* __restrict__ hatt)
{
    int i = blockIdx.x*4 + (threadIdx.x >> 6);   // node (4 nodes per block)
    int lane = threadIdx.x & 63;
    int h  = lane >> 4;
    int d4 = lane & 15;
    int e0 = row_ptr[i*R_REL], e1 = row_ptr[i*R_REL + R_REL];
    int deg = e1 - e0;
    const float* sp = score + (size_t)h*E_EDGES + e0;

    float m = -1e30f;
    for (int j = d4; j < deg; j += 16) m = fmaxf(m, sp[j]);
    #pragma unroll
    for (int o=1;o<16;o<<=1) m = fmaxf(m, __shfl_xor(m, o, 64));

    float ssum = 0.f;
    for (int j = d4; j < deg; j += 16) ssum += __expf(sp[j] - m);
    #pragma unroll
    for (int o=1;o<16;o<<=1) ssum += __shfl_xor(ssum, o, 64);
    float inv = 1.f / fmaxf(ssum, 1e-16f);

    float ax=0.f, ay=0.f, az=0.f, aw=0.f;
    int j = 0;
    for (; j+4 <= deg; j += 4) {
        int s0=csr_src[e0+j], s1=csr_src[e0+j+1], s2=csr_src[e0+j+2], s3=csr_src[e0+j+3];
        float w0 = __expf(sp[j]   - m) * inv;
        float w1 = __expf(sp[j+1] - m) * inv;
        float w2 = __expf(sp[j+2] - m) * inv;
        float w3 = __expf(sp[j+3] - m) * inv;
        ushort4 u0 = *(const ushort4*)(qkvs + (size_t)s0*1024 + 512 + lane*4);
        ushort4 u1 = *(const ushort4*)(qkvs + (size_t)s1*1024 + 512 + lane*4);
        ushort4 u2 = *(const ushort4*)(qkvs + (size_t)s2*1024 + 512 + lane*4);
        ushort4 u3 = *(const ushort4*)(qkvs + (size_t)s3*1024 + 512 + lane*4);
        ax += w0*bfbits2f(u0.x) + w1*bfbits2f(u1.x) + w2*bfbits2f(u2.x) + w3*bfbits2f(u3.x);
        ay += w0*bfbits2f(u0.y) + w1*bfbits2f(u1.y) + w2*bfbits2f(u2.y) + w3*bfbits2f(u3.y);
        az += w0*bfbits2f(u0.z) + w1*bfbits2f(u1.z) + w2*bfbits2f(u2.z) + w3*bfbits2f(u3.z);
        aw += w0*bfbits2f(u0.w) + w1*bfbits2f(u1.w) + w2*bfbits2f(u2.w) + w3*bfbits2f(u3.w);
    }
    for (; j < deg; j++) {
        int s = csr_src[e0+j];
        float w = __expf(sp[j] - m) * inv;
        ushort4 u = *(const ushort4*)(qkvs + (size_t)s*1024 + 512 + lane*4);
        ax += w*bfbits2f(u.x); ay += w*bfbits2f(u.y);
        az += w*bfbits2f(u.z); aw += w*bfbits2f(u.w);
    }
    ushort4 sk = *(const ushort4*)(qkvs + (size_t)i*1024 + 768 + lane*4);
    uint2 w;
    w.x = pack_bf2(ax + bfbits2f(sk.x), ay + bfbits2f(sk.y));
    w.y = pack_bf2(az + bfbits2f(sk.z), aw + bfbits2f(sk.w));
    *(uint2*)(hatt + (size_t)i*256 + lane*4) = w;
}

// ---------------- launch ----------------
extern "C" void kernel_launch(void* const* d_in, const int* in_sizes, int n_in,
                              void* d_out, int out_size, void* d_ws, size_t ws_size,
                              hipStream_t stream)
{
    const float* x       = (const float*)d_in[0];
    const int* edge_index= (const int*)d_in[1];
    const int* edge_type = (const int*)d_in[2];
    const float* hprev   = (const float*)d_in[3];
    const float* W1      = (const float*)d_in[4];
    const float* root1   = (const float*)d_in[5];
    const float* b1      = (const float*)d_in[6];
    const float* W2      = (const float*)d_in[7];
    const float* root2   = (const float*)d_in[8];
    const float* b2      = (const float*)d_in[9];
    const float* Wq      = (const float*)d_in[10];
    const float* bq      = (const float*)d_in[11];
    const float* Wk      = (const float*)d_in[12];
    const float* bk      = (const float*)d_in[13];
    const float* Wv      = (const float*)d_in[14];
    const float* bv      = (const float*)d_in[15];
    const float* Wskip   = (const float*)d_in[16];
    const float* bskip   = (const float*)d_in[17];
    const float* W_ih    = (const float*)d_in[18];
    const float* b_ih    = (const float*)d_in[19];
    const float* W_hh    = (const float*)d_in[20];
    const float* b_hh    = (const float*)d_in[21];

    char* ws = (char*)d_ws;
    size_t off = 0;
    auto take = [&](size_t bytes)->char* {
        char* p = ws + off;
        off = (off + bytes + 255) & ~(size_t)255;
        return p;
    };
    int* cnt        = (int*)take((size_t)NRKEYS*4);
    int* row_ptr    = (int*)take((size_t)(NRKEYS+1)*4);
    int* cursor     = (int*)take((size_t)NRKEYS*4);
    int* csr_src    = (int*)take((size_t)E_EDGES*4);
    int* blocksum   = (int*)take((size_t)SCAN_BLOCKS*4);
    int* blockoff   = (int*)take((size_t)(SCAN_BLOCKS+1)*4);
    float* score    = (float*)take((size_t)R_REL*E_EDGES*4);
    __hip_bfloat16* B1t   = (__hip_bfloat16*)take((size_t)256*640*2);
    __hip_bfloat16* B2t   = (__hip_bfloat16*)take((size_t)256*1280*2);
    __hip_bfloat16* B3t   = (__hip_bfloat16*)take((size_t)1024*256*2);
    __hip_bfloat16* Biht  = (__hip_bfloat16*)take((size_t)768*256*2);
    __hip_bfloat16* Bhht  = (__hip_bfloat16*)take((size_t)768*256*2);
    float*          bias3 = (float*)take((size_t)1024*4);
    __hip_bfloat16* hprev_bf = (__hip_bfloat16*)take((size_t)N_NODES*256*2);
    __hip_bfloat16* xbf      = (__hip_bfloat16*)take((size_t)N_NODES*IN_F*2);
    char* P1 = take((size_t)N_NODES*640*2);
    char* P2 = take((size_t)N_NODES*1536*2);

    __hip_bfloat16* A1   = (__hip_bfloat16*)P1;   // [N,640]  dead after gemm1
    __hip_bfloat16* h2   = (__hip_bfloat16*)P1;   // [N,256]  dead after gemm3
    __hip_bfloat16* hatt = (__hip_bfloat16*)P1;   // [N,256]  read by fused GRU
    __hip_bfloat16* A2   = (__hip_bfloat16*)P2;   // [N,1280] dead after gemm2
    __hip_bfloat16* qkvs = (__hip_bfloat16*)P2;   // [N,1024] dead after attn_agg

    hipMemsetAsync(cnt, 0, (size_t)NRKEYS*4, stream);
    count_kernel<<<(E_EDGES+255)/256, 256, 0, stream>>>(edge_index, edge_type, cnt);
    scan_reduce_kernel<<<SCAN_BLOCKS, 1024, 0, stream>>>(cnt, blocksum);
    scan_sums_kernel<<<1, 128, 0, stream>>>(blocksum, blockoff);
    scan_apply_kernel<<<SCAN_BLOCKS, 1024, 0, stream>>>(cnt, blockoff, row_ptr, cursor);
    fill_kernel<<<(E_EDGES+255)/256, 256, 0, stream>>>(edge_index, edge_type, cursor, csr_src);

    make_b1t<<<(256*640+255)/256, 256, 0, stream>>>(root1, W1, B1t);
    make_b2t<<<(256*1280+255)/256, 256, 0, stream>>>(root2, W2, B2t);
    make_b3t<<<(1024*256+255)/256, 256, 0, stream>>>(Wq, Wk, Wv, Wskip, bq, bk, bv, bskip, B3t, bias3);
    cvt_f32_bf16<<<(768*256+255)/256, 256, 0, stream>>>(W_ih, Biht, 768*256);
    cvt_f32_bf16<<<(768*256+255)/256, 256, 0, stream>>>(W_hh, Bhht, 768*256);
    cvt_f32_bf16<<<(N_NODES*256+255)/256, 256, 0, stream>>>(hprev, hprev_bf, N_NODES*256);
    cvt_f32_bf16<<<(N_NODES*IN_F+255)/256, 256, 0, stream>>>(x, xbf, N_NODES*IN_F);

    agg1_kernel<<<NRKEYS/4, 256, 0, stream>>>(xbf, row_ptr, csr_src, A1);

    // h1 = relu(A1 * B1) written into A2 cols 0..255 (ldc=1280)
    dim3 g12(313, 2);
    gemm_bt_t<2><<<g12, 256, 0, stream>>>(A1, 640, B1t, b1, A2, 1280, N_NODES, 640, 1);

    agg2_kernel<<<NRKEYS/4, 256, 0, stream>>>(row_ptr, csr_src, A2);

    // h2 overwrites A1 (dead) in P1
    gemm_bt_t<2><<<g12, 256, 0, stream>>>(A2, 1280, B2t, b2, h2, 256, N_NODES, 1280, 1);

    // qkvs overwrites A2 (dead) in P2
    dim3 g3(157, 8);
    gemm_bt_t<4><<<g3, 256, 0, stream>>>(h2, 256, B3t, bias3, qkvs, 1024, N_NODES, 256, 0);

    score_kernel<<<N_NODES/4, 256, 0, stream>>>(qkvs, row_ptr, csr_src, score);
    attn_agg_kernel<<<N_NODES/4, 256, 0, stream>>>(qkvs, score, row_ptr, csr_src, hatt);

    // fused GRU gate-GEMMs + elementwise: B-resident barrier-free (256x16 tiles)
    gemm_gru_fused<<<dim3(79, 16), 512, 0, stream>>>(hatt, hprev_bf, Biht, Bhht,
                                                     b_ih, b_hh, hprev, (float*)d_out);
}

// Round 9
// 415.596 us; speedup vs baseline: 1.0445x; 1.0370x over previous
//
#include <hip/hip_runtime.h>
#include <hip/hip_bf16.h>
#include <stdint.h>

#define N_NODES 20000
#define E_EDGES 320000
#define IN_F    128
#define HIDF    256
#define R_REL   4
#define NRKEYS  (N_NODES*R_REL)   // 80000
#define SCAN_BLOCKS 80            // 80*1024 = 81920 >= NRKEYS

typedef __attribute__((ext_vector_type(8))) short  short8;
typedef __attribute__((ext_vector_type(4))) float  floatx4;

__device__ __forceinline__ float bf2f(__hip_bfloat16 v){ return __bfloat162float(v); }
__device__ __forceinline__ __hip_bfloat16 f2bf(float v){ return __float2bfloat16(v); }
__device__ __forceinline__ float bfbits2f(unsigned short u){ return __uint_as_float(((unsigned)u)<<16); }
__device__ __forceinline__ unsigned short f2bfbits(float v){
    __hip_bfloat16 h = __float2bfloat16(v);
    return *(unsigned short*)&h;
}
__device__ __forceinline__ unsigned pack_bf2(float a, float b){
    return (unsigned)f2bfbits(a) | ((unsigned)f2bfbits(b) << 16);
}

// async global->LDS, 16B per lane. LDS dest is WAVE-UNIFORM base (+lane*16 by HW);
// global src is per-lane (pre-swizzled to implement the LDS XOR layout).
__device__ __forceinline__ void gload_lds16(const void* g, void* l)
{
    __builtin_amdgcn_global_load_lds((const __attribute__((address_space(1))) void*)g,
                                     (__attribute__((address_space(3))) void*)l, 16, 0, 0);
}

template<int N>
__device__ __forceinline__ void wait_vm()
{
    if constexpr (N == 0)      asm volatile("s_waitcnt vmcnt(0)" ::: "memory");
    else if constexpr (N == 3) asm volatile("s_waitcnt vmcnt(3)" ::: "memory");
    else if constexpr (N == 4) asm volatile("s_waitcnt vmcnt(4)" ::: "memory");
    else if constexpr (N == 5) asm volatile("s_waitcnt vmcnt(5)" ::: "memory");
    else                       asm volatile("s_waitcnt vmcnt(0)" ::: "memory");
}

// bijective XCD-chunked swizzle (m204 formula). Verified r2: FETCH 63.6->17.3 MB.
// GEMM-structure history: r3 quad-buffer depth-3 lost to occupancy; r4 no-LDS
// register GEMM lost to per-wave L2 latency; r2 triple-buffer / 2-in-flight /
// vmcnt(L) is the measured optimum for long-K. Fused-GRU history: r5-r8 span
// barrier-convoy AND barrier-free schedules, all converge ~49-52 us -> the op
// is gather-bound at its ~49 us floor; r7 variant (48.9) kept as final.
__device__ __forceinline__ int2 xcd_swizzle()
{
    int gx = gridDim.x, gy = gridDim.y;
    int nwg = gx * gy;
    int lin = blockIdx.x + gx * blockIdx.y;
    int q = nwg >> 3, r = nwg & 7;
    int k = lin & 7, i = lin >> 3;
    int j = (k < r ? k*(q+1) : r*(q+1) + (k-r)*q) + i;
    return make_int2(j / gy, j % gy);   // (x tile, y tile), y fastest
}

// ---------------- CSR build ----------------
__global__ void count_kernel(const int* __restrict__ ei, const int* __restrict__ et,
                             int* __restrict__ cnt)
{
    int e = blockIdx.x*256 + threadIdx.x;
    if (e >= E_EDGES) return;
    int dst = ei[E_EDGES + e];
    atomicAdd(&cnt[dst*R_REL + et[e]], 1);
}

__global__ __launch_bounds__(1024) void scan_reduce_kernel(const int* __restrict__ cnt,
                                                           int* __restrict__ blocksum)
{
    int ix = blockIdx.x*1024 + threadIdx.x;
    int v = (ix < NRKEYS) ? cnt[ix] : 0;
    #pragma unroll
    for (int o=32;o>0;o>>=1) v += __shfl_xor(v, o, 64);
    __shared__ int wsum[16];
    int wave = threadIdx.x >> 6, lane = threadIdx.x & 63;
    if (lane == 0) wsum[wave] = v;
    __syncthreads();
    if (threadIdx.x == 0) {
        int s = 0;
        #pragma unroll
        for (int w=0;w<16;w++) s += wsum[w];
        blocksum[blockIdx.x] = s;
    }
}

__global__ __launch_bounds__(128) void scan_sums_kernel(const int* __restrict__ blocksum,
                                                        int* __restrict__ blockoff)
{
    __shared__ int s[128];
    int t = threadIdx.x;
    int v = (t < SCAN_BLOCKS) ? blocksum[t] : 0;
    s[t] = v; __syncthreads();
    for (int off=1; off<128; off<<=1) {
        int u = (t>=off) ? s[t-off] : 0;
        __syncthreads();
        s[t] += u;
        __syncthreads();
    }
    if (t < SCAN_BLOCKS) blockoff[t] = s[t] - v;   // exclusive
}

__global__ __launch_bounds__(1024) void scan_apply_kernel(const int* __restrict__ cnt,
                                                          const int* __restrict__ blockoff,
                                                          int* __restrict__ row_ptr,
                                                          int* __restrict__ cursor)
{
    __shared__ int s[1024];
    int t = threadIdx.x;
    int ix = blockIdx.x*1024 + t;
    int v = (ix < NRKEYS) ? cnt[ix] : 0;
    s[t] = v; __syncthreads();
    for (int off=1; off<1024; off<<=1) {
        int u = (t>=off) ? s[t-off] : 0;
        __syncthreads();
        s[t] += u;
        __syncthreads();
    }
    if (ix < NRKEYS) {
        int excl = blockoff[blockIdx.x] + s[t] - v;
        row_ptr[ix] = excl;
        cursor[ix]  = excl;
        if (ix == NRKEYS-1) row_ptr[NRKEYS] = excl + v;
    }
}

__global__ void fill_kernel(const int* __restrict__ ei, const int* __restrict__ et,
                            int* __restrict__ cursor, int* __restrict__ csr_src)
{
    int e = blockIdx.x*256 + threadIdx.x;
    if (e >= E_EDGES) return;
    int src = ei[e];
    int dst = ei[E_EDGES + e];
    int key = dst*R_REL + et[e];
    int pos = atomicAdd(&cursor[key], 1);
    csr_src[pos] = src;
}

// ---------------- weight prep: fp32 sources -> bf16 B^T = [Nout][K] ----------------
__global__ void make_b1t(const float* __restrict__ root1,
                         const float* __restrict__ W1,
                         __hip_bfloat16* __restrict__ B1t)
{
    int idx = blockIdx.x*256 + threadIdx.x;         // n*640 + k
    if (idx >= 256*640) return;
    int n = idx / 640, k = idx % 640;
    float v;
    if (k < 128) v = root1[k*256 + n];
    else         v = W1[(k-128)*256 + n];           // W1 contiguous [R*128][256]
    B1t[idx] = f2bf(v);
}

__global__ void make_b2t(const float* __restrict__ root2,
                         const float* __restrict__ W2,
                         __hip_bfloat16* __restrict__ B2t)
{
    int idx = blockIdx.x*256 + threadIdx.x;         // n*1280 + k
    if (idx >= 256*1280) return;
    int n = idx / 1280, k = idx % 1280;
    float v;
    if (k < 256) v = root2[k*256 + n];
    else         v = W2[(k-256)*256 + n];           // W2 contiguous [R*256][256]
    B2t[idx] = f2bf(v);
}

__global__ void make_b3t(const float* __restrict__ Wq, const float* __restrict__ Wk,
                         const float* __restrict__ Wv, const float* __restrict__ Wsk,
                         const float* __restrict__ bq, const float* __restrict__ bk,
                         const float* __restrict__ bv, const float* __restrict__ bsk,
                         __hip_bfloat16* __restrict__ B3t, float* __restrict__ bias3)
{
    int idx = blockIdx.x*256 + threadIdx.x;         // n*256 + k, n<1024
    if (idx >= 1024*256) return;
    int n = idx / 256, k = idx % 256;
    int g = n >> 8, nn = n & 255;
    const float* W = (g==0)?Wq:(g==1)?Wk:(g==2)?Wv:Wsk;
    B3t[idx] = f2bf(W[k*256 + nn]);
    if (k == 0) {
        const float* B = (g==0)?bq:(g==1)?bk:(g==2)?bv:bsk;
        bias3[n] = B[nn];
    }
}

// generic fp32 -> bf16 elementwise convert (layout-preserving)
__global__ void cvt_f32_bf16(const float* __restrict__ in, __hip_bfloat16* __restrict__ out, int n)
{
    int i = blockIdx.x*256 + threadIdx.x;
    if (i < n) out[i] = f2bf(in[i]);
}

// ---------------- RGCN aggregation: one WAVE per (node,rel) key, unroll-4 ILP ----------------
// agg1 uses bf16 x (r7-proven, absmax unchanged): lane covers dims 2*lane..2*lane+1
// via uint (2 bf16, 4 B) -> half the gather bytes of fp32 at identical ILP.
__global__ __launch_bounds__(256) void agg1_kernel(const __hip_bfloat16* __restrict__ xbf,
                                                   const int* __restrict__ row_ptr,
                                                   const int* __restrict__ csr_src,
                                                   __hip_bfloat16* __restrict__ A1)
{
    int b = blockIdx.x*4 + (threadIdx.x >> 6);   // key = i*4 + r
    int lane = threadIdx.x & 63;
    int i = b >> 2, r = b & 3;
    int e0 = row_ptr[b], e1 = row_ptr[b+1];
    float sx0=0.f,sy0=0.f, sx1=0.f,sy1=0.f, sx2=0.f,sy2=0.f, sx3=0.f,sy3=0.f;
    int e = e0;
    for (; e+4 <= e1; e += 4) {
        int i0=csr_src[e], i1=csr_src[e+1], i2=csr_src[e+2], i3=csr_src[e+3];
        unsigned u0 = *(const unsigned*)(xbf + (size_t)i0*IN_F + lane*2);
        unsigned u1 = *(const unsigned*)(xbf + (size_t)i1*IN_F + lane*2);
        unsigned u2 = *(const unsigned*)(xbf + (size_t)i2*IN_F + lane*2);
        unsigned u3 = *(const unsigned*)(xbf + (size_t)i3*IN_F + lane*2);
        sx0+=bfbits2f((unsigned short)u0); sy0+=bfbits2f((unsigned short)(u0>>16));
        sx1+=bfbits2f((unsigned short)u1); sy1+=bfbits2f((unsigned short)(u1>>16));
        sx2+=bfbits2f((unsigned short)u2); sy2+=bfbits2f((unsigned short)(u2>>16));
        sx3+=bfbits2f((unsigned short)u3); sy3+=bfbits2f((unsigned short)(u3>>16));
    }
    for (; e < e1; e++) {
        int i0 = csr_src[e];
        unsigned u = *(const unsigned*)(xbf + (size_t)i0*IN_F + lane*2);
        sx0+=bfbits2f((unsigned short)u); sy0+=bfbits2f((unsigned short)(u>>16));
    }
    float sx = (sx0+sx1)+(sx2+sx3);
    float sy = (sy0+sy1)+(sy2+sy3);
    float inv = (e1>e0) ? 1.f/(float)(e1-e0) : 0.f;
    *(unsigned*)(A1 + (size_t)i*640 + 128 + r*128 + lane*2) = pack_bf2(sx*inv, sy*inv);
    if (r == 0)   // root copy: already bf16, straight 4B copy
        *(unsigned*)(A1 + (size_t)i*640 + lane*2) = *(const unsigned*)(xbf + (size_t)i*IN_F + lane*2);
}

// agg2: h1 bf16 in A2 cols 0..255 (ld 1280); lane covers dims 4*lane..4*lane+3 (8 B).
__global__ __launch_bounds__(256) void agg2_kernel(const int* __restrict__ row_ptr,
                                                   const int* __restrict__ csr_src,
                                                   __hip_bfloat16* __restrict__ A2)
{
    int b = blockIdx.x*4 + (threadIdx.x >> 6);
    int lane = threadIdx.x & 63;
    int i = b >> 2, r = b & 3;
    int e0 = row_ptr[b], e1 = row_ptr[b+1];
    float a0=0.f,a1=0.f,a2=0.f,a3=0.f;
    float b0=0.f,b1=0.f,b2=0.f,b3=0.f;
    float c0=0.f,c1=0.f,c2=0.f,c3=0.f;
    float d0=0.f,d1=0.f,d2=0.f,d3=0.f;
    int e = e0;
    for (; e+4 <= e1; e += 4) {
        int i0=csr_src[e], i1=csr_src[e+1], i2=csr_src[e+2], i3=csr_src[e+3];
        ushort4 u0 = *(const ushort4*)(A2 + (size_t)i0*1280 + lane*4);
        ushort4 u1 = *(const ushort4*)(A2 + (size_t)i1*1280 + lane*4);
        ushort4 u2 = *(const ushort4*)(A2 + (size_t)i2*1280 + lane*4);
        ushort4 u3 = *(const ushort4*)(A2 + (size_t)i3*1280 + lane*4);
        a0+=bfbits2f(u0.x); a1+=bfbits2f(u0.y); a2+=bfbits2f(u0.z); a3+=bfbits2f(u0.w);
        b0+=bfbits2f(u1.x); b1+=bfbits2f(u1.y); b2+=bfbits2f(u1.z); b3+=bfbits2f(u1.w);
        c0+=bfbits2f(u2.x); c1+=bfbits2f(u2.y); c2+=bfbits2f(u2.z); c3+=bfbits2f(u2.w);
        d0+=bfbits2f(u3.x); d1+=bfbits2f(u3.y); d2+=bfbits2f(u3.z); d3+=bfbits2f(u3.w);
    }
    for (; e < e1; e++) {
        int i0 = csr_src[e];
        ushort4 u = *(const ushort4*)(A2 + (size_t)i0*1280 + lane*4);
        a0+=bfbits2f(u.x); a1+=bfbits2f(u.y); a2+=bfbits2f(u.z); a3+=bfbits2f(u.w);
    }
    float s0=(a0+b0)+(c0+d0), s1=(a1+b1)+(c1+d1), s2=(a2+b2)+(c2+d2), s3=(a3+b3)+(c3+d3);
    float inv = (e1>e0) ? 1.f/(float)(e1-e0) : 0.f;
    uint2 w;
    w.x = pack_bf2(s0*inv, s1*inv);
    w.y = pack_bf2(s2*inv, s3*inv);
    *(uint2*)(A2 + (size_t)i*1280 + 256 + r*256 + lane*4) = w;
}

// ---------------- LDS-pipelined GEMM (r2 config: best measured) ----------------
template<int MI>
__device__ __forceinline__ void gemm_bt_body(const __hip_bfloat16* __restrict__ A, int lda,
                                             const __hip_bfloat16* __restrict__ Bt,
                                             const float* __restrict__ bias,
                                             __hip_bfloat16* __restrict__ C, int ldc,
                                             int M, int K, int relu,
                                             int tile_m, int tile_n,
                                             __hip_bfloat16* lds_a, __hip_bfloat16* lds_b)
{
    constexpr int A_ELEMS = MI*1024;
    constexpr int B_ELEMS = 4096;
    constexpr int L = MI/2 + 2;
    const int tid  = threadIdx.x;
    const int wave = tid >> 6;
    const int lane = tid & 63;
    const int wm = wave >> 1, wn = wave & 1;
    const int fm = lane & 15;
    const int q  = lane >> 4;
    const int sw = (q ^ ((fm >> 1) & 3)) * 8;

    floatx4 acc[MI][4];
    #pragma unroll
    for (int i=0;i<MI;i++)
        #pragma unroll
        for (int j=0;j<4;j++) acc[i][j] = (floatx4){0.f,0.f,0.f,0.f};

    const int srow   = lane >> 2;
    const int schunk = lane & 3;
    size_t a_goff[MI/2];
    #pragma unroll
    for (int s = 0; s < MI/2; ++s) {
        int r = (s*4 + wave)*16 + srow;
        int c = schunk ^ ((r >> 1) & 3);
        a_goff[s] = (size_t)min(tile_m + r, M-1)*lda + c*8;
    }
    size_t b_goff[2];
    #pragma unroll
    for (int s = 0; s < 2; ++s) {
        int r = (s*4 + wave)*16 + srow;
        int c = schunk ^ ((r >> 1) & 3);
        b_goff[s] = (size_t)(tile_n + r)*K + c*8;
    }

    const int nt = K >> 5;

    auto issue = [&](int t, int bufi) {
        const int kn = t << 5;
        #pragma unroll
        for (int s = 0; s < MI/2; ++s)
            gload_lds16(A + a_goff[s] + kn, lds_a + bufi*A_ELEMS + (s*4 + wave)*512);
        #pragma unroll
        for (int s = 0; s < 2; ++s)
            gload_lds16(Bt + b_goff[s] + kn, lds_b + bufi*B_ELEMS + (s*4 + wave)*512);
    };

    issue(0, 0);
    if (nt > 1) { issue(1, 1); wait_vm<L>(); }
    else        { wait_vm<0>(); }
    __builtin_amdgcn_s_barrier();

    int cur = 0, nx2 = 2;
    for (int t = 0; t < nt; ++t) {
        if (t + 2 < nt) issue(t + 2, nx2);

        const __hip_bfloat16* la = lds_a + cur*A_ELEMS;
        const __hip_bfloat16* lb = lds_b + cur*B_ELEMS;
        short8 afr[MI], bfr[4];
        #pragma unroll
        for (int i=0;i<MI;i++)
            afr[i] = *(const short8*)(la + (wm*(MI*16) + i*16 + fm)*32 + sw);
        #pragma unroll
        for (int j=0;j<4;j++)
            bfr[j] = *(const short8*)(lb + (wn*64 + j*16 + fm)*32 + sw);

        __builtin_amdgcn_s_setprio(1);
        #pragma unroll
        for (int i=0;i<MI;i++)
            #pragma unroll
            for (int j=0;j<4;j++)
                acc[i][j] = __builtin_amdgcn_mfma_f32_16x16x32_bf16(afr[i], bfr[j], acc[i][j], 0,0,0);
        __builtin_amdgcn_s_setprio(0);

        if (t + 1 < nt) {
            if (t + 2 < nt) wait_vm<L>();
            else            wait_vm<0>();
            __builtin_amdgcn_s_barrier();
            cur = (cur == 2) ? 0 : cur + 1;
            nx2 = (nx2 == 2) ? 0 : nx2 + 1;
        }
    }

    const int crow_base = tile_m + wm*(MI*16);
    const int ccol_base = tile_n + wn*64;
    #pragma unroll
    for (int i=0;i<MI;i++) {
        #pragma unroll
        for (int j=0;j<4;j++) {
            int c  = ccol_base + j*16 + fm;
            float bb = bias[c];
            #pragma unroll
            for (int rg=0; rg<4; rg++) {
                int r = crow_base + i*16 + q*4 + rg;
                if (r < M) {
                    float v = acc[i][j][rg] + bb;
                    if (relu) v = fmaxf(v, 0.f);
                    C[(size_t)r*ldc + c] = f2bf(v);
                }
            }
        }
    }
}

template<int MI>
__global__ __launch_bounds__(256) void gemm_bt_t(const __hip_bfloat16* __restrict__ A, int lda,
                                                 const __hip_bfloat16* __restrict__ Bt,
                                                 const float* __restrict__ bias,
                                                 __hip_bfloat16* __restrict__ C, int ldc,
                                                 int M, int K, int relu)
{
    __shared__ __align__(16) __hip_bfloat16 lds_a[3*MI*1024];
    __shared__ __align__(16) __hip_bfloat16 lds_b[3*4096];
    int2 xy = xcd_swizzle();
    gemm_bt_body<MI>(A, lda, Bt, bias, C, ldc, M, K, relu,
                     xy.x*(MI*32), xy.y*128, lds_a, lds_b);
}

// ---------------- fused GRU gate-GEMM + elementwise (r7 final: best measured 48.9us) ----------------
// r5-r8 explored 4 schedules (barrier-convoy x3, barrier-free B-resident); all
// land 49-52 us -> op is at its gather-bound floor. Keeping r7: 512 thr, 128x64
// tile, dbuf 80 KB LDS, 2 batches in flight, vmcnt(5). Writes only fp32 out.
__global__ __launch_bounds__(512) void gemm_gru_fused(
    const __hip_bfloat16* __restrict__ A0,   // hatt bf16 [N,256]
    const __hip_bfloat16* __restrict__ A1,   // hprev bf16 [N,256]
    const __hip_bfloat16* __restrict__ Bt0,  // W_ih [768][256]
    const __hip_bfloat16* __restrict__ Bt1,  // W_hh [768][256]
    const float* __restrict__ b_ih, const float* __restrict__ b_hh,
    const float* __restrict__ hprev, float* __restrict__ out)
{
    constexpr int BUF_ELEMS = 20480;  // A 256x32 (8192) + B 384x32 (12288)
    __shared__ __align__(16) __hip_bfloat16 lds[2*BUF_ELEMS];   // 80 KB
    int2 xy = xcd_swizzle();          // grid (157, 4), y = 64-channel chunk
    const int tile_m = xy.x * 128;
    const int c0     = xy.y * 64;
    const int tid = threadIdx.x, wave = tid >> 6, lane = tid & 63;
    const int wm = wave >> 1, wn = wave & 1;     // 4x2 wave grid: 32 rows x 32 ch
    const int fm = lane & 15, q = lane >> 4;
    const int sw = (q ^ ((fm >> 1) & 3)) * 8;

    const int sub = lane >> 2, ch = lane & 3;
    const __hip_bfloat16* gsrc[5];
    int dstoff[5];
    #pragma unroll
    for (int s = 0; s < 5; ++s) {
        int seg = wave*5 + s;                        // 0..39
        if (seg < 16) {
            int fr = seg*16 + sub;                   // 0..255
            int mat = fr >> 7, rl = fr & 127;
            int c = ch ^ ((fr >> 1) & 3);
            int grow = min(tile_m + rl, N_NODES-1);
            gsrc[s] = (mat ? A1 : A0) + (size_t)grow*256 + c*8;
            dstoff[s] = seg*512;
        } else {
            int fs = seg - 16;
            int fr = fs*16 + sub;                    // 0..383
            int grp = fr >> 6, ri = fr & 63;         // grp = mat*3 + gate
            int mat = grp >= 3, gate = mat ? grp-3 : grp;
            int c = ch ^ ((fr >> 1) & 3);
            int grow = gate*256 + c0 + ri;
            gsrc[s] = (mat ? Bt1 : Bt0) + (size_t)grow*256 + c*8;
            dstoff[s] = 8192 + fs*512;
        }
    }

    floatx4 acc[2][3][2][2];   // [mat][gate][row frag][col frag]
    #pragma unroll
    for (int m=0;m<2;m++)
        #pragma unroll
        for (int g=0;g<3;g++)
            #pragma unroll
            for (int i=0;i<2;i++)
                #pragma unroll
                for (int f=0;f<2;f++) acc[m][g][i][f] = (floatx4){0.f,0.f,0.f,0.f};

    auto issue = [&](int t, int bufi) {
        const int kn = t << 5;
        #pragma unroll
        for (int s = 0; s < 5; ++s)
            gload_lds16(gsrc[s] + kn, lds + bufi*BUF_ELEMS + dstoff[s]);
    };

    issue(0, 0);
    issue(1, 1);
    wait_vm<5>();                      // batch 0 landed; batch 1 in flight
    __builtin_amdgcn_s_barrier();

    #pragma unroll 1
    for (int t = 0; t < 8; ++t) {
        const __hip_bfloat16* lb = lds + (t & 1)*BUF_ELEMS;
        short8 af[2][2], bfr[2][3][2];
        #pragma unroll
        for (int m=0;m<2;m++)
            #pragma unroll
            for (int i=0;i<2;i++)
                af[m][i] = *(const short8*)(lb + (m*128 + wm*32 + i*16 + fm)*32 + sw);
        #pragma unroll
        for (int m=0;m<2;m++)
            #pragma unroll
            for (int g=0;g<3;g++)
                #pragma unroll
                for (int f=0;f<2;f++)
                    bfr[m][g][f] = *(const short8*)(lb + 8192 + (((m*3+g)*64 + wn*32 + f*16 + fm)*32) + sw);

        __builtin_amdgcn_s_setprio(1);
        #pragma unroll
        for (int m=0;m<2;m++)
            #pragma unroll
            for (int g=0;g<3;g++)
                #pragma unroll
                for (int i=0;i<2;i++)
                    #pragma unroll
                    for (int f=0;f<2;f++)
                        acc[m][g][i][f] = __builtin_amdgcn_mfma_f32_16x16x32_bf16(af[m][i], bfr[m][g][f], acc[m][g][i][f], 0,0,0);
        __builtin_amdgcn_s_setprio(0);

        if (t + 1 < 8) {
            __builtin_amdgcn_s_barrier();            // all waves done reading buf[t&1]
            if (t + 2 < 8) { issue(t + 2, t & 1); wait_vm<5>(); }  // t+1 landed, t+2 in flight
            else           wait_vm<0>();                           // tail drain
            __builtin_amdgcn_s_barrier();            // everyone's batch t+1 visible
        }
    }

    // epilogue: GRU math (exp-based sigmoid/tanh), write fp32 out only
    #pragma unroll
    for (int f=0; f<2; ++f) {
        int c = c0 + wn*32 + f*16 + fm;
        float bir = b_ih[c], biz = b_ih[256+c], bin = b_ih[512+c];
        float bhr = b_hh[c], bhz = b_hh[256+c], bhn = b_hh[512+c];
        #pragma unroll
        for (int i=0; i<2; ++i) {
            #pragma unroll
            for (int rg=0; rg<4; ++rg) {
                int r = tile_m + wm*32 + i*16 + q*4 + rg;
                if (r < N_NODES) {
                    float gir = acc[0][0][i][f][rg] + bir;
                    float giz = acc[0][1][i][f][rg] + biz;
                    float gin = acc[0][2][i][f][rg] + bin;
                    float ghr = acc[1][0][i][f][rg] + bhr;
                    float ghz = acc[1][1][i][f][rg] + bhz;
                    float ghn = acc[1][2][i][f][rg] + bhn;
                    float rr = 1.f/(1.f + __expf(-(gir + ghr)));
                    float zz = 1.f/(1.f + __expf(-(giz + ghz)));
                    float xn = gin + rr*ghn;
                    float e2 = __expf(xn + xn);
                    float nn = 1.f - 2.f/(e2 + 1.f);   // tanh(xn)
                    float h  = hprev[(size_t)r*256 + c];
                    out[(size_t)r*256 + c] = (1.f - zz)*nn + zz*h;
                }
            }
        }
    }
}

// ---------------- fused attention (r9): online softmax, ONE pass over edges ----------------
// Replaces score_kernel + attn_agg_kernel. Mechanism: the split kernels gathered
// the SAME qkvs rows twice (K-pass, then V-pass ~40us later after L2 eviction ->
// refetch from L3/HBM). Fused: per edge, K (+256) and V (+512) of the same row
// are gathered back-to-back (second segment hits while row is hot), with online
// softmax (running max m, rescale on max-update -> mathematically identical to
// global-max softmax). Also eliminates the score array write + 3x read and one
// full CSR walk. One wave per node; lane = head h (lane>>4), dims 4*(lane&15)..;
// unroll-2 keeps 4 gathers in flight.
__global__ __launch_bounds__(256) void attn_fused_kernel(
    const __hip_bfloat16* __restrict__ qkvs,
    const int* __restrict__ row_ptr,
    const int* __restrict__ csr_src,
    __hip_bfloat16* __restrict__ hatt)
{
    int i = blockIdx.x*4 + (threadIdx.x >> 6);   // node (4 nodes per block)
    int lane = threadIdx.x & 63;
    int e0 = row_ptr[i*R_REL], e1 = row_ptr[i*R_REL + R_REL];

    ushort4 qv = *(const ushort4*)(qkvs + (size_t)i*1024 + lane*4);
    float qx=bfbits2f(qv.x), qy=bfbits2f(qv.y), qz=bfbits2f(qv.z), qw=bfbits2f(qv.w);

    float m = -1e30f, denom = 0.f;
    float ax=0.f, ay=0.f, az=0.f, aw=0.f;

    int j = e0;
    for (; j+2 <= e1; j += 2) {
        int s0 = csr_src[j], s1 = csr_src[j+1];
        const __hip_bfloat16* r0 = qkvs + (size_t)s0*1024;
        const __hip_bfloat16* r1 = qkvs + (size_t)s1*1024;
        ushort4 k0 = *(const ushort4*)(r0 + 256 + lane*4);
        ushort4 k1 = *(const ushort4*)(r1 + 256 + lane*4);
        ushort4 v0 = *(const ushort4*)(r0 + 512 + lane*4);   // issued before reduce
        ushort4 v1 = *(const ushort4*)(r1 + 512 + lane*4);
        float d0 = qx*bfbits2f(k0.x)+qy*bfbits2f(k0.y)+qz*bfbits2f(k0.z)+qw*bfbits2f(k0.w);
        float d1 = qx*bfbits2f(k1.x)+qy*bfbits2f(k1.y)+qz*bfbits2f(k1.z)+qw*bfbits2f(k1.w);
        #pragma unroll
        for (int o=1;o<16;o<<=1){ d0 += __shfl_xor(d0,o,64); d1 += __shfl_xor(d1,o,64); }
        d0 *= 0.125f; d1 *= 0.125f;     // 1/sqrt(64)
        float mx = fmaxf(d0, d1);
        if (mx > m) {                    // rescale (rare after warm-up)
            float sc = __expf(m - mx);
            ax*=sc; ay*=sc; az*=sc; aw*=sc; denom*=sc;
            m = mx;
        }
        float w0 = __expf(d0 - m), w1 = __expf(d1 - m);
        denom += w0 + w1;
        ax += w0*bfbits2f(v0.x) + w1*bfbits2f(v1.x);
        ay += w0*bfbits2f(v0.y) + w1*bfbits2f(v1.y);
        az += w0*bfbits2f(v0.z) + w1*bfbits2f(v1.z);
        aw += w0*bfbits2f(v0.w) + w1*bfbits2f(v1.w);
    }
    for (; j < e1; ++j) {
        int s0 = csr_src[j];
        const __hip_bfloat16* r0 = qkvs + (size_t)s0*1024;
        ushort4 k0 = *(const ushort4*)(r0 + 256 + lane*4);
        ushort4 v0 = *(const ushort4*)(r0 + 512 + lane*4);
        float d0 = qx*bfbits2f(k0.x)+qy*bfbits2f(k0.y)+qz*bfbits2f(k0.z)+qw*bfbits2f(k0.w);
        #pragma unroll
        for (int o=1;o<16;o<<=1) d0 += __shfl_xor(d0,o,64);
        d0 *= 0.125f;
        if (d0 > m) {
            float sc = __expf(m - d0);
            ax*=sc; ay*=sc; az*=sc; aw*=sc; denom*=sc;
            m = d0;
        }
        float w0 = __expf(d0 - m);
        denom += w0;
        ax += w0*bfbits2f(v0.x); ay += w0*bfbits2f(v0.y);
        az += w0*bfbits2f(v0.z); aw += w0*bfbits2f(v0.w);
    }

    float inv = 1.f / fmaxf(denom, 1e-16f);
    ushort4 sk = *(const ushort4*)(qkvs + (size_t)i*1024 + 768 + lane*4);
    uint2 w;
    w.x = pack_bf2(ax*inv + bfbits2f(sk.x), ay*inv + bfbits2f(sk.y));
    w.y = pack_bf2(az*inv + bfbits2f(sk.z), aw*inv + bfbits2f(sk.w));
    *(uint2*)(hatt + (size_t)i*256 + lane*4) = w;
}

// ---------------- launch ----------------
extern "C" void kernel_launch(void* const* d_in, const int* in_sizes, int n_in,
                              void* d_out, int out_size, void* d_ws, size_t ws_size,
                              hipStream_t stream)
{
    const float* x       = (const float*)d_in[0];
    const int* edge_index= (const int*)d_in[1];
    const int* edge_type = (const int*)d_in[2];
    const float* hprev   = (const float*)d_in[3];
    const float* W1      = (const float*)d_in[4];
    const float* root1   = (const float*)d_in[5];
    const float* b1      = (const float*)d_in[6];
    const float* W2      = (const float*)d_in[7];
    const float* root2   = (const float*)d_in[8];
    const float* b2      = (const float*)d_in[9];
    const float* Wq      = (const float*)d_in[10];
    const float* bq      = (const float*)d_in[11];
    const float* Wk      = (const float*)d_in[12];
    const float* bk      = (const float*)d_in[13];
    const float* Wv      = (const float*)d_in[14];
    const float* bv      = (const float*)d_in[15];
    const float* Wskip   = (const float*)d_in[16];
    const float* bskip   = (const float*)d_in[17];
    const float* W_ih    = (const float*)d_in[18];
    const float* b_ih    = (const float*)d_in[19];
    const float* W_hh    = (const float*)d_in[20];
    const float* b_hh    = (const float*)d_in[21];

    char* ws = (char*)d_ws;
    size_t off = 0;
    auto take = [&](size_t bytes)->char* {
        char* p = ws + off;
        off = (off + bytes + 255) & ~(size_t)255;
        return p;
    };
    int* cnt        = (int*)take((size_t)NRKEYS*4);
    int* row_ptr    = (int*)take((size_t)(NRKEYS+1)*4);
    int* cursor     = (int*)take((size_t)NRKEYS*4);
    int* csr_src    = (int*)take((size_t)E_EDGES*4);
    int* blocksum   = (int*)take((size_t)SCAN_BLOCKS*4);
    int* blockoff   = (int*)take((size_t)(SCAN_BLOCKS+1)*4);
    __hip_bfloat16* B1t   = (__hip_bfloat16*)take((size_t)256*640*2);
    __hip_bfloat16* B2t   = (__hip_bfloat16*)take((size_t)256*1280*2);
    __hip_bfloat16* B3t   = (__hip_bfloat16*)take((size_t)1024*256*2);
    __hip_bfloat16* Biht  = (__hip_bfloat16*)take((size_t)768*256*2);
    __hip_bfloat16* Bhht  = (__hip_bfloat16*)take((size_t)768*256*2);
    float*          bias3 = (float*)take((size_t)1024*4);
    __hip_bfloat16* hprev_bf = (__hip_bfloat16*)take((size_t)N_NODES*256*2);
    __hip_bfloat16* xbf      = (__hip_bfloat16*)take((size_t)N_NODES*IN_F*2);
    char* P1 = take((size_t)N_NODES*640*2);
    char* P2 = take((size_t)N_NODES*1536*2);

    __hip_bfloat16* A1   = (__hip_bfloat16*)P1;   // [N,640]  dead after gemm1
    __hip_bfloat16* h2   = (__hip_bfloat16*)P1;   // [N,256]  dead after gemm3
    __hip_bfloat16* hatt = (__hip_bfloat16*)P1;   // [N,256]  read by fused GRU
    __hip_bfloat16* A2   = (__hip_bfloat16*)P2;   // [N,1280] dead after gemm2
    __hip_bfloat16* qkvs = (__hip_bfloat16*)P2;   // [N,1024] dead after attn_fused

    hipMemsetAsync(cnt, 0, (size_t)NRKEYS*4, stream);
    count_kernel<<<(E_EDGES+255)/256, 256, 0, stream>>>(edge_index, edge_type, cnt);
    scan_reduce_kernel<<<SCAN_BLOCKS, 1024, 0, stream>>>(cnt, blocksum);
    scan_sums_kernel<<<1, 128, 0, stream>>>(blocksum, blockoff);
    scan_apply_kernel<<<SCAN_BLOCKS, 1024, 0, stream>>>(cnt, blockoff, row_ptr, cursor);
    fill_kernel<<<(E_EDGES+255)/256, 256, 0, stream>>>(edge_index, edge_type, cursor, csr_src);

    make_b1t<<<(256*640+255)/256, 256, 0, stream>>>(root1, W1, B1t);
    make_b2t<<<(256*1280+255)/256, 256, 0, stream>>>(root2, W2, B2t);
    make_b3t<<<(1024*256+255)/256, 256, 0, stream>>>(Wq, Wk, Wv, Wskip, bq, bk, bv, bskip, B3t, bias3);
    cvt_f32_bf16<<<(768*256+255)/256, 256, 0, stream>>>(W_ih, Biht, 768*256);
    cvt_f32_bf16<<<(768*256+255)/256, 256, 0, stream>>>(W_hh, Bhht, 768*256);
    cvt_f32_bf16<<<(N_NODES*256+255)/256, 256, 0, stream>>>(hprev, hprev_bf, N_NODES*256);
    cvt_f32_bf16<<<(N_NODES*IN_F+255)/256, 256, 0, stream>>>(x, xbf, N_NODES*IN_F);

    agg1_kernel<<<NRKEYS/4, 256, 0, stream>>>(xbf, row_ptr, csr_src, A1);

    // h1 = relu(A1 * B1) written into A2 cols 0..255 (ldc=1280)
    dim3 g12(313, 2);
    gemm_bt_t<2><<<g12, 256, 0, stream>>>(A1, 640, B1t, b1, A2, 1280, N_NODES, 640, 1);

    agg2_kernel<<<NRKEYS/4, 256, 0, stream>>>(row_ptr, csr_src, A2);

    // h2 overwrites A1 (dead) in P1
    gemm_bt_t<2><<<g12, 256, 0, stream>>>(A2, 1280, B2t, b2, h2, 256, N_NODES, 1280, 1);

    // qkvs overwrites A2 (dead) in P2
    dim3 g3(157, 8);
    gemm_bt_t<4><<<g3, 256, 0, stream>>>(h2, 256, B3t, bias3, qkvs, 1024, N_NODES, 256, 0);

    // fused attention: one pass over edges, online softmax (replaces score+attn_agg)
    attn_fused_kernel<<<N_NODES/4, 256, 0, stream>>>(qkvs, row_ptr, csr_src, hatt);

    // fused GRU gate-GEMMs + elementwise (r7 final: 512 threads, 128x64 tiles)
    gemm_gru_fused<<<dim3(157, 4), 512, 0, stream>>>(hatt, hprev_bf, Biht, Bhht,
                                                     b_ih, b_hh, hprev, (float*)d_out);
}

// Round 10
// 414.804 us; speedup vs baseline: 1.0464x; 1.0019x over previous
//
#include <hip/hip_runtime.h>
#include <hip/hip_bf16.h>
#include <stdint.h>

#define N_NODES 20000
#define E_EDGES 320000
#define IN_F    128
#define HIDF    256
#define R_REL   4
#define NRKEYS  (N_NODES*R_REL)   // 80000
#define SCAN_BLOCKS 80            // 80*1024 = 81920 >= NRKEYS

typedef __attribute__((ext_vector_type(8))) short  short8;
typedef __attribute__((ext_vector_type(4))) float  floatx4;

__device__ __forceinline__ float bf2f(__hip_bfloat16 v){ return __bfloat162float(v); }
__device__ __forceinline__ __hip_bfloat16 f2bf(float v){ return __float2bfloat16(v); }
__device__ __forceinline__ float bfbits2f(unsigned short u){ return __uint_as_float(((unsigned)u)<<16); }
__device__ __forceinline__ unsigned short f2bfbits(float v){
    __hip_bfloat16 h = __float2bfloat16(v);
    return *(unsigned short*)&h;
}
__device__ __forceinline__ unsigned pack_bf2(float a, float b){
    return (unsigned)f2bfbits(a) | ((unsigned)f2bfbits(b) << 16);
}

// async global->LDS, 16B per lane. LDS dest is WAVE-UNIFORM base (+lane*16 by HW);
// global src is per-lane (pre-swizzled to implement the LDS XOR layout).
__device__ __forceinline__ void gload_lds16(const void* g, void* l)
{
    __builtin_amdgcn_global_load_lds((const __attribute__((address_space(1))) void*)g,
                                     (__attribute__((address_space(3))) void*)l, 16, 0, 0);
}

template<int N>
__device__ __forceinline__ void wait_vm()
{
    if constexpr (N == 0)      asm volatile("s_waitcnt vmcnt(0)" ::: "memory");
    else if constexpr (N == 3) asm volatile("s_waitcnt vmcnt(3)" ::: "memory");
    else if constexpr (N == 4) asm volatile("s_waitcnt vmcnt(4)" ::: "memory");
    else if constexpr (N == 5) asm volatile("s_waitcnt vmcnt(5)" ::: "memory");
    else                       asm volatile("s_waitcnt vmcnt(0)" ::: "memory");
}

// bijective XCD-chunked swizzle (m204 formula). Verified r2: FETCH 63.6->17.3 MB.
// GEMM-structure history: r3 quad-buffer depth-3 lost to occupancy; r4 no-LDS
// register GEMM lost to per-wave L2 latency; r2 triple-buffer / 2-in-flight /
// vmcnt(L) is the measured optimum for long-K. Fused-GRU history: r5-r8 span
// barrier-convoy AND barrier-free schedules, all converge ~49-52 us -> gather-
// bound floor; r7 variant kept. Attn history: r9 online-softmax fusion halved
// the pair (~85 -> 50 us); FETCH 143 MB vs 20 MB compulsory = structural
// per-XCD L2 duplication (random srcs, not fixable by swizzle).
__device__ __forceinline__ int2 xcd_swizzle()
{
    int gx = gridDim.x, gy = gridDim.y;
    int nwg = gx * gy;
    int lin = blockIdx.x + gx * blockIdx.y;
    int q = nwg >> 3, r = nwg & 7;
    int k = lin & 7, i = lin >> 3;
    int j = (k < r ? k*(q+1) : r*(q+1) + (k-r)*q) + i;
    return make_int2(j / gy, j % gy);   // (x tile, y tile), y fastest
}

// ---------------- CSR build ----------------
__global__ void count_kernel(const int* __restrict__ ei, const int* __restrict__ et,
                             int* __restrict__ cnt)
{
    int e = blockIdx.x*256 + threadIdx.x;
    if (e >= E_EDGES) return;
    int dst = ei[E_EDGES + e];
    atomicAdd(&cnt[dst*R_REL + et[e]], 1);
}

__global__ __launch_bounds__(1024) void scan_reduce_kernel(const int* __restrict__ cnt,
                                                           int* __restrict__ blocksum)
{
    int ix = blockIdx.x*1024 + threadIdx.x;
    int v = (ix < NRKEYS) ? cnt[ix] : 0;
    #pragma unroll
    for (int o=32;o>0;o>>=1) v += __shfl_xor(v, o, 64);
    __shared__ int wsum[16];
    int wave = threadIdx.x >> 6, lane = threadIdx.x & 63;
    if (lane == 0) wsum[wave] = v;
    __syncthreads();
    if (threadIdx.x == 0) {
        int s = 0;
        #pragma unroll
        for (int w=0;w<16;w++) s += wsum[w];
        blocksum[blockIdx.x] = s;
    }
}

__global__ __launch_bounds__(128) void scan_sums_kernel(const int* __restrict__ blocksum,
                                                        int* __restrict__ blockoff)
{
    __shared__ int s[128];
    int t = threadIdx.x;
    int v = (t < SCAN_BLOCKS) ? blocksum[t] : 0;
    s[t] = v; __syncthreads();
    for (int off=1; off<128; off<<=1) {
        int u = (t>=off) ? s[t-off] : 0;
        __syncthreads();
        s[t] += u;
        __syncthreads();
    }
    if (t < SCAN_BLOCKS) blockoff[t] = s[t] - v;   // exclusive
}

__global__ __launch_bounds__(1024) void scan_apply_kernel(const int* __restrict__ cnt,
                                                          const int* __restrict__ blockoff,
                                                          int* __restrict__ row_ptr,
                                                          int* __restrict__ cursor)
{
    __shared__ int s[1024];
    int t = threadIdx.x;
    int ix = blockIdx.x*1024 + t;
    int v = (ix < NRKEYS) ? cnt[ix] : 0;
    s[t] = v; __syncthreads();
    for (int off=1; off<1024; off<<=1) {
        int u = (t>=off) ? s[t-off] : 0;
        __syncthreads();
        s[t] += u;
        __syncthreads();
    }
    if (ix < NRKEYS) {
        int excl = blockoff[blockIdx.x] + s[t] - v;
        row_ptr[ix] = excl;
        cursor[ix]  = excl;
        if (ix == NRKEYS-1) row_ptr[NRKEYS] = excl + v;
    }
}

__global__ void fill_kernel(const int* __restrict__ ei, const int* __restrict__ et,
                            int* __restrict__ cursor, int* __restrict__ csr_src)
{
    int e = blockIdx.x*256 + threadIdx.x;
    if (e >= E_EDGES) return;
    int src = ei[e];
    int dst = ei[E_EDGES + e];
    int key = dst*R_REL + et[e];
    int pos = atomicAdd(&cursor[key], 1);
    csr_src[pos] = src;
}

// ---------------- weight prep: fp32 sources -> bf16 B^T = [Nout][K] ----------------
__global__ void make_b1t(const float* __restrict__ root1,
                         const float* __restrict__ W1,
                         __hip_bfloat16* __restrict__ B1t)
{
    int idx = blockIdx.x*256 + threadIdx.x;         // n*640 + k
    if (idx >= 256*640) return;
    int n = idx / 640, k = idx % 640;
    float v;
    if (k < 128) v = root1[k*256 + n];
    else         v = W1[(k-128)*256 + n];           // W1 contiguous [R*128][256]
    B1t[idx] = f2bf(v);
}

__global__ void make_b2t(const float* __restrict__ root2,
                         const float* __restrict__ W2,
                         __hip_bfloat16* __restrict__ B2t)
{
    int idx = blockIdx.x*256 + threadIdx.x;         // n*1280 + k
    if (idx >= 256*1280) return;
    int n = idx / 1280, k = idx % 1280;
    float v;
    if (k < 256) v = root2[k*256 + n];
    else         v = W2[(k-256)*256 + n];           // W2 contiguous [R*256][256]
    B2t[idx] = f2bf(v);
}

__global__ void make_b3t(const float* __restrict__ Wq, const float* __restrict__ Wk,
                         const float* __restrict__ Wv, const float* __restrict__ Wsk,
                         const float* __restrict__ bq, const float* __restrict__ bk,
                         const float* __restrict__ bv, const float* __restrict__ bsk,
                         __hip_bfloat16* __restrict__ B3t, float* __restrict__ bias3)
{
    int idx = blockIdx.x*256 + threadIdx.x;         // n*256 + k, n<1024
    if (idx >= 1024*256) return;
    int n = idx / 256, k = idx % 256;
    int g = n >> 8, nn = n & 255;
    const float* W = (g==0)?Wq:(g==1)?Wk:(g==2)?Wv:Wsk;
    B3t[idx] = f2bf(W[k*256 + nn]);
    if (k == 0) {
        const float* B = (g==0)?bq:(g==1)?bk:(g==2)?bv:bsk;
        bias3[n] = B[nn];
    }
}

// generic fp32 -> bf16 elementwise convert (layout-preserving)
__global__ void cvt_f32_bf16(const float* __restrict__ in, __hip_bfloat16* __restrict__ out, int n)
{
    int i = blockIdx.x*256 + threadIdx.x;
    if (i < n) out[i] = f2bf(in[i]);
}

// ---------------- RGCN aggregation: one WAVE per (node,rel) key ----------------
// r10: unroll deepened 4 -> 8 (strictly more memory-level parallelism at the
// same proven structure; the gathers are latency-bound like attn_fused).
__global__ __launch_bounds__(256) void agg1_kernel(const __hip_bfloat16* __restrict__ xbf,
                                                   const int* __restrict__ row_ptr,
                                                   const int* __restrict__ csr_src,
                                                   __hip_bfloat16* __restrict__ A1)
{
    int b = blockIdx.x*4 + (threadIdx.x >> 6);   // key = i*4 + r
    int lane = threadIdx.x & 63;
    int i = b >> 2, r = b & 3;
    int e0 = row_ptr[b], e1 = row_ptr[b+1];
    float sx0=0.f,sy0=0.f, sx1=0.f,sy1=0.f, sx2=0.f,sy2=0.f, sx3=0.f,sy3=0.f;
    int e = e0;
    for (; e+8 <= e1; e += 8) {
        int i0=csr_src[e],   i1=csr_src[e+1], i2=csr_src[e+2], i3=csr_src[e+3];
        int i4=csr_src[e+4], i5=csr_src[e+5], i6=csr_src[e+6], i7=csr_src[e+7];
        unsigned u0 = *(const unsigned*)(xbf + (size_t)i0*IN_F + lane*2);
        unsigned u1 = *(const unsigned*)(xbf + (size_t)i1*IN_F + lane*2);
        unsigned u2 = *(const unsigned*)(xbf + (size_t)i2*IN_F + lane*2);
        unsigned u3 = *(const unsigned*)(xbf + (size_t)i3*IN_F + lane*2);
        unsigned u4 = *(const unsigned*)(xbf + (size_t)i4*IN_F + lane*2);
        unsigned u5 = *(const unsigned*)(xbf + (size_t)i5*IN_F + lane*2);
        unsigned u6 = *(const unsigned*)(xbf + (size_t)i6*IN_F + lane*2);
        unsigned u7 = *(const unsigned*)(xbf + (size_t)i7*IN_F + lane*2);
        sx0+=bfbits2f((unsigned short)u0)+bfbits2f((unsigned short)u4);
        sy0+=bfbits2f((unsigned short)(u0>>16))+bfbits2f((unsigned short)(u4>>16));
        sx1+=bfbits2f((unsigned short)u1)+bfbits2f((unsigned short)u5);
        sy1+=bfbits2f((unsigned short)(u1>>16))+bfbits2f((unsigned short)(u5>>16));
        sx2+=bfbits2f((unsigned short)u2)+bfbits2f((unsigned short)u6);
        sy2+=bfbits2f((unsigned short)(u2>>16))+bfbits2f((unsigned short)(u6>>16));
        sx3+=bfbits2f((unsigned short)u3)+bfbits2f((unsigned short)u7);
        sy3+=bfbits2f((unsigned short)(u3>>16))+bfbits2f((unsigned short)(u7>>16));
    }
    for (; e+4 <= e1; e += 4) {
        int i0=csr_src[e], i1=csr_src[e+1], i2=csr_src[e+2], i3=csr_src[e+3];
        unsigned u0 = *(const unsigned*)(xbf + (size_t)i0*IN_F + lane*2);
        unsigned u1 = *(const unsigned*)(xbf + (size_t)i1*IN_F + lane*2);
        unsigned u2 = *(const unsigned*)(xbf + (size_t)i2*IN_F + lane*2);
        unsigned u3 = *(const unsigned*)(xbf + (size_t)i3*IN_F + lane*2);
        sx0+=bfbits2f((unsigned short)u0); sy0+=bfbits2f((unsigned short)(u0>>16));
        sx1+=bfbits2f((unsigned short)u1); sy1+=bfbits2f((unsigned short)(u1>>16));
        sx2+=bfbits2f((unsigned short)u2); sy2+=bfbits2f((unsigned short)(u2>>16));
        sx3+=bfbits2f((unsigned short)u3); sy3+=bfbits2f((unsigned short)(u3>>16));
    }
    for (; e < e1; e++) {
        int i0 = csr_src[e];
        unsigned u = *(const unsigned*)(xbf + (size_t)i0*IN_F + lane*2);
        sx0+=bfbits2f((unsigned short)u); sy0+=bfbits2f((unsigned short)(u>>16));
    }
    float sx = (sx0+sx1)+(sx2+sx3);
    float sy = (sy0+sy1)+(sy2+sy3);
    float inv = (e1>e0) ? 1.f/(float)(e1-e0) : 0.f;
    *(unsigned*)(A1 + (size_t)i*640 + 128 + r*128 + lane*2) = pack_bf2(sx*inv, sy*inv);
    if (r == 0)   // root copy: already bf16, straight 4B copy
        *(unsigned*)(A1 + (size_t)i*640 + lane*2) = *(const unsigned*)(xbf + (size_t)i*IN_F + lane*2);
}

// agg2: h1 bf16 in A2 cols 0..255 (ld 1280); lane covers dims 4*lane..4*lane+3 (8 B).
__global__ __launch_bounds__(256) void agg2_kernel(const int* __restrict__ row_ptr,
                                                   const int* __restrict__ csr_src,
                                                   __hip_bfloat16* __restrict__ A2)
{
    int b = blockIdx.x*4 + (threadIdx.x >> 6);
    int lane = threadIdx.x & 63;
    int i = b >> 2, r = b & 3;
    int e0 = row_ptr[b], e1 = row_ptr[b+1];
    float a0=0.f,a1=0.f,a2=0.f,a3=0.f;
    float b0=0.f,b1=0.f,b2=0.f,b3=0.f;
    float c0=0.f,c1=0.f,c2=0.f,c3=0.f;
    float d0=0.f,d1=0.f,d2=0.f,d3=0.f;
    int e = e0;
    for (; e+8 <= e1; e += 8) {
        int i0=csr_src[e],   i1=csr_src[e+1], i2=csr_src[e+2], i3=csr_src[e+3];
        int i4=csr_src[e+4], i5=csr_src[e+5], i6=csr_src[e+6], i7=csr_src[e+7];
        ushort4 u0 = *(const ushort4*)(A2 + (size_t)i0*1280 + lane*4);
        ushort4 u1 = *(const ushort4*)(A2 + (size_t)i1*1280 + lane*4);
        ushort4 u2 = *(const ushort4*)(A2 + (size_t)i2*1280 + lane*4);
        ushort4 u3 = *(const ushort4*)(A2 + (size_t)i3*1280 + lane*4);
        ushort4 u4 = *(const ushort4*)(A2 + (size_t)i4*1280 + lane*4);
        ushort4 u5 = *(const ushort4*)(A2 + (size_t)i5*1280 + lane*4);
        ushort4 u6 = *(const ushort4*)(A2 + (size_t)i6*1280 + lane*4);
        ushort4 u7 = *(const ushort4*)(A2 + (size_t)i7*1280 + lane*4);
        a0+=bfbits2f(u0.x)+bfbits2f(u4.x); a1+=bfbits2f(u0.y)+bfbits2f(u4.y);
        a2+=bfbits2f(u0.z)+bfbits2f(u4.z); a3+=bfbits2f(u0.w)+bfbits2f(u4.w);
        b0+=bfbits2f(u1.x)+bfbits2f(u5.x); b1+=bfbits2f(u1.y)+bfbits2f(u5.y);
        b2+=bfbits2f(u1.z)+bfbits2f(u5.z); b3+=bfbits2f(u1.w)+bfbits2f(u5.w);
        c0+=bfbits2f(u2.x)+bfbits2f(u6.x); c1+=bfbits2f(u2.y)+bfbits2f(u6.y);
        c2+=bfbits2f(u2.z)+bfbits2f(u6.z); c3+=bfbits2f(u2.w)+bfbits2f(u6.w);
        d0+=bfbits2f(u3.x)+bfbits2f(u7.x); d1+=bfbits2f(u3.y)+bfbits2f(u7.y);
        d2+=bfbits2f(u3.z)+bfbits2f(u7.z); d3+=bfbits2f(u3.w)+bfbits2f(u7.w);
    }
    for (; e+4 <= e1; e += 4) {
        int i0=csr_src[e], i1=csr_src[e+1], i2=csr_src[e+2], i3=csr_src[e+3];
        ushort4 u0 = *(const ushort4*)(A2 + (size_t)i0*1280 + lane*4);
        ushort4 u1 = *(const ushort4*)(A2 + (size_t)i1*1280 + lane*4);
        ushort4 u2 = *(const ushort4*)(A2 + (size_t)i2*1280 + lane*4);
        ushort4 u3 = *(const ushort4*)(A2 + (size_t)i3*1280 + lane*4);
        a0+=bfbits2f(u0.x); a1+=bfbits2f(u0.y); a2+=bfbits2f(u0.z); a3+=bfbits2f(u0.w);
        b0+=bfbits2f(u1.x); b1+=bfbits2f(u1.y); b2+=bfbits2f(u1.z); b3+=bfbits2f(u1.w);
        c0+=bfbits2f(u2.x); c1+=bfbits2f(u2.y); c2+=bfbits2f(u2.z); c3+=bfbits2f(u2.w);
        d0+=bfbits2f(u3.x); d1+=bfbits2f(u3.y); d2+=bfbits2f(u3.z); d3+=bfbits2f(u3.w);
    }
    for (; e < e1; e++) {
        int i0 = csr_src[e];
        ushort4 u = *(const ushort4*)(A2 + (size_t)i0*1280 + lane*4);
        a0+=bfbits2f(u.x); a1+=bfbits2f(u.y); a2+=bfbits2f(u.z); a3+=bfbits2f(u.w);
    }
    float s0=(a0+b0)+(c0+d0), s1=(a1+b1)+(c1+d1), s2=(a2+b2)+(c2+d2), s3=(a3+b3)+(c3+d3);
    float inv = (e1>e0) ? 1.f/(float)(e1-e0) : 0.f;
    uint2 w;
    w.x = pack_bf2(s0*inv, s1*inv);
    w.y = pack_bf2(s2*inv, s3*inv);
    *(uint2*)(A2 + (size_t)i*1280 + 256 + r*256 + lane*4) = w;
}

// ---------------- LDS-pipelined GEMM (r2 config: best measured) ----------------
template<int MI>
__device__ __forceinline__ void gemm_bt_body(const __hip_bfloat16* __restrict__ A, int lda,
                                             const __hip_bfloat16* __restrict__ Bt,
                                             const float* __restrict__ bias,
                                             __hip_bfloat16* __restrict__ C, int ldc,
                                             int M, int K, int relu,
                                             int tile_m, int tile_n,
                                             __hip_bfloat16* lds_a, __hip_bfloat16* lds_b)
{
    constexpr int A_ELEMS = MI*1024;
    constexpr int B_ELEMS = 4096;
    constexpr int L = MI/2 + 2;
    const int tid  = threadIdx.x;
    const int wave = tid >> 6;
    const int lane = tid & 63;
    const int wm = wave >> 1, wn = wave & 1;
    const int fm = lane & 15;
    const int q  = lane >> 4;
    const int sw = (q ^ ((fm >> 1) & 3)) * 8;

    floatx4 acc[MI][4];
    #pragma unroll
    for (int i=0;i<MI;i++)
        #pragma unroll
        for (int j=0;j<4;j++) acc[i][j] = (floatx4){0.f,0.f,0.f,0.f};

    const int srow   = lane >> 2;
    const int schunk = lane & 3;
    size_t a_goff[MI/2];
    #pragma unroll
    for (int s = 0; s < MI/2; ++s) {
        int r = (s*4 + wave)*16 + srow;
        int c = schunk ^ ((r >> 1) & 3);
        a_goff[s] = (size_t)min(tile_m + r, M-1)*lda + c*8;
    }
    size_t b_goff[2];
    #pragma unroll
    for (int s = 0; s < 2; ++s) {
        int r = (s*4 + wave)*16 + srow;
        int c = schunk ^ ((r >> 1) & 3);
        b_goff[s] = (size_t)(tile_n + r)*K + c*8;
    }

    const int nt = K >> 5;

    auto issue = [&](int t, int bufi) {
        const int kn = t << 5;
        #pragma unroll
        for (int s = 0; s < MI/2; ++s)
            gload_lds16(A + a_goff[s] + kn, lds_a + bufi*A_ELEMS + (s*4 + wave)*512);
        #pragma unroll
        for (int s = 0; s < 2; ++s)
            gload_lds16(Bt + b_goff[s] + kn, lds_b + bufi*B_ELEMS + (s*4 + wave)*512);
    };

    issue(0, 0);
    if (nt > 1) { issue(1, 1); wait_vm<L>(); }
    else        { wait_vm<0>(); }
    __builtin_amdgcn_s_barrier();

    int cur = 0, nx2 = 2;
    for (int t = 0; t < nt; ++t) {
        if (t + 2 < nt) issue(t + 2, nx2);

        const __hip_bfloat16* la = lds_a + cur*A_ELEMS;
        const __hip_bfloat16* lb = lds_b + cur*B_ELEMS;
        short8 afr[MI], bfr[4];
        #pragma unroll
        for (int i=0;i<MI;i++)
            afr[i] = *(const short8*)(la + (wm*(MI*16) + i*16 + fm)*32 + sw);
        #pragma unroll
        for (int j=0;j<4;j++)
            bfr[j] = *(const short8*)(lb + (wn*64 + j*16 + fm)*32 + sw);

        __builtin_amdgcn_s_setprio(1);
        #pragma unroll
        for (int i=0;i<MI;i++)
            #pragma unroll
            for (int j=0;j<4;j++)
                acc[i][j] = __builtin_amdgcn_mfma_f32_16x16x32_bf16(afr[i], bfr[j], acc[i][j], 0,0,0);
        __builtin_amdgcn_s_setprio(0);

        if (t + 1 < nt) {
            if (t + 2 < nt) wait_vm<L>();
            else            wait_vm<0>();
            __builtin_amdgcn_s_barrier();
            cur = (cur == 2) ? 0 : cur + 1;
            nx2 = (nx2 == 2) ? 0 : nx2 + 1;
        }
    }

    const int crow_base = tile_m + wm*(MI*16);
    const int ccol_base = tile_n + wn*64;
    #pragma unroll
    for (int i=0;i<MI;i++) {
        #pragma unroll
        for (int j=0;j<4;j++) {
            int c  = ccol_base + j*16 + fm;
            float bb = bias[c];
            #pragma unroll
            for (int rg=0; rg<4; rg++) {
                int r = crow_base + i*16 + q*4 + rg;
                if (r < M) {
                    float v = acc[i][j][rg] + bb;
                    if (relu) v = fmaxf(v, 0.f);
                    C[(size_t)r*ldc + c] = f2bf(v);
                }
            }
        }
    }
}

template<int MI>
__global__ __launch_bounds__(256) void gemm_bt_t(const __hip_bfloat16* __restrict__ A, int lda,
                                                 const __hip_bfloat16* __restrict__ Bt,
                                                 const float* __restrict__ bias,
                                                 __hip_bfloat16* __restrict__ C, int ldc,
                                                 int M, int K, int relu)
{
    __shared__ __align__(16) __hip_bfloat16 lds_a[3*MI*1024];
    __shared__ __align__(16) __hip_bfloat16 lds_b[3*4096];
    int2 xy = xcd_swizzle();
    gemm_bt_body<MI>(A, lda, Bt, bias, C, ldc, M, K, relu,
                     xy.x*(MI*32), xy.y*128, lds_a, lds_b);
}

// ---------------- fused GRU gate-GEMM + elementwise (r7 final: best measured 48.9us) ----------------
__global__ __launch_bounds__(512) void gemm_gru_fused(
    const __hip_bfloat16* __restrict__ A0,   // hatt bf16 [N,256]
    const __hip_bfloat16* __restrict__ A1,   // hprev bf16 [N,256]
    const __hip_bfloat16* __restrict__ Bt0,  // W_ih [768][256]
    const __hip_bfloat16* __restrict__ Bt1,  // W_hh [768][256]
    const float* __restrict__ b_ih, const float* __restrict__ b_hh,
    const float* __restrict__ hprev, float* __restrict__ out)
{
    constexpr int BUF_ELEMS = 20480;  // A 256x32 (8192) + B 384x32 (12288)
    __shared__ __align__(16) __hip_bfloat16 lds[2*BUF_ELEMS];   // 80 KB
    int2 xy = xcd_swizzle();          // grid (157, 4), y = 64-channel chunk
    const int tile_m = xy.x * 128;
    const int c0     = xy.y * 64;
    const int tid = threadIdx.x, wave = tid >> 6, lane = tid & 63;
    const int wm = wave >> 1, wn = wave & 1;     // 4x2 wave grid: 32 rows x 32 ch
    const int fm = lane & 15, q = lane >> 4;
    const int sw = (q ^ ((fm >> 1) & 3)) * 8;

    const int sub = lane >> 2, ch = lane & 3;
    const __hip_bfloat16* gsrc[5];
    int dstoff[5];
    #pragma unroll
    for (int s = 0; s < 5; ++s) {
        int seg = wave*5 + s;                        // 0..39
        if (seg < 16) {
            int fr = seg*16 + sub;                   // 0..255
            int mat = fr >> 7, rl = fr & 127;
            int c = ch ^ ((fr >> 1) & 3);
            int grow = min(tile_m + rl, N_NODES-1);
            gsrc[s] = (mat ? A1 : A0) + (size_t)grow*256 + c*8;
            dstoff[s] = seg*512;
        } else {
            int fs = seg - 16;
            int fr = fs*16 + sub;                    // 0..383
            int grp = fr >> 6, ri = fr & 63;         // grp = mat*3 + gate
            int mat = grp >= 3, gate = mat ? grp-3 : grp;
            int c = ch ^ ((fr >> 1) & 3);
            int grow = gate*256 + c0 + ri;
            gsrc[s] = (mat ? Bt1 : Bt0) + (size_t)grow*256 + c*8;
            dstoff[s] = 8192 + fs*512;
        }
    }

    floatx4 acc[2][3][2][2];   // [mat][gate][row frag][col frag]
    #pragma unroll
    for (int m=0;m<2;m++)
        #pragma unroll
        for (int g=0;g<3;g++)
            #pragma unroll
            for (int i=0;i<2;i++)
                #pragma unroll
                for (int f=0;f<2;f++) acc[m][g][i][f] = (floatx4){0.f,0.f,0.f,0.f};

    auto issue = [&](int t, int bufi) {
        const int kn = t << 5;
        #pragma unroll
        for (int s = 0; s < 5; ++s)
            gload_lds16(gsrc[s] + kn, lds + bufi*BUF_ELEMS + dstoff[s]);
    };

    issue(0, 0);
    issue(1, 1);
    wait_vm<5>();                      // batch 0 landed; batch 1 in flight
    __builtin_amdgcn_s_barrier();

    #pragma unroll 1
    for (int t = 0; t < 8; ++t) {
        const __hip_bfloat16* lb = lds + (t & 1)*BUF_ELEMS;
        short8 af[2][2], bfr[2][3][2];
        #pragma unroll
        for (int m=0;m<2;m++)
            #pragma unroll
            for (int i=0;i<2;i++)
                af[m][i] = *(const short8*)(lb + (m*128 + wm*32 + i*16 + fm)*32 + sw);
        #pragma unroll
        for (int m=0;m<2;m++)
            #pragma unroll
            for (int g=0;g<3;g++)
                #pragma unroll
                for (int f=0;f<2;f++)
                    bfr[m][g][f] = *(const short8*)(lb + 8192 + (((m*3+g)*64 + wn*32 + f*16 + fm)*32) + sw);

        __builtin_amdgcn_s_setprio(1);
        #pragma unroll
        for (int m=0;m<2;m++)
            #pragma unroll
            for (int g=0;g<3;g++)
                #pragma unroll
                for (int i=0;i<2;i++)
                    #pragma unroll
                    for (int f=0;f<2;f++)
                        acc[m][g][i][f] = __builtin_amdgcn_mfma_f32_16x16x32_bf16(af[m][i], bfr[m][g][f], acc[m][g][i][f], 0,0,0);
        __builtin_amdgcn_s_setprio(0);

        if (t + 1 < 8) {
            __builtin_amdgcn_s_barrier();            // all waves done reading buf[t&1]
            if (t + 2 < 8) { issue(t + 2, t & 1); wait_vm<5>(); }  // t+1 landed, t+2 in flight
            else           wait_vm<0>();                           // tail drain
            __builtin_amdgcn_s_barrier();            // everyone's batch t+1 visible
        }
    }

    // epilogue: GRU math (exp-based sigmoid/tanh), write fp32 out only
    #pragma unroll
    for (int f=0; f<2; ++f) {
        int c = c0 + wn*32 + f*16 + fm;
        float bir = b_ih[c], biz = b_ih[256+c], bin = b_ih[512+c];
        float bhr = b_hh[c], bhz = b_hh[256+c], bhn = b_hh[512+c];
        #pragma unroll
        for (int i=0; i<2; ++i) {
            #pragma unroll
            for (int rg=0; rg<4; ++rg) {
                int r = tile_m + wm*32 + i*16 + q*4 + rg;
                if (r < N_NODES) {
                    float gir = acc[0][0][i][f][rg] + bir;
                    float giz = acc[0][1][i][f][rg] + biz;
                    float gin = acc[0][2][i][f][rg] + bin;
                    float ghr = acc[1][0][i][f][rg] + bhr;
                    float ghz = acc[1][1][i][f][rg] + bhz;
                    float ghn = acc[1][2][i][f][rg] + bhn;
                    float rr = 1.f/(1.f + __expf(-(gir + ghr)));
                    float zz = 1.f/(1.f + __expf(-(giz + ghz)));
                    float xn = gin + rr*ghn;
                    float e2 = __expf(xn + xn);
                    float nn = 1.f - 2.f/(e2 + 1.f);   // tanh(xn)
                    float h  = hprev[(size_t)r*256 + c];
                    out[(size_t)r*256 + c] = (1.f - zz)*nn + zz*h;
                }
            }
        }
    }
}

// ---------------- fused attention (r10): online softmax, unroll-4 ----------------
// r9 verified the fusion (score+attn 85 -> 50 us, FETCH one-pass). r10 deepens
// MLP: 4 edges per iteration = 8 K/V gathers in flight (VGPR was 24 -> ample
// headroom), interleaved 4-way shfl reduce, one rescale check per 4 edges.
__global__ __launch_bounds__(256) void attn_fused_kernel(
    const __hip_bfloat16* __restrict__ qkvs,
    const int* __restrict__ row_ptr,
    const int* __restrict__ csr_src,
    __hip_bfloat16* __restrict__ hatt)
{
    int i = blockIdx.x*4 + (threadIdx.x >> 6);   // node (4 nodes per block)
    int lane = threadIdx.x & 63;
    int e0 = row_ptr[i*R_REL], e1 = row_ptr[i*R_REL + R_REL];

    ushort4 qv = *(const ushort4*)(qkvs + (size_t)i*1024 + lane*4);
    float qx=bfbits2f(qv.x), qy=bfbits2f(qv.y), qz=bfbits2f(qv.z), qw=bfbits2f(qv.w);

    float m = -1e30f, denom = 0.f;
    float ax=0.f, ay=0.f, az=0.f, aw=0.f;

    int j = e0;
    for (; j+4 <= e1; j += 4) {
        int s0 = csr_src[j],   s1 = csr_src[j+1];
        int s2 = csr_src[j+2], s3 = csr_src[j+3];
        const __hip_bfloat16* r0 = qkvs + (size_t)s0*1024;
        const __hip_bfloat16* r1 = qkvs + (size_t)s1*1024;
        const __hip_bfloat16* r2 = qkvs + (size_t)s2*1024;
        const __hip_bfloat16* r3 = qkvs + (size_t)s3*1024;
        ushort4 k0 = *(const ushort4*)(r0 + 256 + lane*4);
        ushort4 k1 = *(const ushort4*)(r1 + 256 + lane*4);
        ushort4 k2 = *(const ushort4*)(r2 + 256 + lane*4);
        ushort4 k3 = *(const ushort4*)(r3 + 256 + lane*4);
        ushort4 v0 = *(const ushort4*)(r0 + 512 + lane*4);   // issued before reduce
        ushort4 v1 = *(const ushort4*)(r1 + 512 + lane*4);
        ushort4 v2 = *(const ushort4*)(r2 + 512 + lane*4);
        ushort4 v3 = *(const ushort4*)(r3 + 512 + lane*4);
        float d0 = qx*bfbits2f(k0.x)+qy*bfbits2f(k0.y)+qz*bfbits2f(k0.z)+qw*bfbits2f(k0.w);
        float d1 = qx*bfbits2f(k1.x)+qy*bfbits2f(k1.y)+qz*bfbits2f(k1.z)+qw*bfbits2f(k1.w);
        float d2 = qx*bfbits2f(k2.x)+qy*bfbits2f(k2.y)+qz*bfbits2f(k2.z)+qw*bfbits2f(k2.w);
        float d3 = qx*bfbits2f(k3.x)+qy*bfbits2f(k3.y)+qz*bfbits2f(k3.z)+qw*bfbits2f(k3.w);
        #pragma unroll
        for (int o=1;o<16;o<<=1){
            d0 += __shfl_xor(d0,o,64); d1 += __shfl_xor(d1,o,64);
            d2 += __shfl_xor(d2,o,64); d3 += __shfl_xor(d3,o,64);
        }
        d0 *= 0.125f; d1 *= 0.125f; d2 *= 0.125f; d3 *= 0.125f;   // 1/sqrt(64)
        float mx = fmaxf(fmaxf(d0, d1), fmaxf(d2, d3));
        if (mx > m) {                    // rescale (rare after warm-up)
            float sc = __expf(m - mx);
            ax*=sc; ay*=sc; az*=sc; aw*=sc; denom*=sc;
            m = mx;
        }
        float w0 = __expf(d0 - m), w1 = __expf(d1 - m);
        float w2 = __expf(d2 - m), w3 = __expf(d3 - m);
        denom += (w0 + w1) + (w2 + w3);
        ax += w0*bfbits2f(v0.x) + w1*bfbits2f(v1.x) + w2*bfbits2f(v2.x) + w3*bfbits2f(v3.x);
        ay += w0*bfbits2f(v0.y) + w1*bfbits2f(v1.y) + w2*bfbits2f(v2.y) + w3*bfbits2f(v3.y);
        az += w0*bfbits2f(v0.z) + w1*bfbits2f(v1.z) + w2*bfbits2f(v2.z) + w3*bfbits2f(v3.z);
        aw += w0*bfbits2f(v0.w) + w1*bfbits2f(v1.w) + w2*bfbits2f(v2.w) + w3*bfbits2f(v3.w);
    }
    for (; j < e1; ++j) {
        int s0 = csr_src[j];
        const __hip_bfloat16* r0 = qkvs + (size_t)s0*1024;
        ushort4 k0 = *(const ushort4*)(r0 + 256 + lane*4);
        ushort4 v0 = *(const ushort4*)(r0 + 512 + lane*4);
        float d0 = qx*bfbits2f(k0.x)+qy*bfbits2f(k0.y)+qz*bfbits2f(k0.z)+qw*bfbits2f(k0.w);
        #pragma unroll
        for (int o=1;o<16;o<<=1) d0 += __shfl_xor(d0,o,64);
        d0 *= 0.125f;
        if (d0 > m) {
            float sc = __expf(m - d0);
            ax*=sc; ay*=sc; az*=sc; aw*=sc; denom*=sc;
            m = d0;
        }
        float w0 = __expf(d0 - m);
        denom += w0;
        ax += w0*bfbits2f(v0.x); ay += w0*bfbits2f(v0.y);
        az += w0*bfbits2f(v0.z); aw += w0*bfbits2f(v0.w);
    }

    float inv = 1.f / fmaxf(denom, 1e-16f);
    ushort4 sk = *(const ushort4*)(qkvs + (size_t)i*1024 + 768 + lane*4);
    uint2 w;
    w.x = pack_bf2(ax*inv + bfbits2f(sk.x), ay*inv + bfbits2f(sk.y));
    w.y = pack_bf2(az*inv + bfbits2f(sk.z), aw*inv + bfbits2f(sk.w));
    *(uint2*)(hatt + (size_t)i*256 + lane*4) = w;
}

// ---------------- launch ----------------
extern "C" void kernel_launch(void* const* d_in, const int* in_sizes, int n_in,
                              void* d_out, int out_size, void* d_ws, size_t ws_size,
                              hipStream_t stream)
{
    const float* x       = (const float*)d_in[0];
    const int* edge_index= (const int*)d_in[1];
    const int* edge_type = (const int*)d_in[2];
    const float* hprev   = (const float*)d_in[3];
    const float* W1      = (const float*)d_in[4];
    const float* root1   = (const float*)d_in[5];
    const float* b1      = (const float*)d_in[6];
    const float* W2      = (const float*)d_in[7];
    const float* root2   = (const float*)d_in[8];
    const float* b2      = (const float*)d_in[9];
    const float* Wq      = (const float*)d_in[10];
    const float* bq      = (const float*)d_in[11];
    const float* Wk      = (const float*)d_in[12];
    const float* bk      = (const float*)d_in[13];
    const float* Wv      = (const float*)d_in[14];
    const float* bv      = (const float*)d_in[15];
    const float* Wskip   = (const float*)d_in[16];
    const float* bskip   = (const float*)d_in[17];
    const float* W_ih    = (const float*)d_in[18];
    const float* b_ih    = (const float*)d_in[19];
    const float* W_hh    = (const float*)d_in[20];
    const float* b_hh    = (const float*)d_in[21];

    char* ws = (char*)d_ws;
    size_t off = 0;
    auto take = [&](size_t bytes)->char* {
        char* p = ws + off;
        off = (off + bytes + 255) & ~(size_t)255;
        return p;
    };
    int* cnt        = (int*)take((size_t)NRKEYS*4);
    int* row_ptr    = (int*)take((size_t)(NRKEYS+1)*4);
    int* cursor     = (int*)take((size_t)NRKEYS*4);
    int* csr_src    = (int*)take((size_t)E_EDGES*4);
    int* blocksum   = (int*)take((size_t)SCAN_BLOCKS*4);
    int* blockoff   = (int*)take((size_t)(SCAN_BLOCKS+1)*4);
    __hip_bfloat16* B1t   = (__hip_bfloat16*)take((size_t)256*640*2);
    __hip_bfloat16* B2t   = (__hip_bfloat16*)take((size_t)256*1280*2);
    __hip_bfloat16* B3t   = (__hip_bfloat16*)take((size_t)1024*256*2);
    __hip_bfloat16* Biht  = (__hip_bfloat16*)take((size_t)768*256*2);
    __hip_bfloat16* Bhht  = (__hip_bfloat16*)take((size_t)768*256*2);
    float*          bias3 = (float*)take((size_t)1024*4);
    __hip_bfloat16* hprev_bf = (__hip_bfloat16*)take((size_t)N_NODES*256*2);
    __hip_bfloat16* xbf      = (__hip_bfloat16*)take((size_t)N_NODES*IN_F*2);
    char* P1 = take((size_t)N_NODES*640*2);
    char* P2 = take((size_t)N_NODES*1536*2);

    __hip_bfloat16* A1   = (__hip_bfloat16*)P1;   // [N,640]  dead after gemm1
    __hip_bfloat16* h2   = (__hip_bfloat16*)P1;   // [N,256]  dead after gemm3
    __hip_bfloat16* hatt = (__hip_bfloat16*)P1;   // [N,256]  read by fused GRU
    __hip_bfloat16* A2   = (__hip_bfloat16*)P2;   // [N,1280] dead after gemm2
    __hip_bfloat16* qkvs = (__hip_bfloat16*)P2;   // [N,1024] dead after attn_fused

    hipMemsetAsync(cnt, 0, (size_t)NRKEYS*4, stream);
    count_kernel<<<(E_EDGES+255)/256, 256, 0, stream>>>(edge_index, edge_type, cnt);
    scan_reduce_kernel<<<SCAN_BLOCKS, 1024, 0, stream>>>(cnt, blocksum);
    scan_sums_kernel<<<1, 128, 0, stream>>>(blocksum, blockoff);
    scan_apply_kernel<<<SCAN_BLOCKS, 1024, 0, stream>>>(cnt, blockoff, row_ptr, cursor);
    fill_kernel<<<(E_EDGES+255)/256, 256, 0, stream>>>(edge_index, edge_type, cursor, csr_src);

    make_b1t<<<(256*640+255)/256, 256, 0, stream>>>(root1, W1, B1t);
    make_b2t<<<(256*1280+255)/256, 256, 0, stream>>>(root2, W2, B2t);
    make_b3t<<<(1024*256+255)/256, 256, 0, stream>>>(Wq, Wk, Wv, Wskip, bq, bk, bv, bskip, B3t, bias3);
    cvt_f32_bf16<<<(768*256+255)/256, 256, 0, stream>>>(W_ih, Biht, 768*256);
    cvt_f32_bf16<<<(768*256+255)/256, 256, 0, stream>>>(W_hh, Bhht, 768*256);
    cvt_f32_bf16<<<(N_NODES*256+255)/256, 256, 0, stream>>>(hprev, hprev_bf, N_NODES*256);
    cvt_f32_bf16<<<(N_NODES*IN_F+255)/256, 256, 0, stream>>>(x, xbf, N_NODES*IN_F);

    agg1_kernel<<<NRKEYS/4, 256, 0, stream>>>(xbf, row_ptr, csr_src, A1);

    // h1 = relu(A1 * B1) written into A2 cols 0..255 (ldc=1280)
    dim3 g12(313, 2);
    gemm_bt_t<2><<<g12, 256, 0, stream>>>(A1, 640, B1t, b1, A2, 1280, N_NODES, 640, 1);

    agg2_kernel<<<NRKEYS/4, 256, 0, stream>>>(row_ptr, csr_src, A2);

    // h2 overwrites A1 (dead) in P1
    gemm_bt_t<2><<<g12, 256, 0, stream>>>(A2, 1280, B2t, b2, h2, 256, N_NODES, 1280, 1);

    // qkvs overwrites A2 (dead) in P2
    dim3 g3(157, 8);
    gemm_bt_t<4><<<g3, 256, 0, stream>>>(h2, 256, B3t, bias3, qkvs, 1024, N_NODES, 256, 0);

    // fused attention: one pass over edges, online softmax (unroll-4)
    attn_fused_kernel<<<N_NODES/4, 256, 0, stream>>>(qkvs, row_ptr, csr_src, hatt);

    // fused GRU gate-GEMMs + elementwise (r7 final: 512 threads, 128x64 tiles)
    gemm_gru_fused<<<dim3(157, 4), 512, 0, stream>>>(hatt, hprev_bf, Biht, Bhht,
                                                     b_ih, b_hh, hprev, (float*)d_out);
}

// Round 12
// 405.062 us; speedup vs baseline: 1.0716x; 1.0241x over previous
//
#include <hip/hip_runtime.h>
#include <hip/hip_bf16.h>
#include <stdint.h>

#define N_NODES 20000
#define E_EDGES 320000
#define IN_F    128
#define HIDF    256
#define R_REL   4
#define NRKEYS  (N_NODES*R_REL)   // 80000
#define SCAN_BLOCKS 80            // 80*1024 = 81920 >= NRKEYS

typedef __attribute__((ext_vector_type(8))) short  short8;
typedef __attribute__((ext_vector_type(4))) float  floatx4;

__device__ __forceinline__ float bf2f(__hip_bfloat16 v){ return __bfloat162float(v); }
__device__ __forceinline__ __hip_bfloat16 f2bf(float v){ return __float2bfloat16(v); }
__device__ __forceinline__ float bfbits2f(unsigned short u){ return __uint_as_float(((unsigned)u)<<16); }
__device__ __forceinline__ unsigned short f2bfbits(float v){
    __hip_bfloat16 h = __float2bfloat16(v);
    return *(unsigned short*)&h;
}
__device__ __forceinline__ unsigned pack_bf2(float a, float b){
    return (unsigned)f2bfbits(a) | ((unsigned)f2bfbits(b) << 16);
}

// async global->LDS, 16B per lane. LDS dest is WAVE-UNIFORM base (+lane*16 by HW);
// global src is per-lane (pre-swizzled to implement the LDS XOR layout).
__device__ __forceinline__ void gload_lds16(const void* g, void* l)
{
    __builtin_amdgcn_global_load_lds((const __attribute__((address_space(1))) void*)g,
                                     (__attribute__((address_space(3))) void*)l, 16, 0, 0);
}

template<int N>
__device__ __forceinline__ void wait_vm()
{
    if constexpr (N == 0)      asm volatile("s_waitcnt vmcnt(0)" ::: "memory");
    else if constexpr (N == 3) asm volatile("s_waitcnt vmcnt(3)" ::: "memory");
    else if constexpr (N == 4) asm volatile("s_waitcnt vmcnt(4)" ::: "memory");
    else if constexpr (N == 5) asm volatile("s_waitcnt vmcnt(5)" ::: "memory");
    else                       asm volatile("s_waitcnt vmcnt(0)" ::: "memory");
}

// bijective XCD-chunked swizzle (m204 formula). Verified r2: FETCH 63.6->17.3 MB.
// Convergence ledger: GEMM structure r2-r4 (triple-buffer/2-in-flight/vmcnt(L)
// optimal); fused-GRU r5-r8 (~49us gather-bound floor, 4 schedule variants);
// attn r9-r10 (online-softmax fusion 85->50us, then flat at the L3 random-
// gather service rate ~3.15 TB/s with structural 8x per-XCD L2 duplication);
// aggs compulsory-gather-bound (avg deg 4/key, unrolls can't engage).
__device__ __forceinline__ int2 xcd_swizzle()
{
    int gx = gridDim.x, gy = gridDim.y;
    int nwg = gx * gy;
    int lin = blockIdx.x + gx * blockIdx.y;
    int q = nwg >> 3, r = nwg & 7;
    int k = lin & 7, i = lin >> 3;
    int j = (k < r ? k*(q+1) : r*(q+1) + (k-r)*q) + i;
    return make_int2(j / gy, j % gy);   // (x tile, y tile), y fastest
}

// ---------------- CSR build ----------------
__global__ void count_kernel(const int* __restrict__ ei, const int* __restrict__ et,
                             int* __restrict__ cnt)
{
    int e = blockIdx.x*256 + threadIdx.x;
    if (e >= E_EDGES) return;
    int dst = ei[E_EDGES + e];
    atomicAdd(&cnt[dst*R_REL + et[e]], 1);
}

__global__ __launch_bounds__(1024) void scan_reduce_kernel(const int* __restrict__ cnt,
                                                           int* __restrict__ blocksum)
{
    int ix = blockIdx.x*1024 + threadIdx.x;
    int v = (ix < NRKEYS) ? cnt[ix] : 0;
    #pragma unroll
    for (int o=32;o>0;o>>=1) v += __shfl_xor(v, o, 64);
    __shared__ int wsum[16];
    int wave = threadIdx.x >> 6, lane = threadIdx.x & 63;
    if (lane == 0) wsum[wave] = v;
    __syncthreads();
    if (threadIdx.x == 0) {
        int s = 0;
        #pragma unroll
        for (int w=0;w<16;w++) s += wsum[w];
        blocksum[blockIdx.x] = s;
    }
}

__global__ __launch_bounds__(128) void scan_sums_kernel(const int* __restrict__ blocksum,
                                                        int* __restrict__ blockoff)
{
    __shared__ int s[128];
    int t = threadIdx.x;
    int v = (t < SCAN_BLOCKS) ? blocksum[t] : 0;
    s[t] = v; __syncthreads();
    for (int off=1; off<128; off<<=1) {
        int u = (t>=off) ? s[t-off] : 0;
        __syncthreads();
        s[t] += u;
        __syncthreads();
    }
    if (t < SCAN_BLOCKS) blockoff[t] = s[t] - v;   // exclusive
}

__global__ __launch_bounds__(1024) void scan_apply_kernel(const int* __restrict__ cnt,
                                                          const int* __restrict__ blockoff,
                                                          int* __restrict__ row_ptr,
                                                          int* __restrict__ cursor)
{
    __shared__ int s[1024];
    int t = threadIdx.x;
    int ix = blockIdx.x*1024 + t;
    int v = (ix < NRKEYS) ? cnt[ix] : 0;
    s[t] = v; __syncthreads();
    for (int off=1; off<1024; off<<=1) {
        int u = (t>=off) ? s[t-off] : 0;
        __syncthreads();
        s[t] += u;
        __syncthreads();
    }
    if (ix < NRKEYS) {
        int excl = blockoff[blockIdx.x] + s[t] - v;
        row_ptr[ix] = excl;
        cursor[ix]  = excl;
        if (ix == NRKEYS-1) row_ptr[NRKEYS] = excl + v;
    }
}

__global__ void fill_kernel(const int* __restrict__ ei, const int* __restrict__ et,
                            int* __restrict__ cursor, int* __restrict__ csr_src)
{
    int e = blockIdx.x*256 + threadIdx.x;
    if (e >= E_EDGES) return;
    int src = ei[e];
    int dst = ei[E_EDGES + e];
    int key = dst*R_REL + et[e];
    int pos = atomicAdd(&cursor[key], 1);
    csr_src[pos] = src;
}

// ---------------- fused weight prep (r11): 7 small kernels -> 1 dispatch ----------------
// Linear-index range dispatch over 8,826,880 elements; divergence only at the
// 6 segment boundaries. Replaces make_b1t/b2t/b3t + cvt(W_ih,W_hh,hprev,x),
// cutting 6 serial launch gaps from the graph. Memory work identical.
#define PREP_S0  163840    // B1t  256*640
#define PREP_S1  327680    // B2t  256*1280
#define PREP_S2  262144    // B3t  1024*256
#define PREP_S3  196608    // Biht 768*256
#define PREP_S4  196608    // Bhht 768*256
#define PREP_S5  5120000   // hprev_bf N*256
#define PREP_S6  2560000   // xbf  N*128
#define PREP_TOTAL (PREP_S0+PREP_S1+PREP_S2+PREP_S3+PREP_S4+PREP_S5+PREP_S6)

__global__ __launch_bounds__(256) void prep_all(
    const float* __restrict__ root1, const float* __restrict__ W1,
    const float* __restrict__ root2, const float* __restrict__ W2,
    const float* __restrict__ Wq, const float* __restrict__ Wk,
    const float* __restrict__ Wv, const float* __restrict__ Wsk,
    const float* __restrict__ bq, const float* __restrict__ bk,
    const float* __restrict__ bv, const float* __restrict__ bsk,
    const float* __restrict__ W_ih, const float* __restrict__ W_hh,
    const float* __restrict__ hprev, const float* __restrict__ x,
    __hip_bfloat16* __restrict__ B1t, __hip_bfloat16* __restrict__ B2t,
    __hip_bfloat16* __restrict__ B3t, float* __restrict__ bias3,
    __hip_bfloat16* __restrict__ Biht, __hip_bfloat16* __restrict__ Bhht,
    __hip_bfloat16* __restrict__ hprev_bf, __hip_bfloat16* __restrict__ xbf)
{
    int idx = blockIdx.x*256 + threadIdx.x;
    if (idx < PREP_S0) {                       // B1t: n*640+k
        int n = idx / 640, k = idx % 640;
        float v = (k < 128) ? root1[k*256 + n] : W1[(k-128)*256 + n];
        B1t[idx] = f2bf(v);
        return;
    }
    idx -= PREP_S0;
    if (idx < PREP_S1) {                       // B2t: n*1280+k
        int n = idx / 1280, k = idx % 1280;
        float v = (k < 256) ? root2[k*256 + n] : W2[(k-256)*256 + n];
        B2t[idx] = f2bf(v);
        return;
    }
    idx -= PREP_S1;
    if (idx < PREP_S2) {                       // B3t: n*256+k (+bias3)
        int n = idx / 256, k = idx % 256;
        int g = n >> 8, nn = n & 255;
        const float* W = (g==0)?Wq:(g==1)?Wk:(g==2)?Wv:Wsk;
        B3t[idx] = f2bf(W[k*256 + nn]);
        if (k == 0) {
            const float* B = (g==0)?bq:(g==1)?bk:(g==2)?bv:bsk;
            bias3[n] = B[nn];
        }
        return;
    }
    idx -= PREP_S2;
    if (idx < PREP_S3) { Biht[idx] = f2bf(W_ih[idx]); return; }
    idx -= PREP_S3;
    if (idx < PREP_S4) { Bhht[idx] = f2bf(W_hh[idx]); return; }
    idx -= PREP_S4;
    if (idx < PREP_S5) { hprev_bf[idx] = f2bf(hprev[idx]); return; }
    idx -= PREP_S5;
    if (idx < PREP_S6) { xbf[idx] = f2bf(x[idx]); }
}

// ---------------- RGCN aggregation: one WAVE per (node,rel) key ----------------
__global__ __launch_bounds__(256) void agg1_kernel(const __hip_bfloat16* __restrict__ xbf,
                                                   const int* __restrict__ row_ptr,
                                                   const int* __restrict__ csr_src,
                                                   __hip_bfloat16* __restrict__ A1)
{
    int b = blockIdx.x*4 + (threadIdx.x >> 6);   // key = i*4 + r
    int lane = threadIdx.x & 63;
    int i = b >> 2, r = b & 3;
    int e0 = row_ptr[b], e1 = row_ptr[b+1];
    float sx0=0.f,sy0=0.f, sx1=0.f,sy1=0.f, sx2=0.f,sy2=0.f, sx3=0.f,sy3=0.f;
    int e = e0;
    for (; e+4 <= e1; e += 4) {
        int i0=csr_src[e], i1=csr_src[e+1], i2=csr_src[e+2], i3=csr_src[e+3];
        unsigned u0 = *(const unsigned*)(xbf + (size_t)i0*IN_F + lane*2);
        unsigned u1 = *(const unsigned*)(xbf + (size_t)i1*IN_F + lane*2);
        unsigned u2 = *(const unsigned*)(xbf + (size_t)i2*IN_F + lane*2);
        unsigned u3 = *(const unsigned*)(xbf + (size_t)i3*IN_F + lane*2);
        sx0+=bfbits2f((unsigned short)u0); sy0+=bfbits2f((unsigned short)(u0>>16));
        sx1+=bfbits2f((unsigned short)u1); sy1+=bfbits2f((unsigned short)(u1>>16));
        sx2+=bfbits2f((unsigned short)u2); sy2+=bfbits2f((unsigned short)(u2>>16));
        sx3+=bfbits2f((unsigned short)u3); sy3+=bfbits2f((unsigned short)(u3>>16));
    }
    for (; e < e1; e++) {
        int i0 = csr_src[e];
        unsigned u = *(const unsigned*)(xbf + (size_t)i0*IN_F + lane*2);
        sx0+=bfbits2f((unsigned short)u); sy0+=bfbits2f((unsigned short)(u>>16));
    }
    float sx = (sx0+sx1)+(sx2+sx3);
    float sy = (sy0+sy1)+(sy2+sy3);
    float inv = (e1>e0) ? 1.f/(float)(e1-e0) : 0.f;
    *(unsigned*)(A1 + (size_t)i*640 + 128 + r*128 + lane*2) = pack_bf2(sx*inv, sy*inv);
    if (r == 0)   // root copy: already bf16, straight 4B copy
        *(unsigned*)(A1 + (size_t)i*640 + lane*2) = *(const unsigned*)(xbf + (size_t)i*IN_F + lane*2);
}

// agg2: h1 bf16 in A2 cols 0..255 (ld 1280); lane covers dims 4*lane..4*lane+3 (8 B).
__global__ __launch_bounds__(256) void agg2_kernel(const int* __restrict__ row_ptr,
                                                   const int* __restrict__ csr_src,
                                                   __hip_bfloat16* __restrict__ A2)
{
    int b = blockIdx.x*4 + (threadIdx.x >> 6);
    int lane = threadIdx.x & 63;
    int i = b >> 2, r = b & 3;
    int e0 = row_ptr[b], e1 = row_ptr[b+1];
    float a0=0.f,a1=0.f,a2=0.f,a3=0.f;
    float b0=0.f,b1=0.f,b2=0.f,b3=0.f;
    float c0=0.f,c1=0.f,c2=0.f,c3=0.f;
    float d0=0.f,d1=0.f,d2=0.f,d3=0.f;
    int e = e0;
    for (; e+4 <= e1; e += 4) {
        int i0=csr_src[e], i1=csr_src[e+1], i2=csr_src[e+2], i3=csr_src[e+3];
        ushort4 u0 = *(const ushort4*)(A2 + (size_t)i0*1280 + lane*4);
        ushort4 u1 = *(const ushort4*)(A2 + (size_t)i1*1280 + lane*4);
        ushort4 u2 = *(const ushort4*)(A2 + (size_t)i2*1280 + lane*4);
        ushort4 u3 = *(const ushort4*)(A2 + (size_t)i3*1280 + lane*4);
        a0+=bfbits2f(u0.x); a1+=bfbits2f(u0.y); a2+=bfbits2f(u0.z); a3+=bfbits2f(u0.w);
        b0+=bfbits2f(u1.x); b1+=bfbits2f(u1.y); b2+=bfbits2f(u1.z); b3+=bfbits2f(u1.w);
        c0+=bfbits2f(u2.x); c1+=bfbits2f(u2.y); c2+=bfbits2f(u2.z); c3+=bfbits2f(u2.w);
        d0+=bfbits2f(u3.x); d1+=bfbits2f(u3.y); d2+=bfbits2f(u3.z); d3+=bfbits2f(u3.w);
    }
    for (; e < e1; e++) {
        int i0 = csr_src[e];
        ushort4 u = *(const ushort4*)(A2 + (size_t)i0*1280 + lane*4);
        a0+=bfbits2f(u.x); a1+=bfbits2f(u.y); a2+=bfbits2f(u.z); a3+=bfbits2f(u.w);
    }
    float s0=(a0+b0)+(c0+d0), s1=(a1+b1)+(c1+d1), s2=(a2+b2)+(c2+d2), s3=(a3+b3)+(c3+d3);
    float inv = (e1>e0) ? 1.f/(float)(e1-e0) : 0.f;
    uint2 w;
    w.x = pack_bf2(s0*inv, s1*inv);
    w.y = pack_bf2(s2*inv, s3*inv);
    *(uint2*)(A2 + (size_t)i*1280 + 256 + r*256 + lane*4) = w;
}

// ---------------- LDS-pipelined GEMM (r2 config: best measured) ----------------
template<int MI>
__device__ __forceinline__ void gemm_bt_body(const __hip_bfloat16* __restrict__ A, int lda,
                                             const __hip_bfloat16* __restrict__ Bt,
                                             const float* __restrict__ bias,
                                             __hip_bfloat16* __restrict__ C, int ldc,
                                             int M, int K, int relu,
                                             int tile_m, int tile_n,
                                             __hip_bfloat16* lds_a, __hip_bfloat16* lds_b)
{
    constexpr int A_ELEMS = MI*1024;
    constexpr int B_ELEMS = 4096;
    constexpr int L = MI/2 + 2;
    const int tid  = threadIdx.x;
    const int wave = tid >> 6;
    const int lane = tid & 63;
    const int wm = wave >> 1, wn = wave & 1;
    const int fm = lane & 15;
    const int q  = lane >> 4;
    const int sw = (q ^ ((fm >> 1) & 3)) * 8;

    floatx4 acc[MI][4];
    #pragma unroll
    for (int i=0;i<MI;i++)
        #pragma unroll
        for (int j=0;j<4;j++) acc[i][j] = (floatx4){0.f,0.f,0.f,0.f};

    const int srow   = lane >> 2;
    const int schunk = lane & 3;
    size_t a_goff[MI/2];
    #pragma unroll
    for (int s = 0; s < MI/2; ++s) {
        int r = (s*4 + wave)*16 + srow;
        int c = schunk ^ ((r >> 1) & 3);
        a_goff[s] = (size_t)min(tile_m + r, M-1)*lda + c*8;
    }
    size_t b_goff[2];
    #pragma unroll
    for (int s = 0; s < 2; ++s) {
        int r = (s*4 + wave)*16 + srow;
        int c = schunk ^ ((r >> 1) & 3);
        b_goff[s] = (size_t)(tile_n + r)*K + c*8;
    }

    const int nt = K >> 5;

    auto issue = [&](int t, int bufi) {
        const int kn = t << 5;
        #pragma unroll
        for (int s = 0; s < MI/2; ++s)
            gload_lds16(A + a_goff[s] + kn, lds_a + bufi*A_ELEMS + (s*4 + wave)*512);
        #pragma unroll
        for (int s = 0; s < 2; ++s)
            gload_lds16(Bt + b_goff[s] + kn, lds_b + bufi*B_ELEMS + (s*4 + wave)*512);
    };

    issue(0, 0);
    if (nt > 1) { issue(1, 1); wait_vm<L>(); }
    else        { wait_vm<0>(); }
    __builtin_amdgcn_s_barrier();

    int cur = 0, nx2 = 2;
    for (int t = 0; t < nt; ++t) {
        if (t + 2 < nt) issue(t + 2, nx2);

        const __hip_bfloat16* la = lds_a + cur*A_ELEMS;
        const __hip_bfloat16* lb = lds_b + cur*B_ELEMS;
        short8 afr[MI], bfr[4];
        #pragma unroll
        for (int i=0;i<MI;i++)
            afr[i] = *(const short8*)(la + (wm*(MI*16) + i*16 + fm)*32 + sw);
        #pragma unroll
        for (int j=0;j<4;j++)
            bfr[j] = *(const short8*)(lb + (wn*64 + j*16 + fm)*32 + sw);

        __builtin_amdgcn_s_setprio(1);
        #pragma unroll
        for (int i=0;i<MI;i++)
            #pragma unroll
            for (int j=0;j<4;j++)
                acc[i][j] = __builtin_amdgcn_mfma_f32_16x16x32_bf16(afr[i], bfr[j], acc[i][j], 0,0,0);
        __builtin_amdgcn_s_setprio(0);

        if (t + 1 < nt) {
            if (t + 2 < nt) wait_vm<L>();
            else            wait_vm<0>();
            __builtin_amdgcn_s_barrier();
            cur = (cur == 2) ? 0 : cur + 1;
            nx2 = (nx2 == 2) ? 0 : nx2 + 1;
        }
    }

    const int crow_base = tile_m + wm*(MI*16);
    const int ccol_base = tile_n + wn*64;
    #pragma unroll
    for (int i=0;i<MI;i++) {
        #pragma unroll
        for (int j=0;j<4;j++) {
            int c  = ccol_base + j*16 + fm;
            float bb = bias[c];
            #pragma unroll
            for (int rg=0; rg<4; rg++) {
                int r = crow_base + i*16 + q*4 + rg;
                if (r < M) {
                    float v = acc[i][j][rg] + bb;
                    if (relu) v = fmaxf(v, 0.f);
                    C[(size_t)r*ldc + c] = f2bf(v);
                }
            }
        }
    }
}

template<int MI>
__global__ __launch_bounds__(256) void gemm_bt_t(const __hip_bfloat16* __restrict__ A, int lda,
                                                 const __hip_bfloat16* __restrict__ Bt,
                                                 const float* __restrict__ bias,
                                                 __hip_bfloat16* __restrict__ C, int ldc,
                                                 int M, int K, int relu)
{
    __shared__ __align__(16) __hip_bfloat16 lds_a[3*MI*1024];
    __shared__ __align__(16) __hip_bfloat16 lds_b[3*4096];
    int2 xy = xcd_swizzle();
    gemm_bt_body<MI>(A, lda, Bt, bias, C, ldc, M, K, relu,
                     xy.x*(MI*32), xy.y*128, lds_a, lds_b);
}

// ---------------- fused GRU gate-GEMM + elementwise (r7 final: best measured 48.9us) ----------------
__global__ __launch_bounds__(512) void gemm_gru_fused(
    const __hip_bfloat16* __restrict__ A0,   // hatt bf16 [N,256]
    const __hip_bfloat16* __restrict__ A1,   // hprev bf16 [N,256]
    const __hip_bfloat16* __restrict__ Bt0,  // W_ih [768][256]
    const __hip_bfloat16* __restrict__ Bt1,  // W_hh [768][256]
    const float* __restrict__ b_ih, const float* __restrict__ b_hh,
    const float* __restrict__ hprev, float* __restrict__ out)
{
    constexpr int BUF_ELEMS = 20480;  // A 256x32 (8192) + B 384x32 (12288)
    __shared__ __align__(16) __hip_bfloat16 lds[2*BUF_ELEMS];   // 80 KB
    int2 xy = xcd_swizzle();          // grid (157, 4), y = 64-channel chunk
    const int tile_m = xy.x * 128;
    const int c0     = xy.y * 64;
    const int tid = threadIdx.x, wave = tid >> 6, lane = tid & 63;
    const int wm = wave >> 1, wn = wave & 1;     // 4x2 wave grid: 32 rows x 32 ch
    const int fm = lane & 15, q = lane >> 4;
    const int sw = (q ^ ((fm >> 1) & 3)) * 8;

    const int sub = lane >> 2, ch = lane & 3;
    const __hip_bfloat16* gsrc[5];
    int dstoff[5];
    #pragma unroll
    for (int s = 0; s < 5; ++s) {
        int seg = wave*5 + s;                        // 0..39
        if (seg < 16) {
            int fr = seg*16 + sub;                   // 0..255
            int mat = fr >> 7, rl = fr & 127;
            int c = ch ^ ((fr >> 1) & 3);
            int grow = min(tile_m + rl, N_NODES-1);
            gsrc[s] = (mat ? A1 : A0) + (size_t)grow*256 + c*8;
            dstoff[s] = seg*512;
        } else {
            int fs = seg - 16;
            int fr = fs*16 + sub;                    // 0..383
            int grp = fr >> 6, ri = fr & 63;         // grp = mat*3 + gate
            int mat = grp >= 3, gate = mat ? grp-3 : grp;
            int c = ch ^ ((fr >> 1) & 3);
            int grow = gate*256 + c0 + ri;
            gsrc[s] = (mat ? Bt1 : Bt0) + (size_t)grow*256 + c*8;
            dstoff[s] = 8192 + fs*512;
        }
    }

    floatx4 acc[2][3][2][2];   // [mat][gate][row frag][col frag]
    #pragma unroll
    for (int m=0;m<2;m++)
        #pragma unroll
        for (int g=0;g<3;g++)
            #pragma unroll
            for (int i=0;i<2;i++)
                #pragma unroll
                for (int f=0;f<2;f++) acc[m][g][i][f] = (floatx4){0.f,0.f,0.f,0.f};

    auto issue = [&](int t, int bufi) {
        const int kn = t << 5;
        #pragma unroll
        for (int s = 0; s < 5; ++s)
            gload_lds16(gsrc[s] + kn, lds + bufi*BUF_ELEMS + dstoff[s]);
    };

    issue(0, 0);
    issue(1, 1);
    wait_vm<5>();                      // batch 0 landed; batch 1 in flight
    __builtin_amdgcn_s_barrier();

    #pragma unroll 1
    for (int t = 0; t < 8; ++t) {
        const __hip_bfloat16* lb = lds + (t & 1)*BUF_ELEMS;
        short8 af[2][2], bfr[2][3][2];
        #pragma unroll
        for (int m=0;m<2;m++)
            #pragma unroll
            for (int i=0;i<2;i++)
                af[m][i] = *(const short8*)(lb + (m*128 + wm*32 + i*16 + fm)*32 + sw);
        #pragma unroll
        for (int m=0;m<2;m++)
            #pragma unroll
            for (int g=0;g<3;g++)
                #pragma unroll
                for (int f=0;f<2;f++)
                    bfr[m][g][f] = *(const short8*)(lb + 8192 + (((m*3+g)*64 + wn*32 + f*16 + fm)*32) + sw);

        __builtin_amdgcn_s_setprio(1);
        #pragma unroll
        for (int m=0;m<2;m++)
            #pragma unroll
            for (int g=0;g<3;g++)
                #pragma unroll
                for (int i=0;i<2;i++)
                    #pragma unroll
                    for (int f=0;f<2;f++)
                        acc[m][g][i][f] = __builtin_amdgcn_mfma_f32_16x16x32_bf16(af[m][i], bfr[m][g][f], acc[m][g][i][f], 0,0,0);
        __builtin_amdgcn_s_setprio(0);

        if (t + 1 < 8) {
            __builtin_amdgcn_s_barrier();            // all waves done reading buf[t&1]
            if (t + 2 < 8) { issue(t + 2, t & 1); wait_vm<5>(); }  // t+1 landed, t+2 in flight
            else           wait_vm<0>();                           // tail drain
            __builtin_amdgcn_s_barrier();            // everyone's batch t+1 visible
        }
    }

    // epilogue: GRU math (exp-based sigmoid/tanh), write fp32 out only
    #pragma unroll
    for (int f=0; f<2; ++f) {
        int c = c0 + wn*32 + f*16 + fm;
        float bir = b_ih[c], biz = b_ih[256+c], bin = b_ih[512+c];
        float bhr = b_hh[c], bhz = b_hh[256+c], bhn = b_hh[512+c];
        #pragma unroll
        for (int i=0; i<2; ++i) {
            #pragma unroll
            for (int rg=0; rg<4; ++rg) {
                int r = tile_m + wm*32 + i*16 + q*4 + rg;
                if (r < N_NODES) {
                    float gir = acc[0][0][i][f][rg] + bir;
                    float giz = acc[0][1][i][f][rg] + biz;
                    float gin = acc[0][2][i][f][rg] + bin;
                    float ghr = acc[1][0][i][f][rg] + bhr;
                    float ghz = acc[1][1][i][f][rg] + bhz;
                    float ghn = acc[1][2][i][f][rg] + bhn;
                    float rr = 1.f/(1.f + __expf(-(gir + ghr)));
                    float zz = 1.f/(1.f + __expf(-(giz + ghz)));
                    float xn = gin + rr*ghn;
                    float e2 = __expf(xn + xn);
                    float nn = 1.f - 2.f/(e2 + 1.f);   // tanh(xn)
                    float h  = hprev[(size_t)r*256 + c];
                    out[(size_t)r*256 + c] = (1.f - zz)*nn + zz*h;
                }
            }
        }
    }
}

// ---------------- fused attention (r10 final): online softmax, unroll-4 ----------------
__global__ __launch_bounds__(256) void attn_fused_kernel(
    const __hip_bfloat16* __restrict__ qkvs,
    const int* __restrict__ row_ptr,
    const int* __restrict__ csr_src,
    __hip_bfloat16* __restrict__ hatt)
{
    int i = blockIdx.x*4 + (threadIdx.x >> 6);   // node (4 nodes per block)
    int lane = threadIdx.x & 63;
    int e0 = row_ptr[i*R_REL], e1 = row_ptr[i*R_REL + R_REL];

    ushort4 qv = *(const ushort4*)(qkvs + (size_t)i*1024 + lane*4);
    float qx=bfbits2f(qv.x), qy=bfbits2f(qv.y), qz=bfbits2f(qv.z), qw=bfbits2f(qv.w);

    float m = -1e30f, denom = 0.f;
    float ax=0.f, ay=0.f, az=0.f, aw=0.f;

    int j = e0;
    for (; j+4 <= e1; j += 4) {
        int s0 = csr_src[j],   s1 = csr_src[j+1];
        int s2 = csr_src[j+2], s3 = csr_src[j+3];
        const __hip_bfloat16* r0 = qkvs + (size_t)s0*1024;
        const __hip_bfloat16* r1 = qkvs + (size_t)s1*1024;
        const __hip_bfloat16* r2 = qkvs + (size_t)s2*1024;
        const __hip_bfloat16* r3 = qkvs + (size_t)s3*1024;
        ushort4 k0 = *(const ushort4*)(r0 + 256 + lane*4);
        ushort4 k1 = *(const ushort4*)(r1 + 256 + lane*4);
        ushort4 k2 = *(const ushort4*)(r2 + 256 + lane*4);
        ushort4 k3 = *(const ushort4*)(r3 + 256 + lane*4);
        ushort4 v0 = *(const ushort4*)(r0 + 512 + lane*4);   // issued before reduce
        ushort4 v1 = *(const ushort4*)(r1 + 512 + lane*4);
        ushort4 v2 = *(const ushort4*)(r2 + 512 + lane*4);
        ushort4 v3 = *(const ushort4*)(r3 + 512 + lane*4);
        float d0 = qx*bfbits2f(k0.x)+qy*bfbits2f(k0.y)+qz*bfbits2f(k0.z)+qw*bfbits2f(k0.w);
        float d1 = qx*bfbits2f(k1.x)+qy*bfbits2f(k1.y)+qz*bfbits2f(k1.z)+qw*bfbits2f(k1.w);
        float d2 = qx*bfbits2f(k2.x)+qy*bfbits2f(k2.y)+qz*bfbits2f(k2.z)+qw*bfbits2f(k2.w);
        float d3 = qx*bfbits2f(k3.x)+qy*bfbits2f(k3.y)+qz*bfbits2f(k3.z)+qw*bfbits2f(k3.w);
        #pragma unroll
        for (int o=1;o<16;o<<=1){
            d0 += __shfl_xor(d0,o,64); d1 += __shfl_xor(d1,o,64);
            d2 += __shfl_xor(d2,o,64); d3 += __shfl_xor(d3,o,64);
        }
        d0 *= 0.125f; d1 *= 0.125f; d2 *= 0.125f; d3 *= 0.125f;   // 1/sqrt(64)
        float mx = fmaxf(fmaxf(d0, d1), fmaxf(d2, d3));
        if (mx > m) {                    // rescale (rare after warm-up)
            float sc = __expf(m - mx);
            ax*=sc; ay*=sc; az*=sc; aw*=sc; denom*=sc;
            m = mx;
        }
        float w0 = __expf(d0 - m), w1 = __expf(d1 - m);
        float w2 = __expf(d2 - m), w3 = __expf(d3 - m);
        denom += (w0 + w1) + (w2 + w3);
        ax += w0*bfbits2f(v0.x) + w1*bfbits2f(v1.x) + w2*bfbits2f(v2.x) + w3*bfbits2f(v3.x);
        ay += w0*bfbits2f(v0.y) + w1*bfbits2f(v1.y) + w2*bfbits2f(v2.y) + w3*bfbits2f(v3.y);
        az += w0*bfbits2f(v0.z) + w1*bfbits2f(v1.z) + w2*bfbits2f(v2.z) + w3*bfbits2f(v3.z);
        aw += w0*bfbits2f(v0.w) + w1*bfbits2f(v1.w) + w2*bfbits2f(v2.w) + w3*bfbits2f(v3.w);
    }
    for (; j < e1; ++j) {
        int s0 = csr_src[j];
        const __hip_bfloat16* r0 = qkvs + (size_t)s0*1024;
        ushort4 k0 = *(const ushort4*)(r0 + 256 + lane*4);
        ushort4 v0 = *(const ushort4*)(r0 + 512 + lane*4);
        float d0 = qx*bfbits2f(k0.x)+qy*bfbits2f(k0.y)+qz*bfbits2f(k0.z)+qw*bfbits2f(k0.w);
        #pragma unroll
        for (int o=1;o<16;o<<=1) d0 += __shfl_xor(d0,o,64);
        d0 *= 0.125f;
        if (d0 > m) {
            float sc = __expf(m - d0);
            ax*=sc; ay*=sc; az*=sc; aw*=sc; denom*=sc;
            m = d0;
        }
        float w0 = __expf(d0 - m);
        denom += w0;
        ax += w0*bfbits2f(v0.x); ay += w0*bfbits2f(v0.y);
        az += w0*bfbits2f(v0.z); aw += w0*bfbits2f(v0.w);
    }

    float inv = 1.f / fmaxf(denom, 1e-16f);
    ushort4 sk = *(const ushort4*)(qkvs + (size_t)i*1024 + 768 + lane*4);
    uint2 w;
    w.x = pack_bf2(ax*inv + bfbits2f(sk.x), ay*inv + bfbits2f(sk.y));
    w.y = pack_bf2(az*inv + bfbits2f(sk.z), aw*inv + bfbits2f(sk.w));
    *(uint2*)(hatt + (size_t)i*256 + lane*4) = w;
}

// ---------------- launch ----------------
extern "C" void kernel_launch(void* const* d_in, const int* in_sizes, int n_in,
                              void* d_out, int out_size, void* d_ws, size_t ws_size,
                              hipStream_t stream)
{
    const float* x       = (const float*)d_in[0];
    const int* edge_index= (const int*)d_in[1];
    const int* edge_type = (const int*)d_in[2];
    const float* hprev   = (const float*)d_in[3];
    const float* W1      = (const float*)d_in[4];
    const float* root1   = (const float*)d_in[5];
    const float* b1      = (const float*)d_in[6];
    const float* W2      = (const float*)d_in[7];
    const float* root2   = (const float*)d_in[8];
    const float* b2      = (const float*)d_in[9];
    const float* Wq      = (const float*)d_in[10];
    const float* bq      = (const float*)d_in[11];
    const float* Wk      = (const float*)d_in[12];
    const float* bk      = (const float*)d_in[13];
    const float* Wv      = (const float*)d_in[14];
    const float* bv      = (const float*)d_in[15];
    const float* Wskip   = (const float*)d_in[16];
    const float* bskip   = (const float*)d_in[17];
    const float* W_ih    = (const float*)d_in[18];
    const float* b_ih    = (const float*)d_in[19];
    const float* W_hh    = (const float*)d_in[20];
    const float* b_hh    = (const float*)d_in[21];

    char* ws = (char*)d_ws;
    size_t off = 0;
    auto take = [&](size_t bytes)->char* {
        char* p = ws + off;
        off = (off + bytes + 255) & ~(size_t)255;
        return p;
    };
    int* cnt        = (int*)take((size_t)NRKEYS*4);
    int* row_ptr    = (int*)take((size_t)(NRKEYS+1)*4);
    int* cursor     = (int*)take((size_t)NRKEYS*4);
    int* csr_src    = (int*)take((size_t)E_EDGES*4);
    int* blocksum   = (int*)take((size_t)SCAN_BLOCKS*4);
    int* blockoff   = (int*)take((size_t)(SCAN_BLOCKS+1)*4);
    __hip_bfloat16* B1t   = (__hip_bfloat16*)take((size_t)256*640*2);
    __hip_bfloat16* B2t   = (__hip_bfloat16*)take((size_t)256*1280*2);
    __hip_bfloat16* B3t   = (__hip_bfloat16*)take((size_t)1024*256*2);
    __hip_bfloat16* Biht  = (__hip_bfloat16*)take((size_t)768*256*2);
    __hip_bfloat16* Bhht  = (__hip_bfloat16*)take((size_t)768*256*2);
    float*          bias3 = (float*)take((size_t)1024*4);
    __hip_bfloat16* hprev_bf = (__hip_bfloat16*)take((size_t)N_NODES*256*2);
    __hip_bfloat16* xbf      = (__hip_bfloat16*)take((size_t)N_NODES*IN_F*2);
    char* P1 = take((size_t)N_NODES*640*2);
    char* P2 = take((size_t)N_NODES*1536*2);

    __hip_bfloat16* A1   = (__hip_bfloat16*)P1;   // [N,640]  dead after gemm1
    __hip_bfloat16* h2   = (__hip_bfloat16*)P1;   // [N,256]  dead after gemm3
    __hip_bfloat16* hatt = (__hip_bfloat16*)P1;   // [N,256]  read by fused GRU
    __hip_bfloat16* A2   = (__hip_bfloat16*)P2;   // [N,1280] dead after gemm2
    __hip_bfloat16* qkvs = (__hip_bfloat16*)P2;   // [N,1024] dead after attn_fused

    hipMemsetAsync(cnt, 0, (size_t)NRKEYS*4, stream);
    count_kernel<<<(E_EDGES+255)/256, 256, 0, stream>>>(edge_index, edge_type, cnt);
    scan_reduce_kernel<<<SCAN_BLOCKS, 1024, 0, stream>>>(cnt, blocksum);
    scan_sums_kernel<<<1, 128, 0, stream>>>(blocksum, blockoff);
    scan_apply_kernel<<<SCAN_BLOCKS, 1024, 0, stream>>>(cnt, blockoff, row_ptr, cursor);
    fill_kernel<<<(E_EDGES+255)/256, 256, 0, stream>>>(edge_index, edge_type, cursor, csr_src);

    // all weight prep + fp32->bf16 converts in ONE dispatch (was 7)
    prep_all<<<(PREP_TOTAL+255)/256, 256, 0, stream>>>(
        root1, W1, root2, W2, Wq, Wk, Wv, Wskip, bq, bk, bv, bskip,
        W_ih, W_hh, hprev, x,
        B1t, B2t, B3t, bias3, Biht, Bhht, hprev_bf, xbf);

    agg1_kernel<<<NRKEYS/4, 256, 0, stream>>>(xbf, row_ptr, csr_src, A1);

    // h1 = relu(A1 * B1) written into A2 cols 0..255 (ldc=1280)
    dim3 g12(313, 2);
    gemm_bt_t<2><<<g12, 256, 0, stream>>>(A1, 640, B1t, b1, A2, 1280, N_NODES, 640, 1);

    agg2_kernel<<<NRKEYS/4, 256, 0, stream>>>(row_ptr, csr_src, A2);

    // h2 overwrites A1 (dead) in P1
    gemm_bt_t<2><<<g12, 256, 0, stream>>>(A2, 1280, B2t, b2, h2, 256, N_NODES, 1280, 1);

    // qkvs overwrites A2 (dead) in P2
    dim3 g3(157, 8);
    gemm_bt_t<4><<<g3, 256, 0, stream>>>(h2, 256, B3t, bias3, qkvs, 1024, N_NODES, 256, 0);

    // fused attention: one pass over edges, online softmax (unroll-4)
    attn_fused_kernel<<<N_NODES/4, 256, 0, stream>>>(qkvs, row_ptr, csr_src, hatt);

    // fused GRU gate-GEMMs + elementwise (r7 final: 512 threads, 128x64 tiles)
    gemm_gru_fused<<<dim3(157, 4), 512, 0, stream>>>(hatt, hprev_bf, Biht, Bhht,
                                                     b_ih, b_hh, hprev, (float*)d_out);
}

// Round 13
// 401.089 us; speedup vs baseline: 1.0822x; 1.0099x over previous
//
#include <hip/hip_runtime.h>
#include <hip/hip_bf16.h>
#include <stdint.h>

#define N_NODES 20000
#define E_EDGES 320000
#define IN_F    128
#define HIDF    256
#define R_REL   4
#define NRKEYS  (N_NODES*R_REL)   // 80000
#define SCAN_BLOCKS 80            // 80*1024 = 81920 >= NRKEYS

typedef __attribute__((ext_vector_type(8))) short  short8;
typedef __attribute__((ext_vector_type(4))) float  floatx4;

__device__ __forceinline__ float bf2f(__hip_bfloat16 v){ return __bfloat162float(v); }
__device__ __forceinline__ __hip_bfloat16 f2bf(float v){ return __float2bfloat16(v); }
__device__ __forceinline__ float bfbits2f(unsigned short u){ return __uint_as_float(((unsigned)u)<<16); }
__device__ __forceinline__ unsigned short f2bfbits(float v){
    __hip_bfloat16 h = __float2bfloat16(v);
    return *(unsigned short*)&h;
}
__device__ __forceinline__ unsigned pack_bf2(float a, float b){
    return (unsigned)f2bfbits(a) | ((unsigned)f2bfbits(b) << 16);
}

// async global->LDS, 16B per lane. LDS dest is WAVE-UNIFORM base (+lane*16 by HW);
// global src is per-lane (pre-swizzled to implement the LDS XOR layout).
__device__ __forceinline__ void gload_lds16(const void* g, void* l)
{
    __builtin_amdgcn_global_load_lds((const __attribute__((address_space(1))) void*)g,
                                     (__attribute__((address_space(3))) void*)l, 16, 0, 0);
}

template<int N>
__device__ __forceinline__ void wait_vm()
{
    if constexpr (N == 0)      asm volatile("s_waitcnt vmcnt(0)" ::: "memory");
    else if constexpr (N == 3) asm volatile("s_waitcnt vmcnt(3)" ::: "memory");
    else if constexpr (N == 4) asm volatile("s_waitcnt vmcnt(4)" ::: "memory");
    else if constexpr (N == 5) asm volatile("s_waitcnt vmcnt(5)" ::: "memory");
    else                       asm volatile("s_waitcnt vmcnt(0)" ::: "memory");
}

// bijective XCD-chunked swizzle (m204 formula). Verified r2: FETCH 63.6->17.3 MB.
// Convergence ledger: GEMM structure r2-r4 (triple-buffer/2-in-flight/vmcnt(L)
// optimal); fused-GRU r5-r8 (~49us gather-bound floor); attn r9-r10 (online-
// softmax fusion 85->50us, then flat at L3 random-gather service rate); aggs
// compulsory-gather-bound; launch gaps ~1.6us each (r12: prep fusion -9.7us).
__device__ __forceinline__ int2 xcd_swizzle()
{
    int gx = gridDim.x, gy = gridDim.y;
    int nwg = gx * gy;
    int lin = blockIdx.x + gx * blockIdx.y;
    int q = nwg >> 3, r = nwg & 7;
    int k = lin & 7, i = lin >> 3;
    int j = (k < r ? k*(q+1) : r*(q+1) + (k-r)*q) + i;
    return make_int2(j / gy, j % gy);   // (x tile, y tile), y fastest
}

// ---------------- CSR build ----------------
__global__ void count_kernel(const int* __restrict__ ei, const int* __restrict__ et,
                             int* __restrict__ cnt)
{
    int e = blockIdx.x*256 + threadIdx.x;
    if (e >= E_EDGES) return;
    int dst = ei[E_EDGES + e];
    atomicAdd(&cnt[dst*R_REL + et[e]], 1);
}

__global__ __launch_bounds__(1024) void scan_reduce_kernel(const int* __restrict__ cnt,
                                                           int* __restrict__ blocksum)
{
    int ix = blockIdx.x*1024 + threadIdx.x;
    int v = (ix < NRKEYS) ? cnt[ix] : 0;
    #pragma unroll
    for (int o=32;o>0;o>>=1) v += __shfl_xor(v, o, 64);
    __shared__ int wsum[16];
    int wave = threadIdx.x >> 6, lane = threadIdx.x & 63;
    if (lane == 0) wsum[wave] = v;
    __syncthreads();
    if (threadIdx.x == 0) {
        int s = 0;
        #pragma unroll
        for (int w=0;w<16;w++) s += wsum[w];
        blocksum[blockIdx.x] = s;
    }
}

// r13: scan_sums folded in — every block redundantly computes the 80-entry
// block-offset prefix via a 128-wide LDS scan (all threads hit the barriers).
// Removes one dispatch + its launch gap at ~zero added cost.
__global__ __launch_bounds__(1024) void scan_apply_kernel(const int* __restrict__ cnt,
                                                          const int* __restrict__ blocksum,
                                                          int* __restrict__ row_ptr,
                                                          int* __restrict__ cursor)
{
    __shared__ int s[1024];
    __shared__ int sb[128];
    int t = threadIdx.x;
    if (t < 128) sb[t] = (t < SCAN_BLOCKS) ? blocksum[t] : 0;
    int ix = blockIdx.x*1024 + t;
    int v = (ix < NRKEYS) ? cnt[ix] : 0;
    s[t] = v;
    __syncthreads();
    // inclusive scan of sb (block sums)
    for (int off=1; off<128; off<<=1) {
        int u = (t < 128 && t >= off) ? sb[t-off] : 0;
        __syncthreads();
        if (t < 128) sb[t] += u;
        __syncthreads();
    }
    // inclusive scan of s (this block's 1024 counts)
    for (int off=1; off<1024; off<<=1) {
        int u = (t>=off) ? s[t-off] : 0;
        __syncthreads();
        s[t] += u;
        __syncthreads();
    }
    if (ix < NRKEYS) {
        int boff = sb[blockIdx.x] - blocksum[blockIdx.x];   // exclusive block offset
        int excl = boff + s[t] - v;
        row_ptr[ix] = excl;
        cursor[ix]  = excl;
        if (ix == NRKEYS-1) row_ptr[NRKEYS] = excl + v;
    }
}

__global__ void fill_kernel(const int* __restrict__ ei, const int* __restrict__ et,
                            int* __restrict__ cursor, int* __restrict__ csr_src)
{
    int e = blockIdx.x*256 + threadIdx.x;
    if (e >= E_EDGES) return;
    int src = ei[e];
    int dst = ei[E_EDGES + e];
    int key = dst*R_REL + et[e];
    int pos = atomicAdd(&cursor[key], 1);
    csr_src[pos] = src;
}

// ---------------- fused weight prep (r11/r13): 7 kernels + memset -> 1 dispatch ----------------
// Linear-index range dispatch; divergence only at segment boundaries. r13 adds
// the cnt zeroing segment (replaces hipMemsetAsync; prep_all now runs FIRST).
#define PREP_S0  163840    // B1t  256*640
#define PREP_S1  327680    // B2t  256*1280
#define PREP_S2  262144    // B3t  1024*256
#define PREP_S3  196608    // Biht 768*256
#define PREP_S4  196608    // Bhht 768*256
#define PREP_S5  5120000   // hprev_bf N*256
#define PREP_S6  2560000   // xbf  N*128
#define PREP_S7  NRKEYS    // cnt zeroing
#define PREP_TOTAL (PREP_S0+PREP_S1+PREP_S2+PREP_S3+PREP_S4+PREP_S5+PREP_S6+PREP_S7)

__global__ __launch_bounds__(256) void prep_all(
    const float* __restrict__ root1, const float* __restrict__ W1,
    const float* __restrict__ root2, const float* __restrict__ W2,
    const float* __restrict__ Wq, const float* __restrict__ Wk,
    const float* __restrict__ Wv, const float* __restrict__ Wsk,
    const float* __restrict__ bq, const float* __restrict__ bk,
    const float* __restrict__ bv, const float* __restrict__ bsk,
    const float* __restrict__ W_ih, const float* __restrict__ W_hh,
    const float* __restrict__ hprev, const float* __restrict__ x,
    __hip_bfloat16* __restrict__ B1t, __hip_bfloat16* __restrict__ B2t,
    __hip_bfloat16* __restrict__ B3t, float* __restrict__ bias3,
    __hip_bfloat16* __restrict__ Biht, __hip_bfloat16* __restrict__ Bhht,
    __hip_bfloat16* __restrict__ hprev_bf, __hip_bfloat16* __restrict__ xbf,
    int* __restrict__ cnt)
{
    int idx = blockIdx.x*256 + threadIdx.x;
    if (idx < PREP_S0) {                       // B1t: n*640+k
        int n = idx / 640, k = idx % 640;
        float v = (k < 128) ? root1[k*256 + n] : W1[(k-128)*256 + n];
        B1t[idx] = f2bf(v);
        return;
    }
    idx -= PREP_S0;
    if (idx < PREP_S1) {                       // B2t: n*1280+k
        int n = idx / 1280, k = idx % 1280;
        float v = (k < 256) ? root2[k*256 + n] : W2[(k-256)*256 + n];
        B2t[idx] = f2bf(v);
        return;
    }
    idx -= PREP_S1;
    if (idx < PREP_S2) {                       // B3t: n*256+k (+bias3)
        int n = idx / 256, k = idx % 256;
        int g = n >> 8, nn = n & 255;
        const float* W = (g==0)?Wq:(g==1)?Wk:(g==2)?Wv:Wsk;
        B3t[idx] = f2bf(W[k*256 + nn]);
        if (k == 0) {
            const float* B = (g==0)?bq:(g==1)?bk:(g==2)?bv:bsk;
            bias3[n] = B[nn];
        }
        return;
    }
    idx -= PREP_S2;
    if (idx < PREP_S3) { Biht[idx] = f2bf(W_ih[idx]); return; }
    idx -= PREP_S3;
    if (idx < PREP_S4) { Bhht[idx] = f2bf(W_hh[idx]); return; }
    idx -= PREP_S4;
    if (idx < PREP_S5) { hprev_bf[idx] = f2bf(hprev[idx]); return; }
    idx -= PREP_S5;
    if (idx < PREP_S6) { xbf[idx] = f2bf(x[idx]); return; }
    idx -= PREP_S6;
    if (idx < PREP_S7) cnt[idx] = 0;
}

// ---------------- RGCN aggregation: one WAVE per (node,rel) key ----------------
__global__ __launch_bounds__(256) void agg1_kernel(const __hip_bfloat16* __restrict__ xbf,
                                                   const int* __restrict__ row_ptr,
                                                   const int* __restrict__ csr_src,
                                                   __hip_bfloat16* __restrict__ A1)
{
    int b = blockIdx.x*4 + (threadIdx.x >> 6);   // key = i*4 + r
    int lane = threadIdx.x & 63;
    int i = b >> 2, r = b & 3;
    int e0 = row_ptr[b], e1 = row_ptr[b+1];
    float sx0=0.f,sy0=0.f, sx1=0.f,sy1=0.f, sx2=0.f,sy2=0.f, sx3=0.f,sy3=0.f;
    int e = e0;
    for (; e+4 <= e1; e += 4) {
        int i0=csr_src[e], i1=csr_src[e+1], i2=csr_src[e+2], i3=csr_src[e+3];
        unsigned u0 = *(const unsigned*)(xbf + (size_t)i0*IN_F + lane*2);
        unsigned u1 = *(const unsigned*)(xbf + (size_t)i1*IN_F + lane*2);
        unsigned u2 = *(const unsigned*)(xbf + (size_t)i2*IN_F + lane*2);
        unsigned u3 = *(const unsigned*)(xbf + (size_t)i3*IN_F + lane*2);
        sx0+=bfbits2f((unsigned short)u0); sy0+=bfbits2f((unsigned short)(u0>>16));
        sx1+=bfbits2f((unsigned short)u1); sy1+=bfbits2f((unsigned short)(u1>>16));
        sx2+=bfbits2f((unsigned short)u2); sy2+=bfbits2f((unsigned short)(u2>>16));
        sx3+=bfbits2f((unsigned short)u3); sy3+=bfbits2f((unsigned short)(u3>>16));
    }
    for (; e < e1; e++) {
        int i0 = csr_src[e];
        unsigned u = *(const unsigned*)(xbf + (size_t)i0*IN_F + lane*2);
        sx0+=bfbits2f((unsigned short)u); sy0+=bfbits2f((unsigned short)(u>>16));
    }
    float sx = (sx0+sx1)+(sx2+sx3);
    float sy = (sy0+sy1)+(sy2+sy3);
    float inv = (e1>e0) ? 1.f/(float)(e1-e0) : 0.f;
    *(unsigned*)(A1 + (size_t)i*640 + 128 + r*128 + lane*2) = pack_bf2(sx*inv, sy*inv);
    if (r == 0)   // root copy: already bf16, straight 4B copy
        *(unsigned*)(A1 + (size_t)i*640 + lane*2) = *(const unsigned*)(xbf + (size_t)i*IN_F + lane*2);
}

// agg2: h1 bf16 in A2 cols 0..255 (ld 1280); lane covers dims 4*lane..4*lane+3 (8 B).
__global__ __launch_bounds__(256) void agg2_kernel(const int* __restrict__ row_ptr,
                                                   const int* __restrict__ csr_src,
                                                   __hip_bfloat16* __restrict__ A2)
{
    int b = blockIdx.x*4 + (threadIdx.x >> 6);
    int lane = threadIdx.x & 63;
    int i = b >> 2, r = b & 3;
    int e0 = row_ptr[b], e1 = row_ptr[b+1];
    float a0=0.f,a1=0.f,a2=0.f,a3=0.f;
    float b0=0.f,b1=0.f,b2=0.f,b3=0.f;
    float c0=0.f,c1=0.f,c2=0.f,c3=0.f;
    float d0=0.f,d1=0.f,d2=0.f,d3=0.f;
    int e = e0;
    for (; e+4 <= e1; e += 4) {
        int i0=csr_src[e], i1=csr_src[e+1], i2=csr_src[e+2], i3=csr_src[e+3];
        ushort4 u0 = *(const ushort4*)(A2 + (size_t)i0*1280 + lane*4);
        ushort4 u1 = *(const ushort4*)(A2 + (size_t)i1*1280 + lane*4);
        ushort4 u2 = *(const ushort4*)(A2 + (size_t)i2*1280 + lane*4);
        ushort4 u3 = *(const ushort4*)(A2 + (size_t)i3*1280 + lane*4);
        a0+=bfbits2f(u0.x); a1+=bfbits2f(u0.y); a2+=bfbits2f(u0.z); a3+=bfbits2f(u0.w);
        b0+=bfbits2f(u1.x); b1+=bfbits2f(u1.y); b2+=bfbits2f(u1.z); b3+=bfbits2f(u1.w);
        c0+=bfbits2f(u2.x); c1+=bfbits2f(u2.y); c2+=bfbits2f(u2.z); c3+=bfbits2f(u2.w);
        d0+=bfbits2f(u3.x); d1+=bfbits2f(u3.y); d2+=bfbits2f(u3.z); d3+=bfbits2f(u3.w);
    }
    for (; e < e1; e++) {
        int i0 = csr_src[e];
        ushort4 u = *(const ushort4*)(A2 + (size_t)i0*1280 + lane*4);
        a0+=bfbits2f(u.x); a1+=bfbits2f(u.y); a2+=bfbits2f(u.z); a3+=bfbits2f(u.w);
    }
    float s0=(a0+b0)+(c0+d0), s1=(a1+b1)+(c1+d1), s2=(a2+b2)+(c2+d2), s3=(a3+b3)+(c3+d3);
    float inv = (e1>e0) ? 1.f/(float)(e1-e0) : 0.f;
    uint2 w;
    w.x = pack_bf2(s0*inv, s1*inv);
    w.y = pack_bf2(s2*inv, s3*inv);
    *(uint2*)(A2 + (size_t)i*1280 + 256 + r*256 + lane*4) = w;
}

// ---------------- LDS-pipelined GEMM (r2 config: best measured) ----------------
template<int MI>
__device__ __forceinline__ void gemm_bt_body(const __hip_bfloat16* __restrict__ A, int lda,
                                             const __hip_bfloat16* __restrict__ Bt,
                                             const float* __restrict__ bias,
                                             __hip_bfloat16* __restrict__ C, int ldc,
                                             int M, int K, int relu,
                                             int tile_m, int tile_n,
                                             __hip_bfloat16* lds_a, __hip_bfloat16* lds_b)
{
    constexpr int A_ELEMS = MI*1024;
    constexpr int B_ELEMS = 4096;
    constexpr int L = MI/2 + 2;
    const int tid  = threadIdx.x;
    const int wave = tid >> 6;
    const int lane = tid & 63;
    const int wm = wave >> 1, wn = wave & 1;
    const int fm = lane & 15;
    const int q  = lane >> 4;
    const int sw = (q ^ ((fm >> 1) & 3)) * 8;

    floatx4 acc[MI][4];
    #pragma unroll
    for (int i=0;i<MI;i++)
        #pragma unroll
        for (int j=0;j<4;j++) acc[i][j] = (floatx4){0.f,0.f,0.f,0.f};

    const int srow   = lane >> 2;
    const int schunk = lane & 3;
    size_t a_goff[MI/2];
    #pragma unroll
    for (int s = 0; s < MI/2; ++s) {
        int r = (s*4 + wave)*16 + srow;
        int c = schunk ^ ((r >> 1) & 3);
        a_goff[s] = (size_t)min(tile_m + r, M-1)*lda + c*8;
    }
    size_t b_goff[2];
    #pragma unroll
    for (int s = 0; s < 2; ++s) {
        int r = (s*4 + wave)*16 + srow;
        int c = schunk ^ ((r >> 1) & 3);
        b_goff[s] = (size_t)(tile_n + r)*K + c*8;
    }

    const int nt = K >> 5;

    auto issue = [&](int t, int bufi) {
        const int kn = t << 5;
        #pragma unroll
        for (int s = 0; s < MI/2; ++s)
            gload_lds16(A + a_goff[s] + kn, lds_a + bufi*A_ELEMS + (s*4 + wave)*512);
        #pragma unroll
        for (int s = 0; s < 2; ++s)
            gload_lds16(Bt + b_goff[s] + kn, lds_b + bufi*B_ELEMS + (s*4 + wave)*512);
    };

    issue(0, 0);
    if (nt > 1) { issue(1, 1); wait_vm<L>(); }
    else        { wait_vm<0>(); }
    __builtin_amdgcn_s_barrier();

    int cur = 0, nx2 = 2;
    for (int t = 0; t < nt; ++t) {
        if (t + 2 < nt) issue(t + 2, nx2);

        const __hip_bfloat16* la = lds_a + cur*A_ELEMS;
        const __hip_bfloat16* lb = lds_b + cur*B_ELEMS;
        short8 afr[MI], bfr[4];
        #pragma unroll
        for (int i=0;i<MI;i++)
            afr[i] = *(const short8*)(la + (wm*(MI*16) + i*16 + fm)*32 + sw);
        #pragma unroll
        for (int j=0;j<4;j++)
            bfr[j] = *(const short8*)(lb + (wn*64 + j*16 + fm)*32 + sw);

        __builtin_amdgcn_s_setprio(1);
        #pragma unroll
        for (int i=0;i<MI;i++)
            #pragma unroll
            for (int j=0;j<4;j++)
                acc[i][j] = __builtin_amdgcn_mfma_f32_16x16x32_bf16(afr[i], bfr[j], acc[i][j], 0,0,0);
        __builtin_amdgcn_s_setprio(0);

        if (t + 1 < nt) {
            if (t + 2 < nt) wait_vm<L>();
            else            wait_vm<0>();
            __builtin_amdgcn_s_barrier();
            cur = (cur == 2) ? 0 : cur + 1;
            nx2 = (nx2 == 2) ? 0 : nx2 + 1;
        }
    }

    const int crow_base = tile_m + wm*(MI*16);
    const int ccol_base = tile_n + wn*64;
    #pragma unroll
    for (int i=0;i<MI;i++) {
        #pragma unroll
        for (int j=0;j<4;j++) {
            int c  = ccol_base + j*16 + fm;
            float bb = bias[c];
            #pragma unroll
            for (int rg=0; rg<4; rg++) {
                int r = crow_base + i*16 + q*4 + rg;
                if (r < M) {
                    float v = acc[i][j][rg] + bb;
                    if (relu) v = fmaxf(v, 0.f);
                    C[(size_t)r*ldc + c] = f2bf(v);
                }
            }
        }
    }
}

template<int MI>
__global__ __launch_bounds__(256) void gemm_bt_t(const __hip_bfloat16* __restrict__ A, int lda,
                                                 const __hip_bfloat16* __restrict__ Bt,
                                                 const float* __restrict__ bias,
                                                 __hip_bfloat16* __restrict__ C, int ldc,
                                                 int M, int K, int relu)
{
    __shared__ __align__(16) __hip_bfloat16 lds_a[3*MI*1024];
    __shared__ __align__(16) __hip_bfloat16 lds_b[3*4096];
    int2 xy = xcd_swizzle();
    gemm_bt_body<MI>(A, lda, Bt, bias, C, ldc, M, K, relu,
                     xy.x*(MI*32), xy.y*128, lds_a, lds_b);
}

// ---------------- fused GRU gate-GEMM + elementwise (r7 final: best measured 48.9us) ----------------
__global__ __launch_bounds__(512) void gemm_gru_fused(
    const __hip_bfloat16* __restrict__ A0,   // hatt bf16 [N,256]
    const __hip_bfloat16* __restrict__ A1,   // hprev bf16 [N,256]
    const __hip_bfloat16* __restrict__ Bt0,  // W_ih [768][256]
    const __hip_bfloat16* __restrict__ Bt1,  // W_hh [768][256]
    const float* __restrict__ b_ih, const float* __restrict__ b_hh,
    const float* __restrict__ hprev, float* __restrict__ out)
{
    constexpr int BUF_ELEMS = 20480;  // A 256x32 (8192) + B 384x32 (12288)
    __shared__ __align__(16) __hip_bfloat16 lds[2*BUF_ELEMS];   // 80 KB
    int2 xy = xcd_swizzle();          // grid (157, 4), y = 64-channel chunk
    const int tile_m = xy.x * 128;
    const int c0     = xy.y * 64;
    const int tid = threadIdx.x, wave = tid >> 6, lane = tid & 63;
    const int wm = wave >> 1, wn = wave & 1;     // 4x2 wave grid: 32 rows x 32 ch
    const int fm = lane & 15, q = lane >> 4;
    const int sw = (q ^ ((fm >> 1) & 3)) * 8;

    const int sub = lane >> 2, ch = lane & 3;
    const __hip_bfloat16* gsrc[5];
    int dstoff[5];
    #pragma unroll
    for (int s = 0; s < 5; ++s) {
        int seg = wave*5 + s;                        // 0..39
        if (seg < 16) {
            int fr = seg*16 + sub;                   // 0..255
            int mat = fr >> 7, rl = fr & 127;
            int c = ch ^ ((fr >> 1) & 3);
            int grow = min(tile_m + rl, N_NODES-1);
            gsrc[s] = (mat ? A1 : A0) + (size_t)grow*256 + c*8;
            dstoff[s] = seg*512;
        } else {
            int fs = seg - 16;
            int fr = fs*16 + sub;                    // 0..383
            int grp = fr >> 6, ri = fr & 63;         // grp = mat*3 + gate
            int mat = grp >= 3, gate = mat ? grp-3 : grp;
            int c = ch ^ ((fr >> 1) & 3);
            int grow = gate*256 + c0 + ri;
            gsrc[s] = (mat ? Bt1 : Bt0) + (size_t)grow*256 + c*8;
            dstoff[s] = 8192 + fs*512;
        }
    }

    floatx4 acc[2][3][2][2];   // [mat][gate][row frag][col frag]
    #pragma unroll
    for (int m=0;m<2;m++)
        #pragma unroll
        for (int g=0;g<3;g++)
            #pragma unroll
            for (int i=0;i<2;i++)
                #pragma unroll
                for (int f=0;f<2;f++) acc[m][g][i][f] = (floatx4){0.f,0.f,0.f,0.f};

    auto issue = [&](int t, int bufi) {
        const int kn = t << 5;
        #pragma unroll
        for (int s = 0; s < 5; ++s)
            gload_lds16(gsrc[s] + kn, lds + bufi*BUF_ELEMS + dstoff[s]);
    };

    issue(0, 0);
    issue(1, 1);
    wait_vm<5>();                      // batch 0 landed; batch 1 in flight
    __builtin_amdgcn_s_barrier();

    #pragma unroll 1
    for (int t = 0; t < 8; ++t) {
        const __hip_bfloat16* lb = lds + (t & 1)*BUF_ELEMS;
        short8 af[2][2], bfr[2][3][2];
        #pragma unroll
        for (int m=0;m<2;m++)
            #pragma unroll
            for (int i=0;i<2;i++)
                af[m][i] = *(const short8*)(lb + (m*128 + wm*32 + i*16 + fm)*32 + sw);
        #pragma unroll
        for (int m=0;m<2;m++)
            #pragma unroll
            for (int g=0;g<3;g++)
                #pragma unroll
                for (int f=0;f<2;f++)
                    bfr[m][g][f] = *(const short8*)(lb + 8192 + (((m*3+g)*64 + wn*32 + f*16 + fm)*32) + sw);

        __builtin_amdgcn_s_setprio(1);
        #pragma unroll
        for (int m=0;m<2;m++)
            #pragma unroll
            for (int g=0;g<3;g++)
                #pragma unroll
                for (int i=0;i<2;i++)
                    #pragma unroll
                    for (int f=0;f<2;f++)
                        acc[m][g][i][f] = __builtin_amdgcn_mfma_f32_16x16x32_bf16(af[m][i], bfr[m][g][f], acc[m][g][i][f], 0,0,0);
        __builtin_amdgcn_s_setprio(0);

        if (t + 1 < 8) {
            __builtin_amdgcn_s_barrier();            // all waves done reading buf[t&1]
            if (t + 2 < 8) { issue(t + 2, t & 1); wait_vm<5>(); }  // t+1 landed, t+2 in flight
            else           wait_vm<0>();                           // tail drain
            __builtin_amdgcn_s_barrier();            // everyone's batch t+1 visible
        }
    }

    // epilogue: GRU math (exp-based sigmoid/tanh), write fp32 out only
    #pragma unroll
    for (int f=0; f<2; ++f) {
        int c = c0 + wn*32 + f*16 + fm;
        float bir = b_ih[c], biz = b_ih[256+c], bin = b_ih[512+c];
        float bhr = b_hh[c], bhz = b_hh[256+c], bhn = b_hh[512+c];
        #pragma unroll
        for (int i=0; i<2; ++i) {
            #pragma unroll
            for (int rg=0; rg<4; ++rg) {
                int r = tile_m + wm*32 + i*16 + q*4 + rg;
                if (r < N_NODES) {
                    float gir = acc[0][0][i][f][rg] + bir;
                    float giz = acc[0][1][i][f][rg] + biz;
                    float gin = acc[0][2][i][f][rg] + bin;
                    float ghr = acc[1][0][i][f][rg] + bhr;
                    float ghz = acc[1][1][i][f][rg] + bhz;
                    float ghn = acc[1][2][i][f][rg] + bhn;
                    float rr = 1.f/(1.f + __expf(-(gir + ghr)));
                    float zz = 1.f/(1.f + __expf(-(giz + ghz)));
                    float xn = gin + rr*ghn;
                    float e2 = __expf(xn + xn);
                    float nn = 1.f - 2.f/(e2 + 1.f);   // tanh(xn)
                    float h  = hprev[(size_t)r*256 + c];
                    out[(size_t)r*256 + c] = (1.f - zz)*nn + zz*h;
                }
            }
        }
    }
}

// ---------------- fused attention (r10 final): online softmax, unroll-4 ----------------
__global__ __launch_bounds__(256) void attn_fused_kernel(
    const __hip_bfloat16* __restrict__ qkvs,
    const int* __restrict__ row_ptr,
    const int* __restrict__ csr_src,
    __hip_bfloat16* __restrict__ hatt)
{
    int i = blockIdx.x*4 + (threadIdx.x >> 6);   // node (4 nodes per block)
    int lane = threadIdx.x & 63;
    int e0 = row_ptr[i*R_REL], e1 = row_ptr[i*R_REL + R_REL];

    ushort4 qv = *(const ushort4*)(qkvs + (size_t)i*1024 + lane*4);
    float qx=bfbits2f(qv.x), qy=bfbits2f(qv.y), qz=bfbits2f(qv.z), qw=bfbits2f(qv.w);

    float m = -1e30f, denom = 0.f;
    float ax=0.f, ay=0.f, az=0.f, aw=0.f;

    int j = e0;
    for (; j+4 <= e1; j += 4) {
        int s0 = csr_src[j],   s1 = csr_src[j+1];
        int s2 = csr_src[j+2], s3 = csr_src[j+3];
        const __hip_bfloat16* r0 = qkvs + (size_t)s0*1024;
        const __hip_bfloat16* r1 = qkvs + (size_t)s1*1024;
        const __hip_bfloat16* r2 = qkvs + (size_t)s2*1024;
        const __hip_bfloat16* r3 = qkvs + (size_t)s3*1024;
        ushort4 k0 = *(const ushort4*)(r0 + 256 + lane*4);
        ushort4 k1 = *(const ushort4*)(r1 + 256 + lane*4);
        ushort4 k2 = *(const ushort4*)(r2 + 256 + lane*4);
        ushort4 k3 = *(const ushort4*)(r3 + 256 + lane*4);
        ushort4 v0 = *(const ushort4*)(r0 + 512 + lane*4);   // issued before reduce
        ushort4 v1 = *(const ushort4*)(r1 + 512 + lane*4);
        ushort4 v2 = *(const ushort4*)(r2 + 512 + lane*4);
        ushort4 v3 = *(const ushort4*)(r3 + 512 + lane*4);
        float d0 = qx*bfbits2f(k0.x)+qy*bfbits2f(k0.y)+qz*bfbits2f(k0.z)+qw*bfbits2f(k0.w);
        float d1 = qx*bfbits2f(k1.x)+qy*bfbits2f(k1.y)+qz*bfbits2f(k1.z)+qw*bfbits2f(k1.w);
        float d2 = qx*bfbits2f(k2.x)+qy*bfbits2f(k2.y)+qz*bfbits2f(k2.z)+qw*bfbits2f(k2.w);
        float d3 = qx*bfbits2f(k3.x)+qy*bfbits2f(k3.y)+qz*bfbits2f(k3.z)+qw*bfbits2f(k3.w);
        #pragma unroll
        for (int o=1;o<16;o<<=1){
            d0 += __shfl_xor(d0,o,64); d1 += __shfl_xor(d1,o,64);
            d2 += __shfl_xor(d2,o,64); d3 += __shfl_xor(d3,o,64);
        }
        d0 *= 0.125f; d1 *= 0.125f; d2 *= 0.125f; d3 *= 0.125f;   // 1/sqrt(64)
        float mx = fmaxf(fmaxf(d0, d1), fmaxf(d2, d3));
        if (mx > m) {                    // rescale (rare after warm-up)
            float sc = __expf(m - mx);
            ax*=sc; ay*=sc; az*=sc; aw*=sc; denom*=sc;
            m = mx;
        }
        float w0 = __expf(d0 - m), w1 = __expf(d1 - m);
        float w2 = __expf(d2 - m), w3 = __expf(d3 - m);
        denom += (w0 + w1) + (w2 + w3);
        ax += w0*bfbits2f(v0.x) + w1*bfbits2f(v1.x) + w2*bfbits2f(v2.x) + w3*bfbits2f(v3.x);
        ay += w0*bfbits2f(v0.y) + w1*bfbits2f(v1.y) + w2*bfbits2f(v2.y) + w3*bfbits2f(v3.y);
        az += w0*bfbits2f(v0.z) + w1*bfbits2f(v1.z) + w2*bfbits2f(v2.z) + w3*bfbits2f(v3.z);
        aw += w0*bfbits2f(v0.w) + w1*bfbits2f(v1.w) + w2*bfbits2f(v2.w) + w3*bfbits2f(v3.w);
    }
    for (; j < e1; ++j) {
        int s0 = csr_src[j];
        const __hip_bfloat16* r0 = qkvs + (size_t)s0*1024;
        ushort4 k0 = *(const ushort4*)(r0 + 256 + lane*4);
        ushort4 v0 = *(const ushort4*)(r0 + 512 + lane*4);
        float d0 = qx*bfbits2f(k0.x)+qy*bfbits2f(k0.y)+qz*bfbits2f(k0.z)+qw*bfbits2f(k0.w);
        #pragma unroll
        for (int o=1;o<16;o<<=1) d0 += __shfl_xor(d0,o,64);
        d0 *= 0.125f;
        if (d0 > m) {
            float sc = __expf(m - d0);
            ax*=sc; ay*=sc; az*=sc; aw*=sc; denom*=sc;
            m = d0;
        }
        float w0 = __expf(d0 - m);
        denom += w0;
        ax += w0*bfbits2f(v0.x); ay += w0*bfbits2f(v0.y);
        az += w0*bfbits2f(v0.z); aw += w0*bfbits2f(v0.w);
    }

    float inv = 1.f / fmaxf(denom, 1e-16f);
    ushort4 sk = *(const ushort4*)(qkvs + (size_t)i*1024 + 768 + lane*4);
    uint2 w;
    w.x = pack_bf2(ax*inv + bfbits2f(sk.x), ay*inv + bfbits2f(sk.y));
    w.y = pack_bf2(az*inv + bfbits2f(sk.z), aw*inv + bfbits2f(sk.w));
    *(uint2*)(hatt + (size_t)i*256 + lane*4) = w;
}

// ---------------- launch ----------------
extern "C" void kernel_launch(void* const* d_in, const int* in_sizes, int n_in,
                              void* d_out, int out_size, void* d_ws, size_t ws_size,
                              hipStream_t stream)
{
    const float* x       = (const float*)d_in[0];
    const int* edge_index= (const int*)d_in[1];
    const int* edge_type = (const int*)d_in[2];
    const float* hprev   = (const float*)d_in[3];
    const float* W1      = (const float*)d_in[4];
    const float* root1   = (const float*)d_in[5];
    const float* b1      = (const float*)d_in[6];
    const float* W2      = (const float*)d_in[7];
    const float* root2   = (const float*)d_in[8];
    const float* b2      = (const float*)d_in[9];
    const float* Wq      = (const float*)d_in[10];
    const float* bq      = (const float*)d_in[11];
    const float* Wk      = (const float*)d_in[12];
    const float* bk      = (const float*)d_in[13];
    const float* Wv      = (const float*)d_in[14];
    const float* bv      = (const float*)d_in[15];
    const float* Wskip   = (const float*)d_in[16];
    const float* bskip   = (const float*)d_in[17];
    const float* W_ih    = (const float*)d_in[18];
    const float* b_ih    = (const float*)d_in[19];
    const float* W_hh    = (const float*)d_in[20];
    const float* b_hh    = (const float*)d_in[21];

    char* ws = (char*)d_ws;
    size_t off = 0;
    auto take = [&](size_t bytes)->char* {
        char* p = ws + off;
        off = (off + bytes + 255) & ~(size_t)255;
        return p;
    };
    int* cnt        = (int*)take((size_t)NRKEYS*4);
    int* row_ptr    = (int*)take((size_t)(NRKEYS+1)*4);
    int* cursor     = (int*)take((size_t)NRKEYS*4);
    int* csr_src    = (int*)take((size_t)E_EDGES*4);
    int* blocksum   = (int*)take((size_t)SCAN_BLOCKS*4);
    __hip_bfloat16* B1t   = (__hip_bfloat16*)take((size_t)256*640*2);
    __hip_bfloat16* B2t   = (__hip_bfloat16*)take((size_t)256*1280*2);
    __hip_bfloat16* B3t   = (__hip_bfloat16*)take((size_t)1024*256*2);
    __hip_bfloat16* Biht  = (__hip_bfloat16*)take((size_t)768*256*2);
    __hip_bfloat16* Bhht  = (__hip_bfloat16*)take((size_t)768*256*2);
    float*          bias3 = (float*)take((size_t)1024*4);
    __hip_bfloat16* hprev_bf = (__hip_bfloat16*)take((size_t)N_NODES*256*2);
    __hip_bfloat16* xbf      = (__hip_bfloat16*)take((size_t)N_NODES*IN_F*2);
    char* P1 = take((size_t)N_NODES*640*2);
    char* P2 = take((size_t)N_NODES*1536*2);

    __hip_bfloat16* A1   = (__hip_bfloat16*)P1;   // [N,640]  dead after gemm1
    __hip_bfloat16* h2   = (__hip_bfloat16*)P1;   // [N,256]  dead after gemm3
    __hip_bfloat16* hatt = (__hip_bfloat16*)P1;   // [N,256]  read by fused GRU
    __hip_bfloat16* A2   = (__hip_bfloat16*)P2;   // [N,1280] dead after gemm2
    __hip_bfloat16* qkvs = (__hip_bfloat16*)P2;   // [N,1024] dead after attn_fused

    // all weight prep + fp32->bf16 converts + cnt zeroing in ONE dispatch
    prep_all<<<(PREP_TOTAL+255)/256, 256, 0, stream>>>(
        root1, W1, root2, W2, Wq, Wk, Wv, Wskip, bq, bk, bv, bskip,
        W_ih, W_hh, hprev, x,
        B1t, B2t, B3t, bias3, Biht, Bhht, hprev_bf, xbf, cnt);

    count_kernel<<<(E_EDGES+255)/256, 256, 0, stream>>>(edge_index, edge_type, cnt);
    scan_reduce_kernel<<<SCAN_BLOCKS, 1024, 0, stream>>>(cnt, blocksum);
    scan_apply_kernel<<<SCAN_BLOCKS, 1024, 0, stream>>>(cnt, blocksum, row_ptr, cursor);
    fill_kernel<<<(E_EDGES+255)/256, 256, 0, stream>>>(edge_index, edge_type, cursor, csr_src);

    agg1_kernel<<<NRKEYS/4, 256, 0, stream>>>(xbf, row_ptr, csr_src, A1);

    // h1 = relu(A1 * B1) written into A2 cols 0..255 (ldc=1280)
    dim3 g12(313, 2);
    gemm_bt_t<2><<<g12, 256, 0, stream>>>(A1, 640, B1t, b1, A2, 1280, N_NODES, 640, 1);

    agg2_kernel<<<NRKEYS/4, 256, 0, stream>>>(row_ptr, csr_src, A2);

    // h2 overwrites A1 (dead) in P1
    gemm_bt_t<2><<<g12, 256, 0, stream>>>(A2, 1280, B2t, b2, h2, 256, N_NODES, 1280, 1);

    // qkvs overwrites A2 (dead) in P2
    dim3 g3(157, 8);
    gemm_bt_t<4><<<g3, 256, 0, stream>>>(h2, 256, B3t, bias3, qkvs, 1024, N_NODES, 256, 0);

    // fused attention: one pass over edges, online softmax (unroll-4)
    attn_fused_kernel<<<N_NODES/4, 256, 0, stream>>>(qkvs, row_ptr, csr_src, hatt);

    // fused GRU gate-GEMMs + elementwise (r7 final: 512 threads, 128x64 tiles)
    gemm_gru_fused<<<dim3(157, 4), 512, 0, stream>>>(hatt, hprev_bf, Biht, Bhht,
                                                     b_ih, b_hh, hprev, (float*)d_out);
}